// Round 2
// baseline (1996.358 us; speedup 1.0000x reference)
//
#include <hip/hip_runtime.h>

typedef unsigned short u16;
typedef unsigned int u32;

// ---------------- threefry2x32 (JAX-compatible, 20 rounds) ----------------
__host__ __device__ inline u32 rotl32(u32 x, int r) { return (x << r) | (x >> (32 - r)); }

__host__ __device__ inline void tf_r4(u32& x0, u32& x1, int r0, int r1, int r2, int r3) {
  x0 += x1; x1 = rotl32(x1, r0); x1 ^= x0;
  x0 += x1; x1 = rotl32(x1, r1); x1 ^= x0;
  x0 += x1; x1 = rotl32(x1, r2); x1 ^= x0;
  x0 += x1; x1 = rotl32(x1, r3); x1 ^= x0;
}

__host__ __device__ inline void tf2x32(u32 k0, u32 k1, u32 c0, u32 c1, u32* o0, u32* o1) {
  u32 ks2 = 0x1BD11BDAu ^ k0 ^ k1;
  u32 x0 = c0 + k0, x1 = c1 + k1;
  tf_r4(x0, x1, 13, 15, 26, 6);  x0 += k1;  x1 += ks2 + 1u;
  tf_r4(x0, x1, 17, 29, 16, 24); x0 += ks2; x1 += k0 + 2u;
  tf_r4(x0, x1, 13, 15, 26, 6);  x0 += k0;  x1 += k1 + 3u;
  tf_r4(x0, x1, 17, 29, 16, 24); x0 += k1;  x1 += ks2 + 4u;
  tf_r4(x0, x1, 13, 15, 26, 6);  x0 += ks2; x1 += k0 + 5u;
  *o0 = x0; *o1 = x1;
}

// XLA/Giles f32 erfinv
__device__ inline float erfinv_f(float x) {
  float w = -log1pf(-x * x);
  float p;
  if (w < 5.0f) {
    w -= 2.5f;
    p = 2.81022636e-08f;
    p = 3.43273939e-07f + p * w;
    p = -3.5233877e-06f + p * w;
    p = -4.39150654e-06f + p * w;
    p = 0.00021858087f + p * w;
    p = -0.00125372503f + p * w;
    p = -0.00417768164f + p * w;
    p = 0.246640727f + p * w;
    p = 1.50140941f + p * w;
  } else {
    w = sqrtf(w) - 3.0f;
    p = -0.000200214257f;
    p = 0.000100950558f + p * w;
    p = 0.00134934322f + p * w;
    p = -0.00367342844f + p * w;
    p = 0.00573950773f + p * w;
    p = -0.0076224613f + p * w;
    p = 0.00943887047f + p * w;
    p = 1.00167406f + p * w;
    p = 2.83297682f + p * w;
  }
  return p * x;
}

__device__ inline float bits2normal(u32 b) {
  float f = __uint_as_float((b >> 9) | 0x3F800000u) - 1.0f;  // [0,1)
  float u = f * 2.0f - 0.99999994f;                           // (hi-lo) rounds to 2.0f
  u = fmaxf(u, -0.99999994f);
  return 1.41421356f * erfinv_f(u);                           // sqrt(2)*erfinv
}

// ---------------- dtype helpers ----------------
__device__ inline float cvt(float v) { return v; }
__device__ inline float cvt(u16 v) { return __uint_as_float(((u32)v) << 16); }
__device__ inline void stor(float* p, float v) { *p = v; }
__device__ inline void stor(u16* p, float v) {
  u32 x = __float_as_uint(v);
  *p = (u16)((x + 0x7FFFu + ((x >> 16) & 1u)) >> 16);  // RTNE bf16
}

// ---------------- graph preprocessing ----------------
__global__ void k_count(const int* __restrict__ ei, int* __restrict__ cnt, int E) {
  int e = blockIdx.x * blockDim.x + threadIdx.x;
  if (e < E) atomicAdd(&cnt[ei[E + e]], 1);
}

__global__ __launch_bounds__(1024) void k_scan(const int* __restrict__ cnt, int* __restrict__ row_ptr,
                                               int* __restrict__ cursor, float* __restrict__ dinv,
                                               int n, int E) {
  __shared__ int buf[1024];
  __shared__ int sbase;
  if (threadIdx.x == 0) sbase = 0;
  __syncthreads();
  for (int c0 = 0; c0 < n; c0 += 1024) {
    int i = c0 + threadIdx.x;
    int v = (i < n) ? cnt[i] : 0;
    buf[threadIdx.x] = v;
    __syncthreads();
    for (int off = 1; off < 1024; off <<= 1) {
      int t = (threadIdx.x >= off) ? buf[threadIdx.x - off] : 0;
      __syncthreads();
      buf[threadIdx.x] += t;
      __syncthreads();
    }
    int incl = buf[threadIdx.x];
    int base = sbase;
    if (i < n) {
      int excl = base + incl - v;
      row_ptr[i] = excl;
      cursor[i] = excl;
      dinv[i] = 1.0f / sqrtf((float)(v + 1));  // deg includes self-loop
    }
    __syncthreads();
    if (threadIdx.x == 1023) sbase = base + incl;
    __syncthreads();
  }
  if (threadIdx.x == 0) row_ptr[n] = E;
}

__global__ void k_place(const int* __restrict__ ei, int* __restrict__ cursor,
                        const float* __restrict__ dinv, int* __restrict__ src_sorted,
                        float* __restrict__ w_sorted, int E) {
  int e = blockIdx.x * blockDim.x + threadIdx.x;
  if (e < E) {
    int s = ei[e], d = ei[E + e];
    int slot = atomicAdd(&cursor[d], 1);
    src_sorted[slot] = s;
    w_sorted[slot] = dinv[s] * dinv[d];
  }
}

// ---------------- std (ddof=1) for 4 tensors ----------------
__global__ __launch_bounds__(1024) void k_std(const float* p0, int n0, const float* p1, int n1,
                                              const float* p2, int n2, const float* p3, int n3,
                                              float* __restrict__ sigma) {
  const float* p; int n;
  if (blockIdx.x == 0) { p = p0; n = n0; }
  else if (blockIdx.x == 1) { p = p1; n = n1; }
  else if (blockIdx.x == 2) { p = p2; n = n2; }
  else { p = p3; n = n3; }
  double s = 0.0, ss = 0.0;
  for (int i = threadIdx.x; i < n; i += 1024) { double v = p[i]; s += v; ss += v * v; }
  __shared__ double sh[1024];
  __shared__ double sh2[1024];
  sh[threadIdx.x] = s; sh2[threadIdx.x] = ss;
  __syncthreads();
  for (int o = 512; o > 0; o >>= 1) {
    if (threadIdx.x < o) { sh[threadIdx.x] += sh[threadIdx.x + o]; sh2[threadIdx.x] += sh2[threadIdx.x + o]; }
    __syncthreads();
  }
  if (threadIdx.x == 0) {
    double mean = sh[0] / n;
    double var = (sh2[0] - sh[0] * mean) / (double)(n - 1);
    if (var < 0.0) var = 0.0;
    sigma[blockIdx.x] = fmaxf((float)sqrt(var), 1e-6f);
  }
}

// partitionable threefry random_bits: per-element 64-bit counter j -> bits = o0 ^ o1
__global__ void k_perturb(const float* __restrict__ p, float* __restrict__ ph, int n,
                          u32 k0, u32 k1, const float* __restrict__ sigma, int sidx) {
  int j = blockIdx.x * blockDim.x + threadIdx.x;
  if (j < n) {
    u32 r0, r1;
    tf2x32(k0, k1, 0u, (u32)j, &r0, &r1);  // hi=0 (n < 2^32), lo=j
    ph[j] = p[j] + sigma[sidx] * bits2normal(r0 ^ r1);
  }
}

// ---------------- CSR aggregation: out = P @ hin (+bias) ----------------
template <typename TIN, typename TOUT, int F, bool BIAS>
__global__ __launch_bounds__(256) void k_agg(const TIN* __restrict__ hin, TOUT* __restrict__ hout,
                                             const int* __restrict__ row_ptr,
                                             const int* __restrict__ src_sorted,
                                             const float* __restrict__ w_sorted,
                                             const float* __restrict__ dinv,
                                             const float* __restrict__ bias, int n) {
  int wv = threadIdx.x >> 6, lane = threadIdx.x & 63;
  int node = blockIdx.x * 4 + wv;
  if (node >= n) return;
  constexpr int PER = F / 64;
  float acc[PER];
#pragma unroll
  for (int j = 0; j < PER; ++j) acc[j] = 0.0f;
  int s0 = row_ptr[node], s1 = row_ptr[node + 1];
  for (int s = s0; s < s1; ++s) {
    float wgt = w_sorted[s];
    int r = src_sorted[s];
    const TIN* row = hin + (size_t)r * F + lane * PER;
#pragma unroll
    for (int j = 0; j < PER; ++j) acc[j] += wgt * cvt(row[j]);
  }
  float sw = dinv[node]; sw *= sw;  // self-loop 1/deg
  const TIN* row = hin + (size_t)node * F + lane * PER;
#pragma unroll
  for (int j = 0; j < PER; ++j) acc[j] += sw * cvt(row[j]);
  TOUT* orow = hout + (size_t)node * F + lane * PER;
#pragma unroll
  for (int j = 0; j < PER; ++j) {
    float v = acc[j];
    if (BIAS) v += bias[lane * PER + j];
    stor(&orow[j], v);
  }
}

// ---------------- tiled GEMM: C = act(A @ B + bias) ----------------
template <typename TA, typename TC, bool RELU, bool BIAS>
__global__ __launch_bounds__(256) void k_gemm(const TA* __restrict__ A, const float* __restrict__ B,
                                              const float* __restrict__ bias, TC* __restrict__ C,
                                              int M, int N, int K) {
  __shared__ float As[64][17];
  __shared__ float Bs[16][65];
  const int tx = threadIdx.x & 15;
  const int ty = threadIdx.x >> 4;
  const int row0 = blockIdx.y * 64;
  const int col0 = blockIdx.x * 64;
  float acc[4][4] = {};
  for (int k0 = 0; k0 < K; k0 += 16) {
#pragma unroll
    for (int i = 0; i < 4; ++i) {
      int lin = threadIdx.x + i * 256;
      int r = lin >> 4, c = lin & 15;
      int gr = row0 + r;
      As[r][c] = (gr < M) ? cvt(A[(size_t)gr * K + k0 + c]) : 0.0f;
    }
#pragma unroll
    for (int i = 0; i < 4; ++i) {
      int lin = threadIdx.x + i * 256;
      int r = lin >> 6, c = lin & 63;
      Bs[r][c] = B[(size_t)(k0 + r) * N + col0 + c];
    }
    __syncthreads();
#pragma unroll
    for (int k = 0; k < 16; ++k) {
      float a[4], b[4];
#pragma unroll
      for (int i = 0; i < 4; ++i) a[i] = As[ty * 4 + i][k];
#pragma unroll
      for (int j = 0; j < 4; ++j) b[j] = Bs[k][tx * 4 + j];
#pragma unroll
      for (int i = 0; i < 4; ++i)
#pragma unroll
        for (int j = 0; j < 4; ++j) acc[i][j] += a[i] * b[j];
    }
    __syncthreads();
  }
#pragma unroll
  for (int i = 0; i < 4; ++i) {
    int gr = row0 + ty * 4 + i;
    if (gr < M) {
#pragma unroll
      for (int j = 0; j < 4; ++j) {
        int gc = col0 + tx * 4 + j;
        float v = acc[i][j];
        if (BIAS) v += bias[gc];
        if (RELU) v = fmaxf(v, 0.0f);
        stor(&C[(size_t)gr * N + gc], v);
      }
    }
  }
}

// ---------------- pooling (mean+max per graph) ----------------
__device__ inline int lbound(const int* a, int n, int v) {
  int lo = 0, hi = n;
  while (lo < hi) { int mid = (lo + hi) >> 1; if (a[mid] < v) lo = mid + 1; else hi = mid; }
  return lo;
}

__global__ __launch_bounds__(256) void k_pool(const float* __restrict__ z, const int* __restrict__ batch,
                                              float* __restrict__ zg, int n) {
  int g = blockIdx.x;
  __shared__ int ss, se;
  if (threadIdx.x == 0) { ss = lbound(batch, n, g); se = lbound(batch, n, g + 1); }
  __syncthreads();
  int start = ss, end = se;
  int f = threadIdx.x;  // 256 features
  float acc = 0.0f, mx = -INFINITY;
  for (int i = start; i < end; ++i) {
    float v = z[(size_t)i * 256 + f];
    acc += v;
    mx = fmaxf(mx, v);
  }
  int c = end - start;
  float mean = acc / fmaxf((float)c, 1.0f);
  float mxo = (c > 0) ? mx : 0.0f;
  zg[(size_t)g * 512 + f] = mean;
  zg[(size_t)g * 512 + 256 + f] = mxo;
}

// ---------------- launch ----------------
extern "C" void kernel_launch(void* const* d_in, const int* in_sizes, int n_in,
                              void* d_out, int out_size, void* d_ws, size_t ws_size,
                              hipStream_t stream) {
  const float* x   = (const float*)d_in[0];
  const int*   ei  = (const int*)d_in[1];
  const int*   bat = (const int*)d_in[2];
  const float* W1  = (const float*)d_in[4];
  const float* b1  = (const float*)d_in[5];
  const float* W2  = (const float*)d_in[6];
  const float* b2  = (const float*)d_in[7];
  const float* Wd  = (const float*)d_in[8];
  const float* bd  = (const float*)d_in[9];
  const float* P1w = (const float*)d_in[10];
  const float* P1b = (const float*)d_in[11];
  const float* P2w = (const float*)d_in[12];
  const float* P2b = (const float*)d_in[13];
  const float* P3w = (const float*)d_in[14];
  const float* P3b = (const float*)d_in[15];

  const int N = in_sizes[0] / 128;  // 50000
  const int E = in_sizes[1] / 2;    // 400000
  const int B = 64;

  // workspace carve (deterministic, ~95 MB)
  char* w = (char*)d_ws;
  auto carve = [&](size_t bytes) -> void* {
    void* p = (void*)w;
    w += (bytes + 255) & ~(size_t)255;
    return p;
  };
  int*   cnt        = (int*)carve((size_t)N * 4);
  int*   row_ptr    = (int*)carve((size_t)(N + 1) * 4);
  int*   cursor     = (int*)carve((size_t)N * 4);
  float* dinv       = (float*)carve((size_t)N * 4);
  int*   src_sorted = (int*)carve((size_t)E * 4);
  float* w_sorted   = (float*)carve((size_t)E * 4);
  float* sigma      = (float*)carve(256);
  float* W1h        = (float*)carve((size_t)128 * 512 * 4);
  float* b1h        = (float*)carve((size_t)512 * 4);
  float* W2h        = (float*)carve((size_t)512 * 256 * 4);
  float* b2h        = (float*)carve((size_t)256 * 4);
  u16*   px         = (u16*)carve((size_t)N * 128 * 2);
  u16*   z1         = (u16*)carve((size_t)N * 512 * 2);  // reused as z1h
  u16*   y1         = (u16*)carve((size_t)N * 256 * 2);  // reused as y1h, y_d
  float* g1         = (float*)carve((size_t)64 * 256 * 4);
  float* g2         = (float*)carve((size_t)64 * 128 * 4);

  float* out       = (float*)d_out;
  float* z_node    = out;
  float* z_g       = z_node + (size_t)N * 256;
  float* zhat_node = z_g + (size_t)B * 512;
  float* zhat_g    = zhat_node + (size_t)N * 256;
  float* h_g       = zhat_g + (size_t)B * 512;
  float* hhat_g    = h_g + (size_t)B * 64;
  float* x_hat     = hhat_g + (size_t)B * 64;

  // host-side: nk = split(key(42), 4) -- partitionable/improved split:
  // nk[i] = threefry2x32(key, counter=(hi=0, lo=i)), both output words are the key
  u32 nk[4][2];
  for (u32 i = 0; i < 4; ++i) tf2x32(0u, 42u, 0u, i, &nk[i][0], &nk[i][1]);

  // --- preprocessing ---
  hipMemsetAsync(cnt, 0, (size_t)N * 4, stream);
  k_count<<<(E + 255) / 256, 256, 0, stream>>>(ei, cnt, E);
  k_scan<<<1, 1024, 0, stream>>>(cnt, row_ptr, cursor, dinv, N, E);
  k_place<<<(E + 255) / 256, 256, 0, stream>>>(ei, cursor, dinv, src_sorted, w_sorted, E);

  k_std<<<4, 1024, 0, stream>>>(W1, 128 * 512, b1, 512, W2, 512 * 256, b2, 256, sigma);
  k_perturb<<<(65536 + 255) / 256, 256, 0, stream>>>(W1, W1h, 128 * 512, nk[0][0], nk[0][1], sigma, 0);
  k_perturb<<<2, 256, 0, stream>>>(b1, b1h, 512, nk[1][0], nk[1][1], sigma, 1);
  k_perturb<<<(131072 + 255) / 256, 256, 0, stream>>>(W2, W2h, 512 * 256, nk[2][0], nk[2][1], sigma, 2);
  k_perturb<<<1, 256, 0, stream>>>(b2, b2h, 256, nk[3][0], nk[3][1], sigma, 3);

  const int aggBlocks = (N + 3) / 4;

  // px = P @ x   (shared by both branches)
  k_agg<float, u16, 128, false><<<aggBlocks, 256, 0, stream>>>(x, px, row_ptr, src_sorted, w_sorted, dinv, nullptr, N);

  dim3 g512(512 / 64, (N + 63) / 64);
  dim3 g256(256 / 64, (N + 63) / 64);
  dim3 g128(128 / 64, (N + 63) / 64);

  // clean branch
  k_gemm<u16, u16, true, true><<<g512, 256, 0, stream>>>(px, W1, b1, z1, N, 512, 128);
  k_gemm<u16, u16, false, false><<<g256, 256, 0, stream>>>(z1, W2, nullptr, y1, N, 256, 512);
  k_agg<u16, float, 256, true><<<aggBlocks, 256, 0, stream>>>(y1, z_node, row_ptr, src_sorted, w_sorted, dinv, b2, N);

  // perturbed branch (reuse z1/y1 buffers)
  k_gemm<u16, u16, true, true><<<g512, 256, 0, stream>>>(px, W1h, b1h, z1, N, 512, 128);
  k_gemm<u16, u16, false, false><<<g256, 256, 0, stream>>>(z1, W2h, nullptr, y1, N, 256, 512);
  k_agg<u16, float, 256, true><<<aggBlocks, 256, 0, stream>>>(y1, zhat_node, row_ptr, src_sorted, w_sorted, dinv, b2h, N);

  // pooling
  k_pool<<<B, 256, 0, stream>>>(z_node, bat, z_g, N);
  k_pool<<<B, 256, 0, stream>>>(zhat_node, bat, zhat_g, N);

  // decoder: x_hat = P @ (z_node @ Wd) + bd
  k_gemm<float, u16, false, false><<<g128, 256, 0, stream>>>(z_node, Wd, nullptr, y1, N, 128, 256);
  k_agg<u16, float, 128, true><<<aggBlocks, 256, 0, stream>>>(y1, x_hat, row_ptr, src_sorted, w_sorted, dinv, bd, N);

  // projection heads
  dim3 p1(256 / 64, 1), p2(128 / 64, 1), p3(64 / 64, 1);
  k_gemm<float, float, true, true><<<p1, 256, 0, stream>>>(z_g, P1w, P1b, g1, 64, 256, 512);
  k_gemm<float, float, true, true><<<p2, 256, 0, stream>>>(g1, P2w, P2b, g2, 64, 128, 256);
  k_gemm<float, float, false, true><<<p3, 256, 0, stream>>>(g2, P3w, P3b, h_g, 64, 64, 128);
  k_gemm<float, float, true, true><<<p1, 256, 0, stream>>>(zhat_g, P1w, P1b, g1, 64, 256, 512);
  k_gemm<float, float, true, true><<<p2, 256, 0, stream>>>(g1, P2w, P2b, g2, 64, 128, 256);
  k_gemm<float, float, false, true><<<p3, 256, 0, stream>>>(g2, P3w, P3b, hhat_g, 64, 64, 128);
}

// Round 3
// 1251.973 us; speedup vs baseline: 1.5946x; 1.5946x over previous
//
#include <hip/hip_runtime.h>

typedef unsigned short u16;
typedef unsigned int u32;
typedef short bf16x8 __attribute__((ext_vector_type(8)));
typedef float f32x4 __attribute__((ext_vector_type(4)));

// ---------------- threefry2x32 (JAX-compatible, 20 rounds) ----------------
__host__ __device__ inline u32 rotl32(u32 x, int r) { return (x << r) | (x >> (32 - r)); }

__host__ __device__ inline void tf_r4(u32& x0, u32& x1, int r0, int r1, int r2, int r3) {
  x0 += x1; x1 = rotl32(x1, r0); x1 ^= x0;
  x0 += x1; x1 = rotl32(x1, r1); x1 ^= x0;
  x0 += x1; x1 = rotl32(x1, r2); x1 ^= x0;
  x0 += x1; x1 = rotl32(x1, r3); x1 ^= x0;
}

__host__ __device__ inline void tf2x32(u32 k0, u32 k1, u32 c0, u32 c1, u32* o0, u32* o1) {
  u32 ks2 = 0x1BD11BDAu ^ k0 ^ k1;
  u32 x0 = c0 + k0, x1 = c1 + k1;
  tf_r4(x0, x1, 13, 15, 26, 6);  x0 += k1;  x1 += ks2 + 1u;
  tf_r4(x0, x1, 17, 29, 16, 24); x0 += ks2; x1 += k0 + 2u;
  tf_r4(x0, x1, 13, 15, 26, 6);  x0 += k0;  x1 += k1 + 3u;
  tf_r4(x0, x1, 17, 29, 16, 24); x0 += k1;  x1 += ks2 + 4u;
  tf_r4(x0, x1, 13, 15, 26, 6);  x0 += ks2; x1 += k0 + 5u;
  *o0 = x0; *o1 = x1;
}

// XLA/Giles f32 erfinv
__device__ inline float erfinv_f(float x) {
  float w = -log1pf(-x * x);
  float p;
  if (w < 5.0f) {
    w -= 2.5f;
    p = 2.81022636e-08f;
    p = 3.43273939e-07f + p * w;
    p = -3.5233877e-06f + p * w;
    p = -4.39150654e-06f + p * w;
    p = 0.00021858087f + p * w;
    p = -0.00125372503f + p * w;
    p = -0.00417768164f + p * w;
    p = 0.246640727f + p * w;
    p = 1.50140941f + p * w;
  } else {
    w = sqrtf(w) - 3.0f;
    p = -0.000200214257f;
    p = 0.000100950558f + p * w;
    p = 0.00134934322f + p * w;
    p = -0.00367342844f + p * w;
    p = 0.00573950773f + p * w;
    p = -0.0076224613f + p * w;
    p = 0.00943887047f + p * w;
    p = 1.00167406f + p * w;
    p = 2.83297682f + p * w;
  }
  return p * x;
}

__device__ inline float bits2normal(u32 b) {
  float f = __uint_as_float((b >> 9) | 0x3F800000u) - 1.0f;  // [0,1)
  float u = f * 2.0f - 0.99999994f;
  u = fmaxf(u, -0.99999994f);
  return 1.41421356f * erfinv_f(u);
}

// ---------------- dtype helpers ----------------
__device__ inline float cvt(float v) { return v; }
__device__ inline float cvt(u16 v) { return __uint_as_float(((u32)v) << 16); }
__device__ inline void stor(float* p, float v) { *p = v; }
__device__ inline void stor(u16* p, float v) {
  u32 x = __float_as_uint(v);
  *p = (u16)((x + 0x7FFFu + ((x >> 16) & 1u)) >> 16);  // RTNE bf16
}
__device__ inline u16 f2b(float v) {
  u32 x = __float_as_uint(v);
  return (u16)((x + 0x7FFFu + ((x >> 16) & 1u)) >> 16);
}

// ---------------- graph preprocessing ----------------
__global__ void k_count(const int* __restrict__ ei, int* __restrict__ cnt, int E) {
  int e = blockIdx.x * blockDim.x + threadIdx.x;
  if (e < E) atomicAdd(&cnt[ei[E + e]], 1);
}

__global__ __launch_bounds__(1024) void k_scan(const int* __restrict__ cnt, int* __restrict__ row_ptr,
                                               int* __restrict__ cursor, float* __restrict__ dinv,
                                               int n, int E) {
  __shared__ int buf[1024];
  __shared__ int sbase;
  if (threadIdx.x == 0) sbase = 0;
  __syncthreads();
  for (int c0 = 0; c0 < n; c0 += 1024) {
    int i = c0 + threadIdx.x;
    int v = (i < n) ? cnt[i] : 0;
    buf[threadIdx.x] = v;
    __syncthreads();
    for (int off = 1; off < 1024; off <<= 1) {
      int t = (threadIdx.x >= off) ? buf[threadIdx.x - off] : 0;
      __syncthreads();
      buf[threadIdx.x] += t;
      __syncthreads();
    }
    int incl = buf[threadIdx.x];
    int base = sbase;
    if (i < n) {
      int excl = base + incl - v;
      row_ptr[i] = excl;
      cursor[i] = excl;
      dinv[i] = 1.0f / sqrtf((float)(v + 1));
    }
    __syncthreads();
    if (threadIdx.x == 1023) sbase = base + incl;
    __syncthreads();
  }
  if (threadIdx.x == 0) row_ptr[n] = E;
}

__global__ void k_place(const int* __restrict__ ei, int* __restrict__ cursor,
                        const float* __restrict__ dinv, int* __restrict__ src_sorted,
                        float* __restrict__ w_sorted, int E) {
  int e = blockIdx.x * blockDim.x + threadIdx.x;
  if (e < E) {
    int s = ei[e], d = ei[E + e];
    int slot = atomicAdd(&cursor[d], 1);
    src_sorted[slot] = s;
    w_sorted[slot] = dinv[s] * dinv[d];
  }
}

// ---------------- std (ddof=1) for 4 tensors ----------------
__global__ __launch_bounds__(1024) void k_std(const float* p0, int n0, const float* p1, int n1,
                                              const float* p2, int n2, const float* p3, int n3,
                                              float* __restrict__ sigma) {
  const float* p; int n;
  if (blockIdx.x == 0) { p = p0; n = n0; }
  else if (blockIdx.x == 1) { p = p1; n = n1; }
  else if (blockIdx.x == 2) { p = p2; n = n2; }
  else { p = p3; n = n3; }
  double s = 0.0, ss = 0.0;
  for (int i = threadIdx.x; i < n; i += 1024) { double v = p[i]; s += v; ss += v * v; }
  __shared__ double sh[1024];
  __shared__ double sh2[1024];
  sh[threadIdx.x] = s; sh2[threadIdx.x] = ss;
  __syncthreads();
  for (int o = 512; o > 0; o >>= 1) {
    if (threadIdx.x < o) { sh[threadIdx.x] += sh[threadIdx.x + o]; sh2[threadIdx.x] += sh2[threadIdx.x + o]; }
    __syncthreads();
  }
  if (threadIdx.x == 0) {
    double mean = sh[0] / n;
    double var = (sh2[0] - sh[0] * mean) / (double)(n - 1);
    if (var < 0.0) var = 0.0;
    sigma[blockIdx.x] = fmaxf((float)sqrt(var), 1e-6f);
  }
}

// partitionable threefry random_bits: counter (0, j) -> bits = o0 ^ o1
__global__ void k_perturb(const float* __restrict__ p, float* __restrict__ ph, int n,
                          u32 k0, u32 k1, const float* __restrict__ sigma, int sidx) {
  int j = blockIdx.x * blockDim.x + threadIdx.x;
  if (j < n) {
    u32 r0, r1;
    tf2x32(k0, k1, 0u, (u32)j, &r0, &r1);
    ph[j] = p[j] + sigma[sidx] * bits2normal(r0 ^ r1);
  }
}

// transpose f32 [K][N] -> bf16 [N][K]
__global__ void k_transpose(const float* __restrict__ in, u16* __restrict__ out, int K, int N) {
  int j = blockIdx.x * blockDim.x + threadIdx.x;
  if (j < K * N) {
    int k = j / N, n = j - k * N;
    out[(size_t)n * K + k] = f2b(in[j]);
  }
}

// ---------------- CSR aggregation: out = P @ hin (+bias) ----------------
template <typename TIN, typename TOUT, int F, bool BIAS, bool DUAL>
__global__ __launch_bounds__(256) void k_agg(const TIN* __restrict__ hin, TOUT* __restrict__ hout,
                                             u16* __restrict__ houtb,
                                             const int* __restrict__ row_ptr,
                                             const int* __restrict__ src_sorted,
                                             const float* __restrict__ w_sorted,
                                             const float* __restrict__ dinv,
                                             const float* __restrict__ bias, int n) {
  int wv = threadIdx.x >> 6, lane = threadIdx.x & 63;
  int node = blockIdx.x * 4 + wv;
  if (node >= n) return;
  constexpr int PER = F / 64;
  float acc[PER];
#pragma unroll
  for (int j = 0; j < PER; ++j) acc[j] = 0.0f;
  int s0 = row_ptr[node], s1 = row_ptr[node + 1];
  for (int s = s0; s < s1; ++s) {
    float wgt = w_sorted[s];
    int r = src_sorted[s];
    const TIN* row = hin + (size_t)r * F + lane * PER;
#pragma unroll
    for (int j = 0; j < PER; ++j) acc[j] += wgt * cvt(row[j]);
  }
  float sw = dinv[node]; sw *= sw;
  const TIN* row = hin + (size_t)node * F + lane * PER;
#pragma unroll
  for (int j = 0; j < PER; ++j) acc[j] += sw * cvt(row[j]);
  TOUT* orow = hout + (size_t)node * F + lane * PER;
#pragma unroll
  for (int j = 0; j < PER; ++j) {
    float v = acc[j];
    if (BIAS) v += bias[lane * PER + j];
    stor(&orow[j], v);
    if (DUAL) houtb[(size_t)node * F + lane * PER + j] = f2b(v);
  }
}

// ---------------- MFMA bf16 GEMM: C = act(A @ BT^T + bias) ----------------
// A: [M][K] bf16 row-major; BT: [N][K] bf16 (i.e. B transposed); C: [M][N]
// 128x128 tile, BK=64, 256 threads = 4 waves in 2x2, each wave 64x64.
template <bool RELU, bool BIAS, typename TC>
__global__ __launch_bounds__(256) void k_mgemm(const u16* __restrict__ A, const u16* __restrict__ BT,
                                               const float* __restrict__ bias, TC* __restrict__ C,
                                               int M, int N, int K) {
  __shared__ u16 As[128 * 64];
  __shared__ u16 Bs[128 * 64];
  const int t = threadIdx.x;
  const int w = t >> 6, lane = t & 63;
  const int brow = blockIdx.y * 128;
  const int bcol = blockIdx.x * 128;
  const int wr = w >> 1, wc = w & 1;

  f32x4 acc[4][4];
#pragma unroll
  for (int m = 0; m < 4; ++m)
#pragma unroll
    for (int n = 0; n < 4; ++n) acc[m][n] = (f32x4){0.f, 0.f, 0.f, 0.f};

  for (int kt = 0; kt < K; kt += 64) {
#pragma unroll
    for (int j = 0; j < 4; ++j) {
      int c = j * 4 + w;              // chunk 0..15 (wave-uniform)
      int li = c * 64 + lane;         // 16B unit index 0..1023
      int row = li >> 3, col8 = li & 7;
      int ar = brow + row; if (ar > M - 1) ar = M - 1;
      __builtin_amdgcn_global_load_lds(
          (const __attribute__((address_space(1))) void*)(A + (size_t)ar * K + kt + col8 * 8),
          (__attribute__((address_space(3))) void*)(As + c * 512), 16, 0, 0);
      __builtin_amdgcn_global_load_lds(
          (const __attribute__((address_space(1))) void*)(BT + (size_t)(bcol + row) * K + kt + col8 * 8),
          (__attribute__((address_space(3))) void*)(Bs + c * 512), 16, 0, 0);
    }
    __syncthreads();
    bf16x8 af[4][2], bb[4][2];
#pragma unroll
    for (int kk = 0; kk < 2; ++kk) {
      int kof = kk * 32 + (lane >> 4) * 8;
#pragma unroll
      for (int m = 0; m < 4; ++m)
        af[m][kk] = *(const bf16x8*)(As + (wr * 64 + m * 16 + (lane & 15)) * 64 + kof);
#pragma unroll
      for (int n = 0; n < 4; ++n)
        bb[n][kk] = *(const bf16x8*)(Bs + (wc * 64 + n * 16 + (lane & 15)) * 64 + kof);
    }
#pragma unroll
    for (int kk = 0; kk < 2; ++kk)
#pragma unroll
      for (int m = 0; m < 4; ++m)
#pragma unroll
        for (int n = 0; n < 4; ++n)
          acc[m][n] = __builtin_amdgcn_mfma_f32_16x16x32_bf16(af[m][kk], bb[n][kk], acc[m][n], 0, 0, 0);
    __syncthreads();
  }
  // epilogue: C/D layout col=lane&15, row=(lane>>4)*4+reg
#pragma unroll
  for (int m = 0; m < 4; ++m) {
    int r0 = brow + wr * 64 + m * 16 + (lane >> 4) * 4;
#pragma unroll
    for (int n = 0; n < 4; ++n) {
      int col = bcol + wc * 64 + n * 16 + (lane & 15);
      float bv = BIAS ? bias[col] : 0.0f;
#pragma unroll
      for (int q = 0; q < 4; ++q) {
        int rr = r0 + q;
        if (rr < M) {
          float v = acc[m][n][q] + bv;
          if (RELU) v = fmaxf(v, 0.0f);
          stor(&C[(size_t)rr * N + col], v);
        }
      }
    }
  }
}

// ---------------- small f32 GEMM (proj heads): C = act(A @ B + bias) ----------------
template <typename TA, typename TC, bool RELU, bool BIAS>
__global__ __launch_bounds__(256) void k_gemm(const TA* __restrict__ A, const float* __restrict__ B,
                                              const float* __restrict__ bias, TC* __restrict__ C,
                                              int M, int N, int K) {
  __shared__ float As[64][17];
  __shared__ float Bs[16][65];
  const int tx = threadIdx.x & 15;
  const int ty = threadIdx.x >> 4;
  const int row0 = blockIdx.y * 64;
  const int col0 = blockIdx.x * 64;
  float acc[4][4] = {};
  for (int k0 = 0; k0 < K; k0 += 16) {
#pragma unroll
    for (int i = 0; i < 4; ++i) {
      int lin = threadIdx.x + i * 256;
      int r = lin >> 4, c = lin & 15;
      int gr = row0 + r;
      As[r][c] = (gr < M) ? cvt(A[(size_t)gr * K + k0 + c]) : 0.0f;
    }
#pragma unroll
    for (int i = 0; i < 4; ++i) {
      int lin = threadIdx.x + i * 256;
      int r = lin >> 6, c = lin & 63;
      Bs[r][c] = B[(size_t)(k0 + r) * N + col0 + c];
    }
    __syncthreads();
#pragma unroll
    for (int k = 0; k < 16; ++k) {
      float a[4], b[4];
#pragma unroll
      for (int i = 0; i < 4; ++i) a[i] = As[ty * 4 + i][k];
#pragma unroll
      for (int j = 0; j < 4; ++j) b[j] = Bs[k][tx * 4 + j];
#pragma unroll
      for (int i = 0; i < 4; ++i)
#pragma unroll
        for (int j = 0; j < 4; ++j) acc[i][j] += a[i] * b[j];
    }
    __syncthreads();
  }
#pragma unroll
  for (int i = 0; i < 4; ++i) {
    int gr = row0 + ty * 4 + i;
    if (gr < M) {
#pragma unroll
      for (int j = 0; j < 4; ++j) {
        int gc = col0 + tx * 4 + j;
        float v = acc[i][j];
        if (BIAS) v += bias[gc];
        if (RELU) v = fmaxf(v, 0.0f);
        stor(&C[(size_t)gr * N + gc], v);
      }
    }
  }
}

// ---------------- pooling (mean+max per graph) ----------------
__device__ inline int lbound(const int* a, int n, int v) {
  int lo = 0, hi = n;
  while (lo < hi) { int mid = (lo + hi) >> 1; if (a[mid] < v) lo = mid + 1; else hi = mid; }
  return lo;
}

__global__ __launch_bounds__(256) void k_pool(const float* __restrict__ z, const int* __restrict__ batch,
                                              float* __restrict__ zg, int n) {
  int g = blockIdx.x;
  __shared__ int ss, se;
  if (threadIdx.x == 0) { ss = lbound(batch, n, g); se = lbound(batch, n, g + 1); }
  __syncthreads();
  int start = ss, end = se;
  int f = threadIdx.x;
  float acc = 0.0f, mx = -INFINITY;
  for (int i = start; i < end; ++i) {
    float v = z[(size_t)i * 256 + f];
    acc += v;
    mx = fmaxf(mx, v);
  }
  int c = end - start;
  float mean = acc / fmaxf((float)c, 1.0f);
  float mxo = (c > 0) ? mx : 0.0f;
  zg[(size_t)g * 512 + f] = mean;
  zg[(size_t)g * 512 + 256 + f] = mxo;
}

// ---------------- launch ----------------
extern "C" void kernel_launch(void* const* d_in, const int* in_sizes, int n_in,
                              void* d_out, int out_size, void* d_ws, size_t ws_size,
                              hipStream_t stream) {
  const float* x   = (const float*)d_in[0];
  const int*   ei  = (const int*)d_in[1];
  const int*   bat = (const int*)d_in[2];
  const float* W1  = (const float*)d_in[4];
  const float* b1  = (const float*)d_in[5];
  const float* W2  = (const float*)d_in[6];
  const float* b2  = (const float*)d_in[7];
  const float* Wd  = (const float*)d_in[8];
  const float* bd  = (const float*)d_in[9];
  const float* P1w = (const float*)d_in[10];
  const float* P1b = (const float*)d_in[11];
  const float* P2w = (const float*)d_in[12];
  const float* P2b = (const float*)d_in[13];
  const float* P3w = (const float*)d_in[14];
  const float* P3b = (const float*)d_in[15];

  const int N = in_sizes[0] / 128;  // 50000
  const int E = in_sizes[1] / 2;    // 400000
  const int B = 64;

  char* w = (char*)d_ws;
  auto carve = [&](size_t bytes) -> void* {
    void* p = (void*)w;
    w += (bytes + 255) & ~(size_t)255;
    return p;
  };
  int*   cnt        = (int*)carve((size_t)N * 4);
  int*   row_ptr    = (int*)carve((size_t)(N + 1) * 4);
  int*   cursor     = (int*)carve((size_t)N * 4);
  float* dinv       = (float*)carve((size_t)N * 4);
  int*   src_sorted = (int*)carve((size_t)E * 4);
  float* w_sorted   = (float*)carve((size_t)E * 4);
  float* sigma      = (float*)carve(256);
  float* W1h        = (float*)carve((size_t)128 * 512 * 4);
  float* b1h        = (float*)carve((size_t)512 * 4);
  float* W2h        = (float*)carve((size_t)512 * 256 * 4);
  float* b2h        = (float*)carve((size_t)256 * 4);
  u16*   W1T        = (u16*)carve((size_t)128 * 512 * 2);
  u16*   W2T        = (u16*)carve((size_t)512 * 256 * 2);
  u16*   WdT        = (u16*)carve((size_t)256 * 128 * 2);
  u16*   W1hT       = (u16*)carve((size_t)128 * 512 * 2);
  u16*   W2hT       = (u16*)carve((size_t)512 * 256 * 2);
  u16*   px         = (u16*)carve((size_t)N * 128 * 2);
  u16*   z1         = (u16*)carve((size_t)N * 512 * 2);   // also aliased as znb after clean L2
  u16*   y1         = (u16*)carve((size_t)N * 256 * 2);
  float* g1         = (float*)carve((size_t)64 * 256 * 4);
  float* g2         = (float*)carve((size_t)64 * 128 * 4);
  u16*   znb        = z1;  // alias: z1 dead after clean layer-2 GEMM

  float* out       = (float*)d_out;
  float* z_node    = out;
  float* z_g       = z_node + (size_t)N * 256;
  float* zhat_node = z_g + (size_t)B * 512;
  float* zhat_g    = zhat_node + (size_t)N * 256;
  float* h_g       = zhat_g + (size_t)B * 512;
  float* hhat_g    = h_g + (size_t)B * 64;
  float* x_hat     = hhat_g + (size_t)B * 64;

  // nk = split(key(42), 4): nk[i] = threefry(key, (0, i))
  u32 nk[4][2];
  for (u32 i = 0; i < 4; ++i) tf2x32(0u, 42u, 0u, i, &nk[i][0], &nk[i][1]);

  // --- graph preprocessing ---
  hipMemsetAsync(cnt, 0, (size_t)N * 4, stream);
  k_count<<<(E + 255) / 256, 256, 0, stream>>>(ei, cnt, E);
  k_scan<<<1, 1024, 0, stream>>>(cnt, row_ptr, cursor, dinv, N, E);
  k_place<<<(E + 255) / 256, 256, 0, stream>>>(ei, cursor, dinv, src_sorted, w_sorted, E);

  // --- perturbed weights ---
  k_std<<<4, 1024, 0, stream>>>(W1, 128 * 512, b1, 512, W2, 512 * 256, b2, 256, sigma);
  k_perturb<<<(65536 + 255) / 256, 256, 0, stream>>>(W1, W1h, 128 * 512, nk[0][0], nk[0][1], sigma, 0);
  k_perturb<<<2, 256, 0, stream>>>(b1, b1h, 512, nk[1][0], nk[1][1], sigma, 1);
  k_perturb<<<(131072 + 255) / 256, 256, 0, stream>>>(W2, W2h, 512 * 256, nk[2][0], nk[2][1], sigma, 2);
  k_perturb<<<1, 256, 0, stream>>>(b2, b2h, 256, nk[3][0], nk[3][1], sigma, 3);

  // --- bf16 transposed weight panels ---
  k_transpose<<<(65536 + 255) / 256, 256, 0, stream>>>(W1, W1T, 128, 512);
  k_transpose<<<(131072 + 255) / 256, 256, 0, stream>>>(W2, W2T, 512, 256);
  k_transpose<<<(32768 + 255) / 256, 256, 0, stream>>>(Wd, WdT, 256, 128);
  k_transpose<<<(65536 + 255) / 256, 256, 0, stream>>>(W1h, W1hT, 128, 512);
  k_transpose<<<(131072 + 255) / 256, 256, 0, stream>>>(W2h, W2hT, 512, 256);

  const int aggBlocks = (N + 3) / 4;

  // px = P @ x (shared by both branches)
  k_agg<float, u16, 128, false, false><<<aggBlocks, 256, 0, stream>>>(x, px, nullptr, row_ptr, src_sorted, w_sorted, dinv, nullptr, N);

  const int MB = (N + 127) / 128;
  dim3 m512(4, MB), m256(2, MB), m128(1, MB);

  // perturbed branch first (so z1 can be reused as znb later)
  k_mgemm<true, true, u16><<<m512, 256, 0, stream>>>(px, W1hT, b1h, z1, N, 512, 128);
  k_mgemm<false, false, u16><<<m256, 256, 0, stream>>>(z1, W2hT, nullptr, y1, N, 256, 512);
  k_agg<u16, float, 256, true, false><<<aggBlocks, 256, 0, stream>>>(y1, zhat_node, nullptr, row_ptr, src_sorted, w_sorted, dinv, b2h, N);

  // clean branch
  k_mgemm<true, true, u16><<<m512, 256, 0, stream>>>(px, W1T, b1, z1, N, 512, 128);
  k_mgemm<false, false, u16><<<m256, 256, 0, stream>>>(z1, W2T, nullptr, y1, N, 256, 512);
  // z1 now dead -> agg dual-writes f32 z_node (d_out) + bf16 znb (= z1 buffer)
  k_agg<u16, float, 256, true, true><<<aggBlocks, 256, 0, stream>>>(y1, z_node, znb, row_ptr, src_sorted, w_sorted, dinv, b2, N);

  // pooling
  k_pool<<<B, 256, 0, stream>>>(z_node, bat, z_g, N);
  k_pool<<<B, 256, 0, stream>>>(zhat_node, bat, zhat_g, N);

  // decoder: x_hat = P @ (z_node @ Wd) + bd
  k_mgemm<false, false, u16><<<m128, 256, 0, stream>>>(znb, WdT, nullptr, y1, N, 128, 256);
  k_agg<u16, float, 128, true, false><<<aggBlocks, 256, 0, stream>>>(y1, x_hat, nullptr, row_ptr, src_sorted, w_sorted, dinv, bd, N);

  // projection heads (tiny, f32 path)
  dim3 p1(256 / 64, 1), p2(128 / 64, 1), p3(64 / 64, 1);
  k_gemm<float, float, true, true><<<p1, 256, 0, stream>>>(z_g, P1w, P1b, g1, 64, 256, 512);
  k_gemm<float, float, true, true><<<p2, 256, 0, stream>>>(g1, P2w, P2b, g2, 64, 128, 256);
  k_gemm<float, float, false, true><<<p3, 256, 0, stream>>>(g2, P3w, P3b, h_g, 64, 64, 128);
  k_gemm<float, float, true, true><<<p1, 256, 0, stream>>>(zhat_g, P1w, P1b, g1, 64, 256, 512);
  k_gemm<float, float, true, true><<<p2, 256, 0, stream>>>(g1, P2w, P2b, g2, 64, 128, 256);
  k_gemm<float, float, false, true><<<p3, 256, 0, stream>>>(g2, P3w, P3b, hhat_g, 64, 64, 128);
}

// Round 4
// 803.471 us; speedup vs baseline: 2.4847x; 1.5582x over previous
//
#include <hip/hip_runtime.h>

typedef unsigned short u16;
typedef unsigned int u32;
typedef short bf16x8 __attribute__((ext_vector_type(8)));
typedef float f32x4 __attribute__((ext_vector_type(4)));

// ---------------- threefry2x32 (JAX-compatible, 20 rounds) ----------------
__host__ __device__ inline u32 rotl32(u32 x, int r) { return (x << r) | (x >> (32 - r)); }

__host__ __device__ inline void tf_r4(u32& x0, u32& x1, int r0, int r1, int r2, int r3) {
  x0 += x1; x1 = rotl32(x1, r0); x1 ^= x0;
  x0 += x1; x1 = rotl32(x1, r1); x1 ^= x0;
  x0 += x1; x1 = rotl32(x1, r2); x1 ^= x0;
  x0 += x1; x1 = rotl32(x1, r3); x1 ^= x0;
}

__host__ __device__ inline void tf2x32(u32 k0, u32 k1, u32 c0, u32 c1, u32* o0, u32* o1) {
  u32 ks2 = 0x1BD11BDAu ^ k0 ^ k1;
  u32 x0 = c0 + k0, x1 = c1 + k1;
  tf_r4(x0, x1, 13, 15, 26, 6);  x0 += k1;  x1 += ks2 + 1u;
  tf_r4(x0, x1, 17, 29, 16, 24); x0 += ks2; x1 += k0 + 2u;
  tf_r4(x0, x1, 13, 15, 26, 6);  x0 += k0;  x1 += k1 + 3u;
  tf_r4(x0, x1, 17, 29, 16, 24); x0 += k1;  x1 += ks2 + 4u;
  tf_r4(x0, x1, 13, 15, 26, 6);  x0 += ks2; x1 += k0 + 5u;
  *o0 = x0; *o1 = x1;
}

// XLA/Giles f32 erfinv
__device__ inline float erfinv_f(float x) {
  float w = -log1pf(-x * x);
  float p;
  if (w < 5.0f) {
    w -= 2.5f;
    p = 2.81022636e-08f;
    p = 3.43273939e-07f + p * w;
    p = -3.5233877e-06f + p * w;
    p = -4.39150654e-06f + p * w;
    p = 0.00021858087f + p * w;
    p = -0.00125372503f + p * w;
    p = -0.00417768164f + p * w;
    p = 0.246640727f + p * w;
    p = 1.50140941f + p * w;
  } else {
    w = sqrtf(w) - 3.0f;
    p = -0.000200214257f;
    p = 0.000100950558f + p * w;
    p = 0.00134934322f + p * w;
    p = -0.00367342844f + p * w;
    p = 0.00573950773f + p * w;
    p = -0.0076224613f + p * w;
    p = 0.00943887047f + p * w;
    p = 1.00167406f + p * w;
    p = 2.83297682f + p * w;
  }
  return p * x;
}

__device__ inline float bits2normal(u32 b) {
  float f = __uint_as_float((b >> 9) | 0x3F800000u) - 1.0f;  // [0,1)
  float u = f * 2.0f - 0.99999994f;
  u = fmaxf(u, -0.99999994f);
  return 1.41421356f * erfinv_f(u);
}

// ---------------- dtype helpers ----------------
__device__ inline float cvt(float v) { return v; }
__device__ inline float cvt(u16 v) { return __uint_as_float(((u32)v) << 16); }
__device__ inline void stor(float* p, float v) { *p = v; }
__device__ inline void stor(u16* p, float v) {
  u32 x = __float_as_uint(v);
  *p = (u16)((x + 0x7FFFu + ((x >> 16) & 1u)) >> 16);  // RTNE bf16
}
__device__ inline u16 f2b(float v) {
  u32 x = __float_as_uint(v);
  return (u16)((x + 0x7FFFu + ((x >> 16) & 1u)) >> 16);
}

// ---------------- graph preprocessing ----------------
__global__ void k_count(const int* __restrict__ ei, int* __restrict__ cnt, int E) {
  int e = blockIdx.x * blockDim.x + threadIdx.x;
  if (e < E) atomicAdd(&cnt[ei[E + e]], 1);
}

__global__ __launch_bounds__(1024) void k_scan(const int* __restrict__ cnt, int* __restrict__ row_ptr,
                                               int* __restrict__ cursor, float* __restrict__ dinv,
                                               int n, int E) {
  __shared__ int buf[1024];
  __shared__ int sbase;
  if (threadIdx.x == 0) sbase = 0;
  __syncthreads();
  for (int c0 = 0; c0 < n; c0 += 1024) {
    int i = c0 + threadIdx.x;
    int v = (i < n) ? cnt[i] : 0;
    buf[threadIdx.x] = v;
    __syncthreads();
    for (int off = 1; off < 1024; off <<= 1) {
      int t = (threadIdx.x >= off) ? buf[threadIdx.x - off] : 0;
      __syncthreads();
      buf[threadIdx.x] += t;
      __syncthreads();
    }
    int incl = buf[threadIdx.x];
    int base = sbase;
    if (i < n) {
      int excl = base + incl - v;
      row_ptr[i] = excl;
      cursor[i] = excl;
      dinv[i] = 1.0f / sqrtf((float)(v + 1));
    }
    __syncthreads();
    if (threadIdx.x == 1023) sbase = base + incl;
    __syncthreads();
  }
  if (threadIdx.x == 0) row_ptr[n] = E;
}

__global__ void k_place(const int* __restrict__ ei, int* __restrict__ cursor,
                        const float* __restrict__ dinv, int* __restrict__ src_sorted,
                        float* __restrict__ w_sorted, int E) {
  int e = blockIdx.x * blockDim.x + threadIdx.x;
  if (e < E) {
    int s = ei[e], d = ei[E + e];
    int slot = atomicAdd(&cursor[d], 1);
    src_sorted[slot] = s;
    w_sorted[slot] = dinv[s] * dinv[d];
  }
}

// ---------------- std (ddof=1) for 4 tensors ----------------
__global__ __launch_bounds__(1024) void k_std(const float* p0, int n0, const float* p1, int n1,
                                              const float* p2, int n2, const float* p3, int n3,
                                              float* __restrict__ sigma) {
  const float* p; int n;
  if (blockIdx.x == 0) { p = p0; n = n0; }
  else if (blockIdx.x == 1) { p = p1; n = n1; }
  else if (blockIdx.x == 2) { p = p2; n = n2; }
  else { p = p3; n = n3; }
  double s = 0.0, ss = 0.0;
  for (int i = threadIdx.x; i < n; i += 1024) { double v = p[i]; s += v; ss += v * v; }
  __shared__ double sh[1024];
  __shared__ double sh2[1024];
  sh[threadIdx.x] = s; sh2[threadIdx.x] = ss;
  __syncthreads();
  for (int o = 512; o > 0; o >>= 1) {
    if (threadIdx.x < o) { sh[threadIdx.x] += sh[threadIdx.x + o]; sh2[threadIdx.x] += sh2[threadIdx.x + o]; }
    __syncthreads();
  }
  if (threadIdx.x == 0) {
    double mean = sh[0] / n;
    double var = (sh2[0] - sh[0] * mean) / (double)(n - 1);
    if (var < 0.0) var = 0.0;
    sigma[blockIdx.x] = fmaxf((float)sqrt(var), 1e-6f);
  }
}

// partitionable threefry random_bits: counter (0, j) -> bits = o0 ^ o1
__global__ void k_perturb(const float* __restrict__ p, float* __restrict__ ph, int n,
                          u32 k0, u32 k1, const float* __restrict__ sigma, int sidx) {
  int j = blockIdx.x * blockDim.x + threadIdx.x;
  if (j < n) {
    u32 r0, r1;
    tf2x32(k0, k1, 0u, (u32)j, &r0, &r1);
    ph[j] = p[j] + sigma[sidx] * bits2normal(r0 ^ r1);
  }
}

// transpose f32 [K][N] -> bf16 [N][K]
__global__ void k_transpose(const float* __restrict__ in, u16* __restrict__ out, int K, int N) {
  int j = blockIdx.x * blockDim.x + threadIdx.x;
  if (j < K * N) {
    int k = j / N, n = j - k * N;
    out[(size_t)n * K + k] = f2b(in[j]);
  }
}

// ---------------- CSR aggregation: out = P @ hin (+bias) ----------------
template <typename TIN, typename TOUT, int F, bool BIAS, bool DUAL>
__global__ __launch_bounds__(256) void k_agg(const TIN* __restrict__ hin, TOUT* __restrict__ hout,
                                             u16* __restrict__ houtb,
                                             const int* __restrict__ row_ptr,
                                             const int* __restrict__ src_sorted,
                                             const float* __restrict__ w_sorted,
                                             const float* __restrict__ dinv,
                                             const float* __restrict__ bias, int n) {
  int wv = threadIdx.x >> 6, lane = threadIdx.x & 63;
  int node = blockIdx.x * 4 + wv;
  if (node >= n) return;
  constexpr int PER = F / 64;
  float acc[PER];
#pragma unroll
  for (int j = 0; j < PER; ++j) acc[j] = 0.0f;
  int s0 = row_ptr[node], s1 = row_ptr[node + 1];
  for (int s = s0; s < s1; ++s) {
    float wgt = w_sorted[s];
    int r = src_sorted[s];
    const TIN* row = hin + (size_t)r * F + lane * PER;
#pragma unroll
    for (int j = 0; j < PER; ++j) acc[j] += wgt * cvt(row[j]);
  }
  float sw = dinv[node]; sw *= sw;
  const TIN* row = hin + (size_t)node * F + lane * PER;
#pragma unroll
  for (int j = 0; j < PER; ++j) acc[j] += sw * cvt(row[j]);
  TOUT* orow = hout + (size_t)node * F + lane * PER;
#pragma unroll
  for (int j = 0; j < PER; ++j) {
    float v = acc[j];
    if (BIAS) v += bias[lane * PER + j];
    stor(&orow[j], v);
    if (DUAL) houtb[(size_t)node * F + lane * PER + j] = f2b(v);
  }
}

// ---------------- MFMA bf16 GEMM: C = act(A @ BT^T + bias) ----------------
template <bool RELU, bool BIAS, typename TC>
__global__ __launch_bounds__(256) void k_mgemm(const u16* __restrict__ A, const u16* __restrict__ BT,
                                               const float* __restrict__ bias, TC* __restrict__ C,
                                               int M, int N, int K) {
  __shared__ u16 As[128 * 64];
  __shared__ u16 Bs[128 * 64];
  const int t = threadIdx.x;
  const int w = t >> 6, lane = t & 63;
  const int brow = blockIdx.y * 128;
  const int bcol = blockIdx.x * 128;
  const int wr = w >> 1, wc = w & 1;

  f32x4 acc[4][4];
#pragma unroll
  for (int m = 0; m < 4; ++m)
#pragma unroll
    for (int n = 0; n < 4; ++n) acc[m][n] = (f32x4){0.f, 0.f, 0.f, 0.f};

  for (int kt = 0; kt < K; kt += 64) {
#pragma unroll
    for (int j = 0; j < 4; ++j) {
      int c = j * 4 + w;              // chunk 0..15 (wave-uniform)
      int li = c * 64 + lane;         // 16B unit index
      int row = li >> 3, col8 = li & 7;
      int ar = brow + row; if (ar > M - 1) ar = M - 1;
      __builtin_amdgcn_global_load_lds(
          (const __attribute__((address_space(1))) void*)(A + (size_t)ar * K + kt + col8 * 8),
          (__attribute__((address_space(3))) void*)(As + c * 512), 16, 0, 0);
      __builtin_amdgcn_global_load_lds(
          (const __attribute__((address_space(1))) void*)(BT + (size_t)(bcol + row) * K + kt + col8 * 8),
          (__attribute__((address_space(3))) void*)(Bs + c * 512), 16, 0, 0);
    }
    __syncthreads();
    bf16x8 af[4][2], bb[4][2];
#pragma unroll
    for (int kk = 0; kk < 2; ++kk) {
      int kof = kk * 32 + (lane >> 4) * 8;
#pragma unroll
      for (int m = 0; m < 4; ++m)
        af[m][kk] = *(const bf16x8*)(As + (wr * 64 + m * 16 + (lane & 15)) * 64 + kof);
#pragma unroll
      for (int n = 0; n < 4; ++n)
        bb[n][kk] = *(const bf16x8*)(Bs + (wc * 64 + n * 16 + (lane & 15)) * 64 + kof);
    }
#pragma unroll
    for (int kk = 0; kk < 2; ++kk)
#pragma unroll
      for (int m = 0; m < 4; ++m)
#pragma unroll
        for (int n = 0; n < 4; ++n)
          acc[m][n] = __builtin_amdgcn_mfma_f32_16x16x32_bf16(af[m][kk], bb[n][kk], acc[m][n], 0, 0, 0);
    __syncthreads();
  }
#pragma unroll
  for (int m = 0; m < 4; ++m) {
    int r0 = brow + wr * 64 + m * 16 + (lane >> 4) * 4;
#pragma unroll
    for (int n = 0; n < 4; ++n) {
      int col = bcol + wc * 64 + n * 16 + (lane & 15);
      float bv = BIAS ? bias[col] : 0.0f;
#pragma unroll
      for (int q = 0; q < 4; ++q) {
        int rr = r0 + q;
        if (rr < M) {
          float v = acc[m][n][q] + bv;
          if (RELU) v = fmaxf(v, 0.0f);
          stor(&C[(size_t)rr * N + col], v);
        }
      }
    }
  }
}

// ---------------- small f32 GEMM (proj heads) ----------------
template <typename TA, typename TC, bool RELU, bool BIAS>
__global__ __launch_bounds__(256) void k_gemm(const TA* __restrict__ A, const float* __restrict__ B,
                                              const float* __restrict__ bias, TC* __restrict__ C,
                                              int M, int N, int K) {
  __shared__ float As[64][17];
  __shared__ float Bs[16][65];
  const int tx = threadIdx.x & 15;
  const int ty = threadIdx.x >> 4;
  const int row0 = blockIdx.y * 64;
  const int col0 = blockIdx.x * 64;
  float acc[4][4] = {};
  for (int k0 = 0; k0 < K; k0 += 16) {
#pragma unroll
    for (int i = 0; i < 4; ++i) {
      int lin = threadIdx.x + i * 256;
      int r = lin >> 4, c = lin & 15;
      int gr = row0 + r;
      As[r][c] = (gr < M) ? cvt(A[(size_t)gr * K + k0 + c]) : 0.0f;
    }
#pragma unroll
    for (int i = 0; i < 4; ++i) {
      int lin = threadIdx.x + i * 256;
      int r = lin >> 6, c = lin & 63;
      Bs[r][c] = B[(size_t)(k0 + r) * N + col0 + c];
    }
    __syncthreads();
#pragma unroll
    for (int k = 0; k < 16; ++k) {
      float a[4], b[4];
#pragma unroll
      for (int i = 0; i < 4; ++i) a[i] = As[ty * 4 + i][k];
#pragma unroll
      for (int j = 0; j < 4; ++j) b[j] = Bs[k][tx * 4 + j];
#pragma unroll
      for (int i = 0; i < 4; ++i)
#pragma unroll
        for (int j = 0; j < 4; ++j) acc[i][j] += a[i] * b[j];
    }
    __syncthreads();
  }
#pragma unroll
  for (int i = 0; i < 4; ++i) {
    int gr = row0 + ty * 4 + i;
    if (gr < M) {
#pragma unroll
      for (int j = 0; j < 4; ++j) {
        int gc = col0 + tx * 4 + j;
        float v = acc[i][j];
        if (BIAS) v += bias[gc];
        if (RELU) v = fmaxf(v, 0.0f);
        stor(&C[(size_t)gr * N + gc], v);
      }
    }
  }
}

// ---------------- pooling: two-stage deterministic reduction ----------------
__device__ inline int lbound(const int* a, int n, int v) {
  int lo = 0, hi = n;
  while (lo < hi) { int mid = (lo + hi) >> 1; if (a[mid] < v) lo = mid + 1; else hi = mid; }
  return lo;
}

#define POOL_NCH 32

// stage 1: grid (B, NCH); each block reduces a node sub-range of graph g over 256 features
__global__ __launch_bounds__(256) void k_pool_partial(const float* __restrict__ z,
                                                      const int* __restrict__ batch,
                                                      float* __restrict__ psum, float* __restrict__ pmax,
                                                      int n) {
  int g = blockIdx.x, ch = blockIdx.y;
  __shared__ int ss, se;
  if (threadIdx.x == 0) { ss = lbound(batch, n, g); se = lbound(batch, n, g + 1); }
  __syncthreads();
  int start = ss, len = se - ss;
  int c0 = start + (int)((long long)len * ch / POOL_NCH);
  int c1 = start + (int)((long long)len * (ch + 1) / POOL_NCH);
  int f = threadIdx.x;
  float acc = 0.0f, mx = -INFINITY;
  for (int i = c0; i < c1; ++i) {
    float v = z[(size_t)i * 256 + f];
    acc += v;
    mx = fmaxf(mx, v);
  }
  size_t o = ((size_t)g * POOL_NCH + ch) * 256 + f;
  psum[o] = acc;
  pmax[o] = mx;
}

// stage 2: grid (B); reduce NCH partials in fixed order, write [mean|max] row
__global__ __launch_bounds__(256) void k_pool_final(const float* __restrict__ psum,
                                                    const float* __restrict__ pmax,
                                                    const int* __restrict__ batch,
                                                    float* __restrict__ zg, int n) {
  int g = blockIdx.x, f = threadIdx.x;
  float s = 0.0f, m = -INFINITY;
#pragma unroll 4
  for (int c = 0; c < POOL_NCH; ++c) {
    size_t o = ((size_t)g * POOL_NCH + c) * 256 + f;
    s += psum[o];
    m = fmaxf(m, pmax[o]);
  }
  __shared__ int ss, se;
  if (threadIdx.x == 0) { ss = lbound(batch, n, g); se = lbound(batch, n, g + 1); }
  __syncthreads();
  int cnt = se - ss;
  zg[(size_t)g * 512 + f] = s / fmaxf((float)cnt, 1.0f);
  zg[(size_t)g * 512 + 256 + f] = (cnt > 0) ? m : 0.0f;
}

// ---------------- launch ----------------
extern "C" void kernel_launch(void* const* d_in, const int* in_sizes, int n_in,
                              void* d_out, int out_size, void* d_ws, size_t ws_size,
                              hipStream_t stream) {
  const float* x   = (const float*)d_in[0];
  const int*   ei  = (const int*)d_in[1];
  const int*   bat = (const int*)d_in[2];
  const float* W1  = (const float*)d_in[4];
  const float* b1  = (const float*)d_in[5];
  const float* W2  = (const float*)d_in[6];
  const float* b2  = (const float*)d_in[7];
  const float* Wd  = (const float*)d_in[8];
  const float* bd  = (const float*)d_in[9];
  const float* P1w = (const float*)d_in[10];
  const float* P1b = (const float*)d_in[11];
  const float* P2w = (const float*)d_in[12];
  const float* P2b = (const float*)d_in[13];
  const float* P3w = (const float*)d_in[14];
  const float* P3b = (const float*)d_in[15];

  const int N = in_sizes[0] / 128;  // 50000
  const int E = in_sizes[1] / 2;    // 400000
  const int B = 64;

  char* w = (char*)d_ws;
  auto carve = [&](size_t bytes) -> void* {
    void* p = (void*)w;
    w += (bytes + 255) & ~(size_t)255;
    return p;
  };
  int*   cnt        = (int*)carve((size_t)N * 4);
  int*   row_ptr    = (int*)carve((size_t)(N + 1) * 4);
  int*   cursor     = (int*)carve((size_t)N * 4);
  float* dinv       = (float*)carve((size_t)N * 4);
  int*   src_sorted = (int*)carve((size_t)E * 4);
  float* w_sorted   = (float*)carve((size_t)E * 4);
  float* sigma      = (float*)carve(256);
  float* W1h        = (float*)carve((size_t)128 * 512 * 4);
  float* b1h        = (float*)carve((size_t)512 * 4);
  float* W2h        = (float*)carve((size_t)512 * 256 * 4);
  float* b2h        = (float*)carve((size_t)256 * 4);
  u16*   W1T        = (u16*)carve((size_t)128 * 512 * 2);
  u16*   W2T        = (u16*)carve((size_t)512 * 256 * 2);
  u16*   WdT        = (u16*)carve((size_t)256 * 128 * 2);
  u16*   W1hT       = (u16*)carve((size_t)128 * 512 * 2);
  u16*   W2hT       = (u16*)carve((size_t)512 * 256 * 2);
  u16*   px         = (u16*)carve((size_t)N * 128 * 2);
  u16*   z1         = (u16*)carve((size_t)N * 512 * 2);   // aliased as znb after clean L2
  u16*   y1         = (u16*)carve((size_t)N * 256 * 2);
  float* g1         = (float*)carve((size_t)64 * 256 * 4);
  float* g2         = (float*)carve((size_t)64 * 128 * 4);
  float* psum       = (float*)carve((size_t)B * POOL_NCH * 256 * 4);
  float* pmax       = (float*)carve((size_t)B * POOL_NCH * 256 * 4);
  u16*   znb        = z1;  // alias: z1 dead after clean layer-2 GEMM

  float* out       = (float*)d_out;
  float* z_node    = out;
  float* z_g       = z_node + (size_t)N * 256;
  float* zhat_node = z_g + (size_t)B * 512;
  float* zhat_g    = zhat_node + (size_t)N * 256;
  float* h_g       = zhat_g + (size_t)B * 512;
  float* hhat_g    = h_g + (size_t)B * 64;
  float* x_hat     = hhat_g + (size_t)B * 64;

  // nk = split(key(42), 4): nk[i] = threefry(key, (0, i))
  u32 nk[4][2];
  for (u32 i = 0; i < 4; ++i) tf2x32(0u, 42u, 0u, i, &nk[i][0], &nk[i][1]);

  // --- graph preprocessing ---
  hipMemsetAsync(cnt, 0, (size_t)N * 4, stream);
  k_count<<<(E + 255) / 256, 256, 0, stream>>>(ei, cnt, E);
  k_scan<<<1, 1024, 0, stream>>>(cnt, row_ptr, cursor, dinv, N, E);
  k_place<<<(E + 255) / 256, 256, 0, stream>>>(ei, cursor, dinv, src_sorted, w_sorted, E);

  // --- perturbed weights ---
  k_std<<<4, 1024, 0, stream>>>(W1, 128 * 512, b1, 512, W2, 512 * 256, b2, 256, sigma);
  k_perturb<<<(65536 + 255) / 256, 256, 0, stream>>>(W1, W1h, 128 * 512, nk[0][0], nk[0][1], sigma, 0);
  k_perturb<<<2, 256, 0, stream>>>(b1, b1h, 512, nk[1][0], nk[1][1], sigma, 1);
  k_perturb<<<(131072 + 255) / 256, 256, 0, stream>>>(W2, W2h, 512 * 256, nk[2][0], nk[2][1], sigma, 2);
  k_perturb<<<1, 256, 0, stream>>>(b2, b2h, 256, nk[3][0], nk[3][1], sigma, 3);

  // --- bf16 transposed weight panels ---
  k_transpose<<<(65536 + 255) / 256, 256, 0, stream>>>(W1, W1T, 128, 512);
  k_transpose<<<(131072 + 255) / 256, 256, 0, stream>>>(W2, W2T, 512, 256);
  k_transpose<<<(32768 + 255) / 256, 256, 0, stream>>>(Wd, WdT, 256, 128);
  k_transpose<<<(65536 + 255) / 256, 256, 0, stream>>>(W1h, W1hT, 128, 512);
  k_transpose<<<(131072 + 255) / 256, 256, 0, stream>>>(W2h, W2hT, 512, 256);

  const int aggBlocks = (N + 3) / 4;

  // px = P @ x (shared by both branches)
  k_agg<float, u16, 128, false, false><<<aggBlocks, 256, 0, stream>>>(x, px, nullptr, row_ptr, src_sorted, w_sorted, dinv, nullptr, N);

  const int MB = (N + 127) / 128;
  dim3 m512(4, MB), m256(2, MB), m128(1, MB);

  // perturbed branch first (so z1 can be reused as znb later)
  k_mgemm<true, true, u16><<<m512, 256, 0, stream>>>(px, W1hT, b1h, z1, N, 512, 128);
  k_mgemm<false, false, u16><<<m256, 256, 0, stream>>>(z1, W2hT, nullptr, y1, N, 256, 512);
  k_agg<u16, float, 256, true, false><<<aggBlocks, 256, 0, stream>>>(y1, zhat_node, nullptr, row_ptr, src_sorted, w_sorted, dinv, b2h, N);

  // clean branch
  k_mgemm<true, true, u16><<<m512, 256, 0, stream>>>(px, W1T, b1, z1, N, 512, 128);
  k_mgemm<false, false, u16><<<m256, 256, 0, stream>>>(z1, W2T, nullptr, y1, N, 256, 512);
  k_agg<u16, float, 256, true, true><<<aggBlocks, 256, 0, stream>>>(y1, z_node, znb, row_ptr, src_sorted, w_sorted, dinv, b2, N);

  // pooling (two-stage)
  dim3 pgrid(B, POOL_NCH);
  k_pool_partial<<<pgrid, 256, 0, stream>>>(z_node, bat, psum, pmax, N);
  k_pool_final<<<B, 256, 0, stream>>>(psum, pmax, bat, z_g, N);
  k_pool_partial<<<pgrid, 256, 0, stream>>>(zhat_node, bat, psum, pmax, N);
  k_pool_final<<<B, 256, 0, stream>>>(psum, pmax, bat, zhat_g, N);

  // decoder: x_hat = P @ (z_node @ Wd) + bd
  k_mgemm<false, false, u16><<<m128, 256, 0, stream>>>(znb, WdT, nullptr, y1, N, 128, 256);
  k_agg<u16, float, 128, true, false><<<aggBlocks, 256, 0, stream>>>(y1, x_hat, nullptr, row_ptr, src_sorted, w_sorted, dinv, bd, N);

  // projection heads (tiny, f32 path)
  dim3 p1(256 / 64, 1), p2(128 / 64, 1), p3(64 / 64, 1);
  k_gemm<float, float, true, true><<<p1, 256, 0, stream>>>(z_g, P1w, P1b, g1, 64, 256, 512);
  k_gemm<float, float, true, true><<<p2, 256, 0, stream>>>(g1, P2w, P2b, g2, 64, 128, 256);
  k_gemm<float, float, false, true><<<p3, 256, 0, stream>>>(g2, P3w, P3b, h_g, 64, 64, 128);
  k_gemm<float, float, true, true><<<p1, 256, 0, stream>>>(zhat_g, P1w, P1b, g1, 64, 256, 512);
  k_gemm<float, float, true, true><<<p2, 256, 0, stream>>>(g1, P2w, P2b, g2, 64, 128, 256);
  k_gemm<float, float, false, true><<<p3, 256, 0, stream>>>(g2, P3w, P3b, hhat_g, 64, 64, 128);
}

// Round 5
// 738.475 us; speedup vs baseline: 2.7034x; 1.0880x over previous
//
#include <hip/hip_runtime.h>

typedef unsigned short u16;
typedef unsigned int u32;
typedef short bf16x8 __attribute__((ext_vector_type(8)));
typedef float f32x4 __attribute__((ext_vector_type(4)));

// ---------------- threefry2x32 (JAX-compatible, 20 rounds) ----------------
__host__ __device__ inline u32 rotl32(u32 x, int r) { return (x << r) | (x >> (32 - r)); }

__host__ __device__ inline void tf_r4(u32& x0, u32& x1, int r0, int r1, int r2, int r3) {
  x0 += x1; x1 = rotl32(x1, r0); x1 ^= x0;
  x0 += x1; x1 = rotl32(x1, r1); x1 ^= x0;
  x0 += x1; x1 = rotl32(x1, r2); x1 ^= x0;
  x0 += x1; x1 = rotl32(x1, r3); x1 ^= x0;
}

__host__ __device__ inline void tf2x32(u32 k0, u32 k1, u32 c0, u32 c1, u32* o0, u32* o1) {
  u32 ks2 = 0x1BD11BDAu ^ k0 ^ k1;
  u32 x0 = c0 + k0, x1 = c1 + k1;
  tf_r4(x0, x1, 13, 15, 26, 6);  x0 += k1;  x1 += ks2 + 1u;
  tf_r4(x0, x1, 17, 29, 16, 24); x0 += ks2; x1 += k0 + 2u;
  tf_r4(x0, x1, 13, 15, 26, 6);  x0 += k0;  x1 += k1 + 3u;
  tf_r4(x0, x1, 17, 29, 16, 24); x0 += k1;  x1 += ks2 + 4u;
  tf_r4(x0, x1, 13, 15, 26, 6);  x0 += ks2; x1 += k0 + 5u;
  *o0 = x0; *o1 = x1;
}

// XLA/Giles f32 erfinv
__device__ inline float erfinv_f(float x) {
  float w = -log1pf(-x * x);
  float p;
  if (w < 5.0f) {
    w -= 2.5f;
    p = 2.81022636e-08f;
    p = 3.43273939e-07f + p * w;
    p = -3.5233877e-06f + p * w;
    p = -4.39150654e-06f + p * w;
    p = 0.00021858087f + p * w;
    p = -0.00125372503f + p * w;
    p = -0.00417768164f + p * w;
    p = 0.246640727f + p * w;
    p = 1.50140941f + p * w;
  } else {
    w = sqrtf(w) - 3.0f;
    p = -0.000200214257f;
    p = 0.000100950558f + p * w;
    p = 0.00134934322f + p * w;
    p = -0.00367342844f + p * w;
    p = 0.00573950773f + p * w;
    p = -0.0076224613f + p * w;
    p = 0.00943887047f + p * w;
    p = 1.00167406f + p * w;
    p = 2.83297682f + p * w;
  }
  return p * x;
}

__device__ inline float bits2normal(u32 b) {
  float f = __uint_as_float((b >> 9) | 0x3F800000u) - 1.0f;  // [0,1)
  float u = f * 2.0f - 0.99999994f;
  u = fmaxf(u, -0.99999994f);
  return 1.41421356f * erfinv_f(u);
}

// ---------------- dtype helpers ----------------
__device__ inline float cvt(float v) { return v; }
__device__ inline float cvt(u16 v) { return __uint_as_float(((u32)v) << 16); }
__device__ inline void stor(float* p, float v) { *p = v; }
__device__ inline void stor(u16* p, float v) {
  u32 x = __float_as_uint(v);
  *p = (u16)((x + 0x7FFFu + ((x >> 16) & 1u)) >> 16);  // RTNE bf16
}
__device__ inline u16 f2b(float v) {
  u32 x = __float_as_uint(v);
  return (u16)((x + 0x7FFFu + ((x >> 16) & 1u)) >> 16);
}

// ---------------- graph preprocessing ----------------
__global__ void k_count(const int* __restrict__ ei, int* __restrict__ cnt, int E) {
  int e = blockIdx.x * blockDim.x + threadIdx.x;
  if (e < E) atomicAdd(&cnt[ei[E + e]], 1);
}

// three-phase hierarchical exclusive scan of cnt -> row_ptr/cursor (+dinv)
__global__ __launch_bounds__(1024) void k_scan_local(const int* __restrict__ cnt,
                                                     int* __restrict__ incl, int* __restrict__ bsum,
                                                     int n) {
  __shared__ int buf[1024];
  int i = blockIdx.x * 1024 + threadIdx.x;
  int v = (i < n) ? cnt[i] : 0;
  buf[threadIdx.x] = v;
  __syncthreads();
  for (int off = 1; off < 1024; off <<= 1) {
    int t = (threadIdx.x >= off) ? buf[threadIdx.x - off] : 0;
    __syncthreads();
    buf[threadIdx.x] += t;
    __syncthreads();
  }
  if (i < n) incl[i] = buf[threadIdx.x];
  if (threadIdx.x == 1023) bsum[blockIdx.x] = buf[1023];
}

__global__ __launch_bounds__(1024) void k_scan_bsum(int* __restrict__ bsum, int nb) {
  __shared__ int buf[1024];
  int v = (threadIdx.x < nb) ? bsum[threadIdx.x] : 0;
  buf[threadIdx.x] = v;
  __syncthreads();
  for (int off = 1; off < 1024; off <<= 1) {
    int t = (threadIdx.x >= off) ? buf[threadIdx.x - off] : 0;
    __syncthreads();
    buf[threadIdx.x] += t;
    __syncthreads();
  }
  if (threadIdx.x < nb) bsum[threadIdx.x] = buf[threadIdx.x] - v;  // exclusive
}

__global__ __launch_bounds__(1024) void k_scan_final(const int* __restrict__ cnt,
                                                     const int* __restrict__ incl,
                                                     const int* __restrict__ bsum,
                                                     int* __restrict__ row_ptr, int* __restrict__ cursor,
                                                     float* __restrict__ dinv, int n, int E) {
  int i = blockIdx.x * 1024 + threadIdx.x;
  if (i < n) {
    int c = cnt[i];
    int ex = incl[i] + bsum[blockIdx.x] - c;
    row_ptr[i] = ex;
    cursor[i] = ex;
    dinv[i] = 1.0f / sqrtf((float)(c + 1));  // deg includes self-loop
  }
  if (i == 0) row_ptr[n] = E;
}

__global__ void k_place(const int* __restrict__ ei, int* __restrict__ cursor,
                        const float* __restrict__ dinv, int* __restrict__ src_sorted,
                        float* __restrict__ w_sorted, int E) {
  int e = blockIdx.x * blockDim.x + threadIdx.x;
  if (e < E) {
    int s = ei[e], d = ei[E + e];
    int slot = atomicAdd(&cursor[d], 1);
    src_sorted[slot] = s;
    w_sorted[slot] = dinv[s] * dinv[d];
  }
}

// ---------------- std (ddof=1) for 4 tensors ----------------
__global__ __launch_bounds__(1024) void k_std(const float* p0, int n0, const float* p1, int n1,
                                              const float* p2, int n2, const float* p3, int n3,
                                              float* __restrict__ sigma) {
  const float* p; int n;
  if (blockIdx.x == 0) { p = p0; n = n0; }
  else if (blockIdx.x == 1) { p = p1; n = n1; }
  else if (blockIdx.x == 2) { p = p2; n = n2; }
  else { p = p3; n = n3; }
  double s = 0.0, ss = 0.0;
  for (int i = threadIdx.x; i < n; i += 1024) { double v = p[i]; s += v; ss += v * v; }
  __shared__ double sh[1024];
  __shared__ double sh2[1024];
  sh[threadIdx.x] = s; sh2[threadIdx.x] = ss;
  __syncthreads();
  for (int o = 512; o > 0; o >>= 1) {
    if (threadIdx.x < o) { sh[threadIdx.x] += sh[threadIdx.x + o]; sh2[threadIdx.x] += sh2[threadIdx.x + o]; }
    __syncthreads();
  }
  if (threadIdx.x == 0) {
    double mean = sh[0] / n;
    double var = (sh2[0] - sh[0] * mean) / (double)(n - 1);
    if (var < 0.0) var = 0.0;
    sigma[blockIdx.x] = fmaxf((float)sqrt(var), 1e-6f);
  }
}

// partitionable threefry random_bits: counter (0, j) -> bits = o0 ^ o1
__global__ void k_perturb(const float* __restrict__ p, float* __restrict__ ph, int n,
                          u32 k0, u32 k1, const float* __restrict__ sigma, int sidx) {
  int j = blockIdx.x * blockDim.x + threadIdx.x;
  if (j < n) {
    u32 r0, r1;
    tf2x32(k0, k1, 0u, (u32)j, &r0, &r1);
    ph[j] = p[j] + sigma[sidx] * bits2normal(r0 ^ r1);
  }
}

// transpose f32 [K][N] -> bf16 [N][K]
__global__ void k_transpose(const float* __restrict__ in, u16* __restrict__ out, int K, int N) {
  int j = blockIdx.x * blockDim.x + threadIdx.x;
  if (j < K * N) {
    int k = j / N, n = j - k * N;
    out[(size_t)n * K + k] = f2b(in[j]);
  }
}

// ---------------- CSR aggregation: out = P @ hin (+bias) ----------------
template <typename TIN, typename TOUT, int F, bool BIAS, bool DUAL>
__global__ __launch_bounds__(256) void k_agg(const TIN* __restrict__ hin, TOUT* __restrict__ hout,
                                             u16* __restrict__ houtb,
                                             const int* __restrict__ row_ptr,
                                             const int* __restrict__ src_sorted,
                                             const float* __restrict__ w_sorted,
                                             const float* __restrict__ dinv,
                                             const float* __restrict__ bias, int n) {
  int wv = threadIdx.x >> 6, lane = threadIdx.x & 63;
  int node = blockIdx.x * 4 + wv;
  if (node >= n) return;
  constexpr int PER = F / 64;
  float acc[PER];
#pragma unroll
  for (int j = 0; j < PER; ++j) acc[j] = 0.0f;
  int s0 = row_ptr[node], s1 = row_ptr[node + 1];
  for (int s = s0; s < s1; ++s) {
    float wgt = w_sorted[s];
    int r = src_sorted[s];
    const TIN* row = hin + (size_t)r * F + lane * PER;
#pragma unroll
    for (int j = 0; j < PER; ++j) acc[j] += wgt * cvt(row[j]);
  }
  float sw = dinv[node]; sw *= sw;
  const TIN* row = hin + (size_t)node * F + lane * PER;
#pragma unroll
  for (int j = 0; j < PER; ++j) acc[j] += sw * cvt(row[j]);
  TOUT* orow = hout + (size_t)node * F + lane * PER;
#pragma unroll
  for (int j = 0; j < PER; ++j) {
    float v = acc[j];
    if (BIAS) v += bias[lane * PER + j];
    stor(&orow[j], v);
    if (DUAL) houtb[(size_t)node * F + lane * PER + j] = f2b(v);
  }
}

// ---------------- MFMA bf16 GEMM: C = act(A @ BT^T + bias) ----------------
template <bool RELU, bool BIAS, typename TC>
__global__ __launch_bounds__(256) void k_mgemm(const u16* __restrict__ A, const u16* __restrict__ BT,
                                               const float* __restrict__ bias, TC* __restrict__ C,
                                               int M, int N, int K) {
  __shared__ u16 As[128 * 64];
  __shared__ u16 Bs[128 * 64];
  const int t = threadIdx.x;
  const int w = t >> 6, lane = t & 63;
  const int brow = blockIdx.y * 128;
  const int bcol = blockIdx.x * 128;
  const int wr = w >> 1, wc = w & 1;

  f32x4 acc[4][4];
#pragma unroll
  for (int m = 0; m < 4; ++m)
#pragma unroll
    for (int n = 0; n < 4; ++n) acc[m][n] = (f32x4){0.f, 0.f, 0.f, 0.f};

  for (int kt = 0; kt < K; kt += 64) {
#pragma unroll
    for (int j = 0; j < 4; ++j) {
      int c = j * 4 + w;              // chunk 0..15 (wave-uniform)
      int li = c * 64 + lane;         // 16B unit index
      int row = li >> 3, col8 = li & 7;
      int ar = brow + row; if (ar > M - 1) ar = M - 1;
      __builtin_amdgcn_global_load_lds(
          (const __attribute__((address_space(1))) void*)(A + (size_t)ar * K + kt + col8 * 8),
          (__attribute__((address_space(3))) void*)(As + c * 512), 16, 0, 0);
      __builtin_amdgcn_global_load_lds(
          (const __attribute__((address_space(1))) void*)(BT + (size_t)(bcol + row) * K + kt + col8 * 8),
          (__attribute__((address_space(3))) void*)(Bs + c * 512), 16, 0, 0);
    }
    __syncthreads();
    bf16x8 af[4][2], bb[4][2];
#pragma unroll
    for (int kk = 0; kk < 2; ++kk) {
      int kof = kk * 32 + (lane >> 4) * 8;
#pragma unroll
      for (int m = 0; m < 4; ++m)
        af[m][kk] = *(const bf16x8*)(As + (wr * 64 + m * 16 + (lane & 15)) * 64 + kof);
#pragma unroll
      for (int n = 0; n < 4; ++n)
        bb[n][kk] = *(const bf16x8*)(Bs + (wc * 64 + n * 16 + (lane & 15)) * 64 + kof);
    }
#pragma unroll
    for (int kk = 0; kk < 2; ++kk)
#pragma unroll
      for (int m = 0; m < 4; ++m)
#pragma unroll
        for (int n = 0; n < 4; ++n)
          acc[m][n] = __builtin_amdgcn_mfma_f32_16x16x32_bf16(af[m][kk], bb[n][kk], acc[m][n], 0, 0, 0);
    __syncthreads();
  }
#pragma unroll
  for (int m = 0; m < 4; ++m) {
    int r0 = brow + wr * 64 + m * 16 + (lane >> 4) * 4;
#pragma unroll
    for (int n = 0; n < 4; ++n) {
      int col = bcol + wc * 64 + n * 16 + (lane & 15);
      float bv = BIAS ? bias[col] : 0.0f;
#pragma unroll
      for (int q = 0; q < 4; ++q) {
        int rr = r0 + q;
        if (rr < M) {
          float v = acc[m][n][q] + bv;
          if (RELU) v = fmaxf(v, 0.0f);
          stor(&C[(size_t)rr * N + col], v);
        }
      }
    }
  }
}

// ---------------- small f32 GEMM (proj heads) ----------------
template <typename TA, typename TC, bool RELU, bool BIAS>
__global__ __launch_bounds__(256) void k_gemm(const TA* __restrict__ A, const float* __restrict__ B,
                                              const float* __restrict__ bias, TC* __restrict__ C,
                                              int M, int N, int K) {
  __shared__ float As[64][17];
  __shared__ float Bs[16][65];
  const int tx = threadIdx.x & 15;
  const int ty = threadIdx.x >> 4;
  const int row0 = blockIdx.y * 64;
  const int col0 = blockIdx.x * 64;
  float acc[4][4] = {};
  for (int k0 = 0; k0 < K; k0 += 16) {
#pragma unroll
    for (int i = 0; i < 4; ++i) {
      int lin = threadIdx.x + i * 256;
      int r = lin >> 4, c = lin & 15;
      int gr = row0 + r;
      As[r][c] = (gr < M) ? cvt(A[(size_t)gr * K + k0 + c]) : 0.0f;
    }
#pragma unroll
    for (int i = 0; i < 4; ++i) {
      int lin = threadIdx.x + i * 256;
      int r = lin >> 6, c = lin & 63;
      Bs[r][c] = B[(size_t)(k0 + r) * N + col0 + c];
    }
    __syncthreads();
#pragma unroll
    for (int k = 0; k < 16; ++k) {
      float a[4], b[4];
#pragma unroll
      for (int i = 0; i < 4; ++i) a[i] = As[ty * 4 + i][k];
#pragma unroll
      for (int j = 0; j < 4; ++j) b[j] = Bs[k][tx * 4 + j];
#pragma unroll
      for (int i = 0; i < 4; ++i)
#pragma unroll
        for (int j = 0; j < 4; ++j) acc[i][j] += a[i] * b[j];
    }
    __syncthreads();
  }
#pragma unroll
  for (int i = 0; i < 4; ++i) {
    int gr = row0 + ty * 4 + i;
    if (gr < M) {
#pragma unroll
      for (int j = 0; j < 4; ++j) {
        int gc = col0 + tx * 4 + j;
        float v = acc[i][j];
        if (BIAS) v += bias[gc];
        if (RELU) v = fmaxf(v, 0.0f);
        stor(&C[(size_t)gr * N + gc], v);
      }
    }
  }
}

// ---------------- pooling: two-stage deterministic reduction ----------------
__device__ inline int lbound(const int* a, int n, int v) {
  int lo = 0, hi = n;
  while (lo < hi) { int mid = (lo + hi) >> 1; if (a[mid] < v) lo = mid + 1; else hi = mid; }
  return lo;
}

#define POOL_NCH 32

__global__ __launch_bounds__(256) void k_pool_partial(const float* __restrict__ z,
                                                      const int* __restrict__ batch,
                                                      float* __restrict__ psum, float* __restrict__ pmax,
                                                      int n) {
  int g = blockIdx.x, ch = blockIdx.y;
  __shared__ int ss, se;
  if (threadIdx.x == 0) { ss = lbound(batch, n, g); se = lbound(batch, n, g + 1); }
  __syncthreads();
  int start = ss, len = se - ss;
  int c0 = start + (int)((long long)len * ch / POOL_NCH);
  int c1 = start + (int)((long long)len * (ch + 1) / POOL_NCH);
  int f = threadIdx.x;
  float acc = 0.0f, mx = -INFINITY;
  for (int i = c0; i < c1; ++i) {
    float v = z[(size_t)i * 256 + f];
    acc += v;
    mx = fmaxf(mx, v);
  }
  size_t o = ((size_t)g * POOL_NCH + ch) * 256 + f;
  psum[o] = acc;
  pmax[o] = mx;
}

__global__ __launch_bounds__(256) void k_pool_final(const float* __restrict__ psum,
                                                    const float* __restrict__ pmax,
                                                    const int* __restrict__ batch,
                                                    float* __restrict__ zg, int n) {
  int g = blockIdx.x, f = threadIdx.x;
  float s = 0.0f, m = -INFINITY;
#pragma unroll 4
  for (int c = 0; c < POOL_NCH; ++c) {
    size_t o = ((size_t)g * POOL_NCH + c) * 256 + f;
    s += psum[o];
    m = fmaxf(m, pmax[o]);
  }
  __shared__ int ss, se;
  if (threadIdx.x == 0) { ss = lbound(batch, n, g); se = lbound(batch, n, g + 1); }
  __syncthreads();
  int cnt = se - ss;
  zg[(size_t)g * 512 + f] = s / fmaxf((float)cnt, 1.0f);
  zg[(size_t)g * 512 + 256 + f] = (cnt > 0) ? m : 0.0f;
}

// ---------------- launch ----------------
extern "C" void kernel_launch(void* const* d_in, const int* in_sizes, int n_in,
                              void* d_out, int out_size, void* d_ws, size_t ws_size,
                              hipStream_t stream) {
  const float* x   = (const float*)d_in[0];
  const int*   ei  = (const int*)d_in[1];
  const int*   bat = (const int*)d_in[2];
  const float* W1  = (const float*)d_in[4];
  const float* b1  = (const float*)d_in[5];
  const float* W2  = (const float*)d_in[6];
  const float* b2  = (const float*)d_in[7];
  const float* Wd  = (const float*)d_in[8];
  const float* bd  = (const float*)d_in[9];
  const float* P1w = (const float*)d_in[10];
  const float* P1b = (const float*)d_in[11];
  const float* P2w = (const float*)d_in[12];
  const float* P2b = (const float*)d_in[13];
  const float* P3w = (const float*)d_in[14];
  const float* P3b = (const float*)d_in[15];

  const int N = in_sizes[0] / 128;  // 50000
  const int E = in_sizes[1] / 2;    // 400000
  const int B = 64;
  const int NB = (N + 1023) / 1024; // scan blocks

  char* w = (char*)d_ws;
  auto carve = [&](size_t bytes) -> void* {
    void* p = (void*)w;
    w += (bytes + 255) & ~(size_t)255;
    return p;
  };
  int*   cnt        = (int*)carve((size_t)N * 4);
  int*   row_ptr    = (int*)carve((size_t)(N + 1) * 4);
  int*   cursor     = (int*)carve((size_t)N * 4);
  float* dinv       = (float*)carve((size_t)N * 4);
  int*   incl       = (int*)carve((size_t)N * 4);
  int*   bsum       = (int*)carve((size_t)1024 * 4);
  int*   src_sorted = (int*)carve((size_t)E * 4);
  float* w_sorted   = (float*)carve((size_t)E * 4);
  float* sigma      = (float*)carve(256);
  float* W1h        = (float*)carve((size_t)128 * 512 * 4);
  float* b1h        = (float*)carve((size_t)512 * 4);
  float* W2h        = (float*)carve((size_t)512 * 256 * 4);
  float* b2h        = (float*)carve((size_t)256 * 4);
  u16*   W1T        = (u16*)carve((size_t)128 * 512 * 2);
  u16*   W2T        = (u16*)carve((size_t)512 * 256 * 2);
  u16*   WdT        = (u16*)carve((size_t)256 * 128 * 2);
  u16*   W1hT       = (u16*)carve((size_t)128 * 512 * 2);
  u16*   W2hT       = (u16*)carve((size_t)512 * 256 * 2);
  u16*   px         = (u16*)carve((size_t)N * 128 * 2);
  u16*   z1         = (u16*)carve((size_t)N * 512 * 2);   // aliased as znb after clean L2
  u16*   y1         = (u16*)carve((size_t)N * 256 * 2);
  float* g1         = (float*)carve((size_t)64 * 256 * 4);
  float* g2         = (float*)carve((size_t)64 * 128 * 4);
  float* psum       = (float*)carve((size_t)B * POOL_NCH * 256 * 4);
  float* pmax       = (float*)carve((size_t)B * POOL_NCH * 256 * 4);
  u16*   znb        = z1;  // alias: z1 dead after clean layer-2 GEMM

  float* out       = (float*)d_out;
  float* z_node    = out;
  float* z_g       = z_node + (size_t)N * 256;
  float* zhat_node = z_g + (size_t)B * 512;
  float* zhat_g    = zhat_node + (size_t)N * 256;
  float* h_g       = zhat_g + (size_t)B * 512;
  float* hhat_g    = h_g + (size_t)B * 64;
  float* x_hat     = hhat_g + (size_t)B * 64;

  // nk = split(key(42), 4): nk[i] = threefry(key, (0, i))
  u32 nk[4][2];
  for (u32 i = 0; i < 4; ++i) tf2x32(0u, 42u, 0u, i, &nk[i][0], &nk[i][1]);

  // --- graph preprocessing ---
  hipMemsetAsync(cnt, 0, (size_t)N * 4, stream);
  k_count<<<(E + 255) / 256, 256, 0, stream>>>(ei, cnt, E);
  k_scan_local<<<NB, 1024, 0, stream>>>(cnt, incl, bsum, N);
  k_scan_bsum<<<1, 1024, 0, stream>>>(bsum, NB);
  k_scan_final<<<NB, 1024, 0, stream>>>(cnt, incl, bsum, row_ptr, cursor, dinv, N, E);
  k_place<<<(E + 255) / 256, 256, 0, stream>>>(ei, cursor, dinv, src_sorted, w_sorted, E);

  // --- perturbed weights ---
  k_std<<<4, 1024, 0, stream>>>(W1, 128 * 512, b1, 512, W2, 512 * 256, b2, 256, sigma);
  k_perturb<<<(65536 + 255) / 256, 256, 0, stream>>>(W1, W1h, 128 * 512, nk[0][0], nk[0][1], sigma, 0);
  k_perturb<<<2, 256, 0, stream>>>(b1, b1h, 512, nk[1][0], nk[1][1], sigma, 1);
  k_perturb<<<(131072 + 255) / 256, 256, 0, stream>>>(W2, W2h, 512 * 256, nk[2][0], nk[2][1], sigma, 2);
  k_perturb<<<1, 256, 0, stream>>>(b2, b2h, 256, nk[3][0], nk[3][1], sigma, 3);

  // --- bf16 transposed weight panels ---
  k_transpose<<<(65536 + 255) / 256, 256, 0, stream>>>(W1, W1T, 128, 512);
  k_transpose<<<(131072 + 255) / 256, 256, 0, stream>>>(W2, W2T, 512, 256);
  k_transpose<<<(32768 + 255) / 256, 256, 0, stream>>>(Wd, WdT, 256, 128);
  k_transpose<<<(65536 + 255) / 256, 256, 0, stream>>>(W1h, W1hT, 128, 512);
  k_transpose<<<(131072 + 255) / 256, 256, 0, stream>>>(W2h, W2hT, 512, 256);

  const int aggBlocks = (N + 3) / 4;

  // px = P @ x (shared by both branches)
  k_agg<float, u16, 128, false, false><<<aggBlocks, 256, 0, stream>>>(x, px, nullptr, row_ptr, src_sorted, w_sorted, dinv, nullptr, N);

  const int MB = (N + 127) / 128;
  dim3 m512(4, MB), m256(2, MB), m128(1, MB);

  // perturbed branch first (so z1 can be reused as znb later)
  k_mgemm<true, true, u16><<<m512, 256, 0, stream>>>(px, W1hT, b1h, z1, N, 512, 128);
  k_mgemm<false, false, u16><<<m256, 256, 0, stream>>>(z1, W2hT, nullptr, y1, N, 256, 512);
  k_agg<u16, float, 256, true, false><<<aggBlocks, 256, 0, stream>>>(y1, zhat_node, nullptr, row_ptr, src_sorted, w_sorted, dinv, b2h, N);

  // clean branch
  k_mgemm<true, true, u16><<<m512, 256, 0, stream>>>(px, W1T, b1, z1, N, 512, 128);
  k_mgemm<false, false, u16><<<m256, 256, 0, stream>>>(z1, W2T, nullptr, y1, N, 256, 512);
  k_agg<u16, float, 256, true, true><<<aggBlocks, 256, 0, stream>>>(y1, z_node, znb, row_ptr, src_sorted, w_sorted, dinv, b2, N);

  // pooling (two-stage)
  dim3 pgrid(B, POOL_NCH);
  k_pool_partial<<<pgrid, 256, 0, stream>>>(z_node, bat, psum, pmax, N);
  k_pool_final<<<B, 256, 0, stream>>>(psum, pmax, bat, z_g, N);
  k_pool_partial<<<pgrid, 256, 0, stream>>>(zhat_node, bat, psum, pmax, N);
  k_pool_final<<<B, 256, 0, stream>>>(psum, pmax, bat, zhat_g, N);

  // decoder: x_hat = P @ (z_node @ Wd) + bd
  k_mgemm<false, false, u16><<<m128, 256, 0, stream>>>(znb, WdT, nullptr, y1, N, 128, 256);
  k_agg<u16, float, 128, true, false><<<aggBlocks, 256, 0, stream>>>(y1, x_hat, nullptr, row_ptr, src_sorted, w_sorted, dinv, bd, N);

  // projection heads (tiny, f32 path)
  dim3 p1(256 / 64, 1), p2(128 / 64, 1), p3(64 / 64, 1);
  k_gemm<float, float, true, true><<<p1, 256, 0, stream>>>(z_g, P1w, P1b, g1, 64, 256, 512);
  k_gemm<float, float, true, true><<<p2, 256, 0, stream>>>(g1, P2w, P2b, g2, 64, 128, 256);
  k_gemm<float, float, false, true><<<p3, 256, 0, stream>>>(g2, P3w, P3b, h_g, 64, 64, 128);
  k_gemm<float, float, true, true><<<p1, 256, 0, stream>>>(zhat_g, P1w, P1b, g1, 64, 256, 512);
  k_gemm<float, float, true, true><<<p2, 256, 0, stream>>>(g1, P2w, P2b, g2, 64, 128, 256);
  k_gemm<float, float, false, true><<<p3, 256, 0, stream>>>(g2, P3w, P3b, hhat_g, 64, 64, 128);
}

// Round 6
// 610.981 us; speedup vs baseline: 3.2675x; 1.2087x over previous
//
#include <hip/hip_runtime.h>

typedef unsigned short u16;
typedef unsigned int u32;
typedef short bf16x8 __attribute__((ext_vector_type(8)));
typedef float f32x4 __attribute__((ext_vector_type(4)));

// ---------------- threefry2x32 (JAX-compatible, 20 rounds) ----------------
__host__ __device__ inline u32 rotl32(u32 x, int r) { return (x << r) | (x >> (32 - r)); }

__host__ __device__ inline void tf_r4(u32& x0, u32& x1, int r0, int r1, int r2, int r3) {
  x0 += x1; x1 = rotl32(x1, r0); x1 ^= x0;
  x0 += x1; x1 = rotl32(x1, r1); x1 ^= x0;
  x0 += x1; x1 = rotl32(x1, r2); x1 ^= x0;
  x0 += x1; x1 = rotl32(x1, r3); x1 ^= x0;
}

__host__ __device__ inline void tf2x32(u32 k0, u32 k1, u32 c0, u32 c1, u32* o0, u32* o1) {
  u32 ks2 = 0x1BD11BDAu ^ k0 ^ k1;
  u32 x0 = c0 + k0, x1 = c1 + k1;
  tf_r4(x0, x1, 13, 15, 26, 6);  x0 += k1;  x1 += ks2 + 1u;
  tf_r4(x0, x1, 17, 29, 16, 24); x0 += ks2; x1 += k0 + 2u;
  tf_r4(x0, x1, 13, 15, 26, 6);  x0 += k0;  x1 += k1 + 3u;
  tf_r4(x0, x1, 17, 29, 16, 24); x0 += k1;  x1 += ks2 + 4u;
  tf_r4(x0, x1, 13, 15, 26, 6);  x0 += ks2; x1 += k0 + 5u;
  *o0 = x0; *o1 = x1;
}

// XLA/Giles f32 erfinv
__device__ inline float erfinv_f(float x) {
  float w = -log1pf(-x * x);
  float p;
  if (w < 5.0f) {
    w -= 2.5f;
    p = 2.81022636e-08f;
    p = 3.43273939e-07f + p * w;
    p = -3.5233877e-06f + p * w;
    p = -4.39150654e-06f + p * w;
    p = 0.00021858087f + p * w;
    p = -0.00125372503f + p * w;
    p = -0.00417768164f + p * w;
    p = 0.246640727f + p * w;
    p = 1.50140941f + p * w;
  } else {
    w = sqrtf(w) - 3.0f;
    p = -0.000200214257f;
    p = 0.000100950558f + p * w;
    p = 0.00134934322f + p * w;
    p = -0.00367342844f + p * w;
    p = 0.00573950773f + p * w;
    p = -0.0076224613f + p * w;
    p = 0.00943887047f + p * w;
    p = 1.00167406f + p * w;
    p = 2.83297682f + p * w;
  }
  return p * x;
}

__device__ inline float bits2normal(u32 b) {
  float f = __uint_as_float((b >> 9) | 0x3F800000u) - 1.0f;  // [0,1)
  float u = f * 2.0f - 0.99999994f;
  u = fmaxf(u, -0.99999994f);
  return 1.41421356f * erfinv_f(u);
}

// ---------------- dtype helpers ----------------
__device__ inline float cvt(float v) { return v; }
__device__ inline float cvt(u16 v) { return __uint_as_float(((u32)v) << 16); }
__device__ inline void stor(float* p, float v) { *p = v; }
__device__ inline void stor(u16* p, float v) {
  u32 x = __float_as_uint(v);
  *p = (u16)((x + 0x7FFFu + ((x >> 16) & 1u)) >> 16);  // RTNE bf16
}
__device__ inline u16 f2b(float v) {
  u32 x = __float_as_uint(v);
  return (u16)((x + 0x7FFFu + ((x >> 16) & 1u)) >> 16);
}
__device__ inline float blo(u32 w) { return __uint_as_float(w << 16); }
__device__ inline float bhi(u32 w) { return __uint_as_float(w & 0xFFFF0000u); }

// ---------------- graph preprocessing ----------------
__global__ void k_count(const int* __restrict__ ei, int* __restrict__ cnt, int E) {
  int e = blockIdx.x * blockDim.x + threadIdx.x;
  if (e < E) atomicAdd(&cnt[ei[E + e]], 1);
}

__global__ __launch_bounds__(1024) void k_scan_local(const int* __restrict__ cnt,
                                                     int* __restrict__ incl, int* __restrict__ bsum,
                                                     int n) {
  __shared__ int buf[1024];
  int i = blockIdx.x * 1024 + threadIdx.x;
  int v = (i < n) ? cnt[i] : 0;
  buf[threadIdx.x] = v;
  __syncthreads();
  for (int off = 1; off < 1024; off <<= 1) {
    int t = (threadIdx.x >= off) ? buf[threadIdx.x - off] : 0;
    __syncthreads();
    buf[threadIdx.x] += t;
    __syncthreads();
  }
  if (i < n) incl[i] = buf[threadIdx.x];
  if (threadIdx.x == 1023) bsum[blockIdx.x] = buf[1023];
}

__global__ __launch_bounds__(1024) void k_scan_bsum(int* __restrict__ bsum, int nb) {
  __shared__ int buf[1024];
  int v = (threadIdx.x < nb) ? bsum[threadIdx.x] : 0;
  buf[threadIdx.x] = v;
  __syncthreads();
  for (int off = 1; off < 1024; off <<= 1) {
    int t = (threadIdx.x >= off) ? buf[threadIdx.x - off] : 0;
    __syncthreads();
    buf[threadIdx.x] += t;
    __syncthreads();
  }
  if (threadIdx.x < nb) bsum[threadIdx.x] = buf[threadIdx.x] - v;  // exclusive
}

__global__ __launch_bounds__(1024) void k_scan_final(const int* __restrict__ cnt,
                                                     const int* __restrict__ incl,
                                                     const int* __restrict__ bsum,
                                                     int* __restrict__ row_ptr, int* __restrict__ cursor,
                                                     float* __restrict__ dinv, int n, int E) {
  int i = blockIdx.x * 1024 + threadIdx.x;
  if (i < n) {
    int c = cnt[i];
    int ex = incl[i] + bsum[blockIdx.x] - c;
    row_ptr[i] = ex;
    cursor[i] = ex;
    dinv[i] = 1.0f / sqrtf((float)(c + 1));  // deg includes self-loop
  }
  if (i == 0) row_ptr[n] = E;
}

__global__ void k_place(const int* __restrict__ ei, int* __restrict__ cursor,
                        const float* __restrict__ dinv, int* __restrict__ src_sorted,
                        float* __restrict__ w_sorted, int E) {
  int e = blockIdx.x * blockDim.x + threadIdx.x;
  if (e < E) {
    int s = ei[e], d = ei[E + e];
    int slot = atomicAdd(&cursor[d], 1);
    src_sorted[slot] = s;
    w_sorted[slot] = dinv[s] * dinv[d];
  }
}

// ---------------- std (ddof=1), two-stage ----------------
__global__ __launch_bounds__(256) void k_std1(const float* p0, int n0, const float* p1, int n1,
                                              const float* p2, int n2, const float* p3, int n3,
                                              double* __restrict__ psd) {
  int t = blockIdx.x >> 4, ch = blockIdx.x & 15;
  const float* p; int n;
  if (t == 0) { p = p0; n = n0; }
  else if (t == 1) { p = p1; n = n1; }
  else if (t == 2) { p = p2; n = n2; }
  else { p = p3; n = n3; }
  int c0 = (int)((long long)n * ch / 16), c1 = (int)((long long)n * (ch + 1) / 16);
  double s = 0.0, ss = 0.0;
  for (int i = c0 + threadIdx.x; i < c1; i += 256) { double v = p[i]; s += v; ss += v * v; }
  __shared__ double sh[256];
  __shared__ double sh2[256];
  sh[threadIdx.x] = s; sh2[threadIdx.x] = ss;
  __syncthreads();
  for (int o = 128; o > 0; o >>= 1) {
    if (threadIdx.x < o) { sh[threadIdx.x] += sh[threadIdx.x + o]; sh2[threadIdx.x] += sh2[threadIdx.x + o]; }
    __syncthreads();
  }
  if (threadIdx.x == 0) { psd[blockIdx.x * 2] = sh[0]; psd[blockIdx.x * 2 + 1] = sh2[0]; }
}

__global__ void k_std2(const double* __restrict__ psd, int n0, int n1, int n2, int n3,
                       float* __restrict__ sigma) {
  int l = threadIdx.x;  // 64 lanes
  double s = psd[l * 2], ss = psd[l * 2 + 1];
  for (int off = 1; off < 16; off <<= 1) { s += __shfl_xor(s, off); ss += __shfl_xor(ss, off); }
  if ((l & 15) == 0) {
    int t = l >> 4;
    int n = (t == 0) ? n0 : (t == 1) ? n1 : (t == 2) ? n2 : n3;
    double mean = s / n;
    double var = (ss - s * mean) / (double)(n - 1);
    if (var < 0.0) var = 0.0;
    sigma[t] = fmaxf((float)sqrt(var), 1e-6f);
  }
}

// partitionable threefry random_bits: counter (0, j) -> bits = o0 ^ o1
__global__ void k_perturb(const float* __restrict__ p, float* __restrict__ ph, int n,
                          u32 k0, u32 k1, const float* __restrict__ sigma, int sidx) {
  int j = blockIdx.x * blockDim.x + threadIdx.x;
  if (j < n) {
    u32 r0, r1;
    tf2x32(k0, k1, 0u, (u32)j, &r0, &r1);
    ph[j] = p[j] + sigma[sidx] * bits2normal(r0 ^ r1);
  }
}

// transpose f32 [K][N] -> bf16 [N][K]
__global__ void k_transpose(const float* __restrict__ in, u16* __restrict__ out, int K, int N) {
  int j = blockIdx.x * blockDim.x + threadIdx.x;
  if (j < K * N) {
    int k = j / N, n = j - k * N;
    out[(size_t)n * K + k] = f2b(in[j]);
  }
}

__global__ void k_bcat(const float* __restrict__ b2, const float* __restrict__ b2h,
                       float* __restrict__ bcat) {
  int i = threadIdx.x;  // 512 threads
  bcat[i] = (i < 256) ? b2[i] : b2h[i - 256];
}

// ---------------- CSR aggregations (vectorized) ----------------
// px = P @ x : x f32 [N][128] -> px bf16 [N][128]; float2 per lane
__global__ __launch_bounds__(256) void k_agg_px(const float* __restrict__ x, u16* __restrict__ px,
                                                const int* __restrict__ rp, const int* __restrict__ src,
                                                const float* __restrict__ wst, const float* __restrict__ dinv,
                                                int n) {
  int wv = threadIdx.x >> 6, lane = threadIdx.x & 63;
  int node = blockIdx.x * 4 + wv;
  if (node >= n) return;
  float a0 = 0.f, a1 = 0.f;
  int s0 = rp[node], s1 = rp[node + 1];
  for (int s = s0; s < s1; ++s) {
    float wgt = wst[s];
    int r = src[s];
    float2 v = *((const float2*)(x + (size_t)r * 128) + lane);
    a0 += wgt * v.x; a1 += wgt * v.y;
  }
  float sw = dinv[node]; sw *= sw;
  float2 v = *((const float2*)(x + (size_t)node * 128) + lane);
  a0 += sw * v.x; a1 += sw * v.y;
  u32 w = ((u32)f2b(a0)) | (((u32)f2b(a1)) << 16);
  *((u32*)(px + (size_t)node * 128) + lane) = w;
}

// merged layer-2 agg: ycat bf16 [N][512] = [y_clean | y_pert];
// lanes 0-31 -> z_node f32 + znb bf16; lanes 32-63 -> zhat_node f32. uint4 per lane.
__global__ __launch_bounds__(256) void k_agg512(const u16* __restrict__ ycat,
                                                float* __restrict__ zc, u16* __restrict__ zcb,
                                                float* __restrict__ zh,
                                                const int* __restrict__ rp, const int* __restrict__ src,
                                                const float* __restrict__ wst, const float* __restrict__ dinv,
                                                const float* __restrict__ bcat, int n) {
  int wv = threadIdx.x >> 6, lane = threadIdx.x & 63;
  int node = blockIdx.x * 4 + wv;
  if (node >= n) return;
  float acc[8] = {};
  int s0 = rp[node], s1 = rp[node + 1];
  for (int s = s0; s < s1; ++s) {
    float wgt = wst[s];
    int r = src[s];
    uint4 v = *((const uint4*)(ycat + (size_t)r * 512) + lane);
#pragma unroll
    for (int q = 0; q < 4; ++q) {
      u32 word = ((const u32*)&v)[q];
      acc[2 * q]     += wgt * blo(word);
      acc[2 * q + 1] += wgt * bhi(word);
    }
  }
  float sw = dinv[node]; sw *= sw;
  uint4 v = *((const uint4*)(ycat + (size_t)node * 512) + lane);
#pragma unroll
  for (int q = 0; q < 4; ++q) {
    u32 word = ((const u32*)&v)[q];
    acc[2 * q]     += sw * blo(word);
    acc[2 * q + 1] += sw * bhi(word);
  }
  int f0 = lane * 8;
#pragma unroll
  for (int j = 0; j < 8; ++j) acc[j] += bcat[f0 + j];
  if (lane < 32) {
    float* o = zc + (size_t)node * 256 + f0;
    u16* ob = zcb + (size_t)node * 256 + f0;
#pragma unroll
    for (int j = 0; j < 8; ++j) { o[j] = acc[j]; ob[j] = f2b(acc[j]); }
  } else {
    float* o = zh + (size_t)node * 256 + (f0 - 256);
#pragma unroll
    for (int j = 0; j < 8; ++j) o[j] = acc[j];
  }
}

// decoder agg: yd bf16 [N][128] -> x_hat f32 [N][128] (+bd); u32 per lane
__global__ __launch_bounds__(256) void k_agg_dec(const u16* __restrict__ yd, float* __restrict__ xhat,
                                                 const int* __restrict__ rp, const int* __restrict__ src,
                                                 const float* __restrict__ wst, const float* __restrict__ dinv,
                                                 const float* __restrict__ bd, int n) {
  int wv = threadIdx.x >> 6, lane = threadIdx.x & 63;
  int node = blockIdx.x * 4 + wv;
  if (node >= n) return;
  float a0 = 0.f, a1 = 0.f;
  int s0 = rp[node], s1 = rp[node + 1];
  for (int s = s0; s < s1; ++s) {
    float wgt = wst[s];
    int r = src[s];
    u32 w = *((const u32*)(yd + (size_t)r * 128) + lane);
    a0 += wgt * blo(w); a1 += wgt * bhi(w);
  }
  float sw = dinv[node]; sw *= sw;
  u32 w = *((const u32*)(yd + (size_t)node * 128) + lane);
  a0 += sw * blo(w); a1 += sw * bhi(w);
  float2 o;
  o.x = a0 + bd[lane * 2];
  o.y = a1 + bd[lane * 2 + 1];
  *((float2*)(xhat + (size_t)node * 128) + lane) = o;
}

// ---------------- MFMA bf16 GEMM: C = act(A @ BT^T + bias), ldc/coloff epilogue ----------------
template <bool RELU, bool BIAS, typename TC>
__global__ __launch_bounds__(256) void k_mgemm(const u16* __restrict__ A, const u16* __restrict__ BT,
                                               const float* __restrict__ bias, TC* __restrict__ C,
                                               int M, int N, int K, int ldc, int coloff) {
  __shared__ u16 As[128 * 64];
  __shared__ u16 Bs[128 * 64];
  const int t = threadIdx.x;
  const int w = t >> 6, lane = t & 63;
  const int brow = blockIdx.y * 128;
  const int bcol = blockIdx.x * 128;
  const int wr = w >> 1, wc = w & 1;

  f32x4 acc[4][4];
#pragma unroll
  for (int m = 0; m < 4; ++m)
#pragma unroll
    for (int n = 0; n < 4; ++n) acc[m][n] = (f32x4){0.f, 0.f, 0.f, 0.f};

  for (int kt = 0; kt < K; kt += 64) {
#pragma unroll
    for (int j = 0; j < 4; ++j) {
      int c = j * 4 + w;              // chunk 0..15 (wave-uniform)
      int li = c * 64 + lane;         // 16B unit index
      int row = li >> 3, col8 = li & 7;
      int ar = brow + row; if (ar > M - 1) ar = M - 1;
      __builtin_amdgcn_global_load_lds(
          (const __attribute__((address_space(1))) void*)(A + (size_t)ar * K + kt + col8 * 8),
          (__attribute__((address_space(3))) void*)(As + c * 512), 16, 0, 0);
      __builtin_amdgcn_global_load_lds(
          (const __attribute__((address_space(1))) void*)(BT + (size_t)(bcol + row) * K + kt + col8 * 8),
          (__attribute__((address_space(3))) void*)(Bs + c * 512), 16, 0, 0);
    }
    __syncthreads();
    bf16x8 af[4][2], bb[4][2];
#pragma unroll
    for (int kk = 0; kk < 2; ++kk) {
      int kof = kk * 32 + (lane >> 4) * 8;
#pragma unroll
      for (int m = 0; m < 4; ++m)
        af[m][kk] = *(const bf16x8*)(As + (wr * 64 + m * 16 + (lane & 15)) * 64 + kof);
#pragma unroll
      for (int n = 0; n < 4; ++n)
        bb[n][kk] = *(const bf16x8*)(Bs + (wc * 64 + n * 16 + (lane & 15)) * 64 + kof);
    }
#pragma unroll
    for (int kk = 0; kk < 2; ++kk)
#pragma unroll
      for (int m = 0; m < 4; ++m)
#pragma unroll
        for (int n = 0; n < 4; ++n)
          acc[m][n] = __builtin_amdgcn_mfma_f32_16x16x32_bf16(af[m][kk], bb[n][kk], acc[m][n], 0, 0, 0);
    __syncthreads();
  }
#pragma unroll
  for (int m = 0; m < 4; ++m) {
    int r0 = brow + wr * 64 + m * 16 + (lane >> 4) * 4;
#pragma unroll
    for (int n = 0; n < 4; ++n) {
      int col = bcol + wc * 64 + n * 16 + (lane & 15);
      float bv = BIAS ? bias[col] : 0.0f;
#pragma unroll
      for (int q = 0; q < 4; ++q) {
        int rr = r0 + q;
        if (rr < M) {
          float v = acc[m][n][q] + bv;
          if (RELU) v = fmaxf(v, 0.0f);
          stor(&C[(size_t)rr * ldc + coloff + col], v);
        }
      }
    }
  }
}

// ---------------- small f32 GEMM (proj heads) ----------------
template <typename TA, typename TC, bool RELU, bool BIAS>
__global__ __launch_bounds__(256) void k_gemm(const TA* __restrict__ A, const float* __restrict__ B,
                                              const float* __restrict__ bias, TC* __restrict__ C,
                                              int M, int N, int K) {
  __shared__ float As[64][17];
  __shared__ float Bs[16][65];
  const int tx = threadIdx.x & 15;
  const int ty = threadIdx.x >> 4;
  const int row0 = blockIdx.y * 64;
  const int col0 = blockIdx.x * 64;
  float acc[4][4] = {};
  for (int k0 = 0; k0 < K; k0 += 16) {
#pragma unroll
    for (int i = 0; i < 4; ++i) {
      int lin = threadIdx.x + i * 256;
      int r = lin >> 4, c = lin & 15;
      int gr = row0 + r;
      As[r][c] = (gr < M) ? cvt(A[(size_t)gr * K + k0 + c]) : 0.0f;
    }
#pragma unroll
    for (int i = 0; i < 4; ++i) {
      int lin = threadIdx.x + i * 256;
      int r = lin >> 6, c = lin & 63;
      Bs[r][c] = B[(size_t)(k0 + r) * N + col0 + c];
    }
    __syncthreads();
#pragma unroll
    for (int k = 0; k < 16; ++k) {
      float a[4], b[4];
#pragma unroll
      for (int i = 0; i < 4; ++i) a[i] = As[ty * 4 + i][k];
#pragma unroll
      for (int j = 0; j < 4; ++j) b[j] = Bs[k][tx * 4 + j];
#pragma unroll
      for (int i = 0; i < 4; ++i)
#pragma unroll
        for (int j = 0; j < 4; ++j) acc[i][j] += a[i] * b[j];
    }
    __syncthreads();
  }
#pragma unroll
  for (int i = 0; i < 4; ++i) {
    int gr = row0 + ty * 4 + i;
    if (gr < M) {
#pragma unroll
      for (int j = 0; j < 4; ++j) {
        int gc = col0 + tx * 4 + j;
        float v = acc[i][j];
        if (BIAS) v += bias[gc];
        if (RELU) v = fmaxf(v, 0.0f);
        stor(&C[(size_t)gr * N + gc], v);
      }
    }
  }
}

__global__ void k_split(const float* __restrict__ pg3, float* __restrict__ h_g,
                        float* __restrict__ hhat_g) {
  int i = blockIdx.x * 256 + threadIdx.x;  // 8192 = 128x64
  if (i < 8192) {
    int r = i >> 6;
    if (r < 64) h_g[i] = pg3[i];
    else hhat_g[i - 4096] = pg3[i];
  }
}

// ---------------- pooling: two-stage deterministic reduction ----------------
__device__ inline int lbound(const int* a, int n, int v) {
  int lo = 0, hi = n;
  while (lo < hi) { int mid = (lo + hi) >> 1; if (a[mid] < v) lo = mid + 1; else hi = mid; }
  return lo;
}

#define POOL_NCH 32

__global__ __launch_bounds__(256) void k_pool_partial(const float* __restrict__ z,
                                                      const int* __restrict__ batch,
                                                      float* __restrict__ psum, float* __restrict__ pmax,
                                                      int n) {
  int g = blockIdx.x, ch = blockIdx.y;
  __shared__ int ss, se;
  if (threadIdx.x == 0) { ss = lbound(batch, n, g); se = lbound(batch, n, g + 1); }
  __syncthreads();
  int start = ss, len = se - ss;
  int c0 = start + (int)((long long)len * ch / POOL_NCH);
  int c1 = start + (int)((long long)len * (ch + 1) / POOL_NCH);
  int f = threadIdx.x;
  float acc = 0.0f, mx = -INFINITY;
  for (int i = c0; i < c1; ++i) {
    float v = z[(size_t)i * 256 + f];
    acc += v;
    mx = fmaxf(mx, v);
  }
  size_t o = ((size_t)g * POOL_NCH + ch) * 256 + f;
  psum[o] = acc;
  pmax[o] = mx;
}

// stage 2: writes zg (d_out layout) AND gcat row (stacked proj input)
__global__ __launch_bounds__(256) void k_pool_final(const float* __restrict__ psum,
                                                    const float* __restrict__ pmax,
                                                    const int* __restrict__ batch,
                                                    float* __restrict__ zg, float* __restrict__ gcat,
                                                    int rowoff, int n) {
  int g = blockIdx.x, f = threadIdx.x;
  float s = 0.0f, m = -INFINITY;
#pragma unroll 4
  for (int c = 0; c < POOL_NCH; ++c) {
    size_t o = ((size_t)g * POOL_NCH + c) * 256 + f;
    s += psum[o];
    m = fmaxf(m, pmax[o]);
  }
  __shared__ int ss, se;
  if (threadIdx.x == 0) { ss = lbound(batch, n, g); se = lbound(batch, n, g + 1); }
  __syncthreads();
  int cnt = se - ss;
  float mean = s / fmaxf((float)cnt, 1.0f);
  float mxo = (cnt > 0) ? m : 0.0f;
  zg[(size_t)g * 512 + f] = mean;
  zg[(size_t)g * 512 + 256 + f] = mxo;
  gcat[(size_t)(rowoff + g) * 512 + f] = mean;
  gcat[(size_t)(rowoff + g) * 512 + 256 + f] = mxo;
}

// ---------------- launch ----------------
extern "C" void kernel_launch(void* const* d_in, const int* in_sizes, int n_in,
                              void* d_out, int out_size, void* d_ws, size_t ws_size,
                              hipStream_t stream) {
  const float* x   = (const float*)d_in[0];
  const int*   ei  = (const int*)d_in[1];
  const int*   bat = (const int*)d_in[2];
  const float* W1  = (const float*)d_in[4];
  const float* b1  = (const float*)d_in[5];
  const float* W2  = (const float*)d_in[6];
  const float* b2  = (const float*)d_in[7];
  const float* Wd  = (const float*)d_in[8];
  const float* bd  = (const float*)d_in[9];
  const float* P1w = (const float*)d_in[10];
  const float* P1b = (const float*)d_in[11];
  const float* P2w = (const float*)d_in[12];
  const float* P2b = (const float*)d_in[13];
  const float* P3w = (const float*)d_in[14];
  const float* P3b = (const float*)d_in[15];

  const int N = in_sizes[0] / 128;  // 50000
  const int E = in_sizes[1] / 2;    // 400000
  const int B = 64;
  const int NB = (N + 1023) / 1024;

  char* w = (char*)d_ws;
  auto carve = [&](size_t bytes) -> void* {
    void* p = (void*)w;
    w += (bytes + 255) & ~(size_t)255;
    return p;
  };
  int*    cnt        = (int*)carve((size_t)N * 4);
  int*    row_ptr    = (int*)carve((size_t)(N + 1) * 4);
  int*    cursor     = (int*)carve((size_t)N * 4);
  float*  dinv       = (float*)carve((size_t)N * 4);
  int*    incl       = (int*)carve((size_t)N * 4);
  int*    bsum       = (int*)carve((size_t)1024 * 4);
  int*    src_sorted = (int*)carve((size_t)E * 4);
  float*  w_sorted   = (float*)carve((size_t)E * 4);
  float*  sigma      = (float*)carve(256);
  double* psd        = (double*)carve((size_t)64 * 2 * 8);
  float*  W1h        = (float*)carve((size_t)128 * 512 * 4);
  float*  b1h        = (float*)carve((size_t)512 * 4);
  float*  W2h        = (float*)carve((size_t)512 * 256 * 4);
  float*  b2h        = (float*)carve((size_t)256 * 4);
  float*  bcat       = (float*)carve((size_t)512 * 4);
  u16*    W1T        = (u16*)carve((size_t)128 * 512 * 2);
  u16*    W2T        = (u16*)carve((size_t)512 * 256 * 2);
  u16*    WdT        = (u16*)carve((size_t)256 * 128 * 2);
  u16*    W1hT       = (u16*)carve((size_t)128 * 512 * 2);
  u16*    W2hT       = (u16*)carve((size_t)512 * 256 * 2);
  u16*    px         = (u16*)carve((size_t)N * 128 * 2);
  u16*    z1         = (u16*)carve((size_t)N * 512 * 2);   // L1 scratch (reused both branches)
  u16*    ycat       = (u16*)carve((size_t)N * 512 * 2);   // [y_clean | y_pert]; later aliased as yd
  u16*    znb        = (u16*)carve((size_t)N * 256 * 2);   // bf16 z_node (decoder A)
  float*  gcat       = (float*)carve((size_t)128 * 512 * 4);
  float*  pg1        = (float*)carve((size_t)128 * 256 * 4);
  float*  pg2        = (float*)carve((size_t)128 * 128 * 4);
  float*  pg3        = (float*)carve((size_t)128 * 64 * 4);
  float*  psum       = (float*)carve((size_t)B * POOL_NCH * 256 * 4);
  float*  pmax       = (float*)carve((size_t)B * POOL_NCH * 256 * 4);
  u16*    yd         = ycat;  // alias: ycat dead after k_agg512

  float* out       = (float*)d_out;
  float* z_node    = out;
  float* z_g       = z_node + (size_t)N * 256;
  float* zhat_node = z_g + (size_t)B * 512;
  float* zhat_g    = zhat_node + (size_t)N * 256;
  float* h_g       = zhat_g + (size_t)B * 512;
  float* hhat_g    = h_g + (size_t)B * 64;
  float* x_hat     = hhat_g + (size_t)B * 64;

  // nk = split(key(42), 4): nk[i] = threefry(key, (0, i))
  u32 nk[4][2];
  for (u32 i = 0; i < 4; ++i) tf2x32(0u, 42u, 0u, i, &nk[i][0], &nk[i][1]);

  // --- graph preprocessing ---
  hipMemsetAsync(cnt, 0, (size_t)N * 4, stream);
  k_count<<<(E + 255) / 256, 256, 0, stream>>>(ei, cnt, E);
  k_scan_local<<<NB, 1024, 0, stream>>>(cnt, incl, bsum, N);
  k_scan_bsum<<<1, 1024, 0, stream>>>(bsum, NB);
  k_scan_final<<<NB, 1024, 0, stream>>>(cnt, incl, bsum, row_ptr, cursor, dinv, N, E);
  k_place<<<(E + 255) / 256, 256, 0, stream>>>(ei, cursor, dinv, src_sorted, w_sorted, E);

  // --- perturbed weights ---
  k_std1<<<64, 256, 0, stream>>>(W1, 128 * 512, b1, 512, W2, 512 * 256, b2, 256, psd);
  k_std2<<<1, 64, 0, stream>>>(psd, 128 * 512, 512, 512 * 256, 256, sigma);
  k_perturb<<<(65536 + 255) / 256, 256, 0, stream>>>(W1, W1h, 128 * 512, nk[0][0], nk[0][1], sigma, 0);
  k_perturb<<<2, 256, 0, stream>>>(b1, b1h, 512, nk[1][0], nk[1][1], sigma, 1);
  k_perturb<<<(131072 + 255) / 256, 256, 0, stream>>>(W2, W2h, 512 * 256, nk[2][0], nk[2][1], sigma, 2);
  k_perturb<<<1, 256, 0, stream>>>(b2, b2h, 256, nk[3][0], nk[3][1], sigma, 3);
  k_bcat<<<1, 512, 0, stream>>>(b2, b2h, bcat);

  // --- bf16 transposed weight panels ---
  k_transpose<<<(65536 + 255) / 256, 256, 0, stream>>>(W1, W1T, 128, 512);
  k_transpose<<<(131072 + 255) / 256, 256, 0, stream>>>(W2, W2T, 512, 256);
  k_transpose<<<(32768 + 255) / 256, 256, 0, stream>>>(Wd, WdT, 256, 128);
  k_transpose<<<(65536 + 255) / 256, 256, 0, stream>>>(W1h, W1hT, 128, 512);
  k_transpose<<<(131072 + 255) / 256, 256, 0, stream>>>(W2h, W2hT, 512, 256);

  const int aggBlocks = (N + 3) / 4;

  // px = P @ x (shared by both branches)
  k_agg_px<<<aggBlocks, 256, 0, stream>>>(x, px, row_ptr, src_sorted, w_sorted, dinv, N);

  const int MB = (N + 127) / 128;
  dim3 m512(4, MB), m256(2, MB), m128(1, MB);

  // perturbed branch L1+L2 -> ycat cols 256-511
  k_mgemm<true, true, u16><<<m512, 256, 0, stream>>>(px, W1hT, b1h, z1, N, 512, 128, 512, 0);
  k_mgemm<false, false, u16><<<m256, 256, 0, stream>>>(z1, W2hT, nullptr, ycat, N, 256, 512, 512, 256);
  // clean branch L1+L2 -> ycat cols 0-255 (z1 reused)
  k_mgemm<true, true, u16><<<m512, 256, 0, stream>>>(px, W1T, b1, z1, N, 512, 128, 512, 0);
  k_mgemm<false, false, u16><<<m256, 256, 0, stream>>>(z1, W2T, nullptr, ycat, N, 256, 512, 512, 0);

  // single merged aggregation pass: z_node (+znb bf16) and zhat_node
  k_agg512<<<aggBlocks, 256, 0, stream>>>(ycat, z_node, znb, zhat_node,
                                          row_ptr, src_sorted, w_sorted, dinv, bcat, N);

  // pooling (two-stage), dual-writing gcat for stacked proj heads
  dim3 pgrid(B, POOL_NCH);
  k_pool_partial<<<pgrid, 256, 0, stream>>>(z_node, bat, psum, pmax, N);
  k_pool_final<<<B, 256, 0, stream>>>(psum, pmax, bat, z_g, gcat, 0, N);
  k_pool_partial<<<pgrid, 256, 0, stream>>>(zhat_node, bat, psum, pmax, N);
  k_pool_final<<<B, 256, 0, stream>>>(psum, pmax, bat, zhat_g, gcat, 64, N);

  // decoder: x_hat = P @ (z_node @ Wd) + bd   (yd aliases ycat, dead after agg512)
  k_mgemm<false, false, u16><<<m128, 256, 0, stream>>>(znb, WdT, nullptr, yd, N, 128, 256, 128, 0);
  k_agg_dec<<<aggBlocks, 256, 0, stream>>>(yd, x_hat, row_ptr, src_sorted, w_sorted, dinv, bd, N);

  // stacked projection heads: [z_g; zhat_g] (128 rows)
  dim3 q1(4, 2), q2(2, 2), q3(1, 2);
  k_gemm<float, float, true, true><<<q1, 256, 0, stream>>>(gcat, P1w, P1b, pg1, 128, 256, 512);
  k_gemm<float, float, true, true><<<q2, 256, 0, stream>>>(pg1, P2w, P2b, pg2, 128, 128, 256);
  k_gemm<float, float, false, true><<<q3, 256, 0, stream>>>(pg2, P3w, P3b, pg3, 128, 64, 128);
  k_split<<<32, 256, 0, stream>>>(pg3, h_g, hhat_g);
}

// Round 7
// 579.364 us; speedup vs baseline: 3.4458x; 1.0546x over previous
//
#include <hip/hip_runtime.h>

typedef unsigned short u16;
typedef unsigned int u32;
typedef short bf16x8 __attribute__((ext_vector_type(8)));
typedef float f32x4 __attribute__((ext_vector_type(4)));

// ---------------- threefry2x32 (JAX-compatible, 20 rounds) ----------------
__host__ __device__ inline u32 rotl32(u32 x, int r) { return (x << r) | (x >> (32 - r)); }

__host__ __device__ inline void tf_r4(u32& x0, u32& x1, int r0, int r1, int r2, int r3) {
  x0 += x1; x1 = rotl32(x1, r0); x1 ^= x0;
  x0 += x1; x1 = rotl32(x1, r1); x1 ^= x0;
  x0 += x1; x1 = rotl32(x1, r2); x1 ^= x0;
  x0 += x1; x1 = rotl32(x1, r3); x1 ^= x0;
}

__host__ __device__ inline void tf2x32(u32 k0, u32 k1, u32 c0, u32 c1, u32* o0, u32* o1) {
  u32 ks2 = 0x1BD11BDAu ^ k0 ^ k1;
  u32 x0 = c0 + k0, x1 = c1 + k1;
  tf_r4(x0, x1, 13, 15, 26, 6);  x0 += k1;  x1 += ks2 + 1u;
  tf_r4(x0, x1, 17, 29, 16, 24); x0 += ks2; x1 += k0 + 2u;
  tf_r4(x0, x1, 13, 15, 26, 6);  x0 += k0;  x1 += k1 + 3u;
  tf_r4(x0, x1, 17, 29, 16, 24); x0 += k1;  x1 += ks2 + 4u;
  tf_r4(x0, x1, 13, 15, 26, 6);  x0 += ks2; x1 += k0 + 5u;
  *o0 = x0; *o1 = x1;
}

// XLA/Giles f32 erfinv
__device__ inline float erfinv_f(float x) {
  float w = -log1pf(-x * x);
  float p;
  if (w < 5.0f) {
    w -= 2.5f;
    p = 2.81022636e-08f;
    p = 3.43273939e-07f + p * w;
    p = -3.5233877e-06f + p * w;
    p = -4.39150654e-06f + p * w;
    p = 0.00021858087f + p * w;
    p = -0.00125372503f + p * w;
    p = -0.00417768164f + p * w;
    p = 0.246640727f + p * w;
    p = 1.50140941f + p * w;
  } else {
    w = sqrtf(w) - 3.0f;
    p = -0.000200214257f;
    p = 0.000100950558f + p * w;
    p = 0.00134934322f + p * w;
    p = -0.00367342844f + p * w;
    p = 0.00573950773f + p * w;
    p = -0.0076224613f + p * w;
    p = 0.00943887047f + p * w;
    p = 1.00167406f + p * w;
    p = 2.83297682f + p * w;
  }
  return p * x;
}

__device__ inline float bits2normal(u32 b) {
  float f = __uint_as_float((b >> 9) | 0x3F800000u) - 1.0f;  // [0,1)
  float u = f * 2.0f - 0.99999994f;
  u = fmaxf(u, -0.99999994f);
  return 1.41421356f * erfinv_f(u);
}

// ---------------- dtype helpers ----------------
__device__ inline float cvt(float v) { return v; }
__device__ inline float cvt(u16 v) { return __uint_as_float(((u32)v) << 16); }
__device__ inline void stor(float* p, float v) { *p = v; }
__device__ inline void stor(u16* p, float v) {
  u32 x = __float_as_uint(v);
  *p = (u16)((x + 0x7FFFu + ((x >> 16) & 1u)) >> 16);  // RTNE bf16
}
__device__ inline u16 f2b(float v) {
  u32 x = __float_as_uint(v);
  return (u16)((x + 0x7FFFu + ((x >> 16) & 1u)) >> 16);
}
__device__ inline float blo(u32 w) { return __uint_as_float(w << 16); }
__device__ inline float bhi(u32 w) { return __uint_as_float(w & 0xFFFF0000u); }

// ---------------- graph preprocessing ----------------
__global__ void k_count(const int* __restrict__ ei, int* __restrict__ cnt, int E) {
  int e = blockIdx.x * blockDim.x + threadIdx.x;
  if (e < E) atomicAdd(&cnt[ei[E + e]], 1);
}

__global__ __launch_bounds__(1024) void k_scan_local(const int* __restrict__ cnt,
                                                     int* __restrict__ incl, int* __restrict__ bsum,
                                                     int n) {
  __shared__ int buf[1024];
  int i = blockIdx.x * 1024 + threadIdx.x;
  int v = (i < n) ? cnt[i] : 0;
  buf[threadIdx.x] = v;
  __syncthreads();
  for (int off = 1; off < 1024; off <<= 1) {
    int t = (threadIdx.x >= off) ? buf[threadIdx.x - off] : 0;
    __syncthreads();
    buf[threadIdx.x] += t;
    __syncthreads();
  }
  if (i < n) incl[i] = buf[threadIdx.x];
  if (threadIdx.x == 1023) bsum[blockIdx.x] = buf[1023];
}

__global__ __launch_bounds__(1024) void k_scan_bsum(int* __restrict__ bsum, int nb) {
  __shared__ int buf[1024];
  int v = (threadIdx.x < nb) ? bsum[threadIdx.x] : 0;
  buf[threadIdx.x] = v;
  __syncthreads();
  for (int off = 1; off < 1024; off <<= 1) {
    int t = (threadIdx.x >= off) ? buf[threadIdx.x - off] : 0;
    __syncthreads();
    buf[threadIdx.x] += t;
    __syncthreads();
  }
  if (threadIdx.x < nb) bsum[threadIdx.x] = buf[threadIdx.x] - v;  // exclusive
}

__global__ __launch_bounds__(1024) void k_scan_final(const int* __restrict__ cnt,
                                                     const int* __restrict__ incl,
                                                     const int* __restrict__ bsum,
                                                     int* __restrict__ row_ptr, int* __restrict__ cursor,
                                                     float* __restrict__ dinv, int n, int E) {
  int i = blockIdx.x * 1024 + threadIdx.x;
  if (i < n) {
    int c = cnt[i];
    int ex = incl[i] + bsum[blockIdx.x] - c;
    row_ptr[i] = ex;
    cursor[i] = ex;
    dinv[i] = 1.0f / sqrtf((float)(c + 1));  // deg includes self-loop
  }
  if (i == 0) row_ptr[n] = E;
}

__global__ void k_place(const int* __restrict__ ei, int* __restrict__ cursor,
                        const float* __restrict__ dinv, int* __restrict__ src_sorted,
                        float* __restrict__ w_sorted, int E) {
  int e = blockIdx.x * blockDim.x + threadIdx.x;
  if (e < E) {
    int s = ei[e], d = ei[E + e];
    int slot = atomicAdd(&cursor[d], 1);
    src_sorted[slot] = s;
    w_sorted[slot] = dinv[s] * dinv[d];
  }
}

// ---------------- std (ddof=1), two-stage ----------------
__global__ __launch_bounds__(256) void k_std1(const float* p0, int n0, const float* p1, int n1,
                                              const float* p2, int n2, const float* p3, int n3,
                                              double* __restrict__ psd) {
  int t = blockIdx.x >> 4, ch = blockIdx.x & 15;
  const float* p; int n;
  if (t == 0) { p = p0; n = n0; }
  else if (t == 1) { p = p1; n = n1; }
  else if (t == 2) { p = p2; n = n2; }
  else { p = p3; n = n3; }
  int c0 = (int)((long long)n * ch / 16), c1 = (int)((long long)n * (ch + 1) / 16);
  double s = 0.0, ss = 0.0;
  for (int i = c0 + threadIdx.x; i < c1; i += 256) { double v = p[i]; s += v; ss += v * v; }
  __shared__ double sh[256];
  __shared__ double sh2[256];
  sh[threadIdx.x] = s; sh2[threadIdx.x] = ss;
  __syncthreads();
  for (int o = 128; o > 0; o >>= 1) {
    if (threadIdx.x < o) { sh[threadIdx.x] += sh[threadIdx.x + o]; sh2[threadIdx.x] += sh2[threadIdx.x + o]; }
    __syncthreads();
  }
  if (threadIdx.x == 0) { psd[blockIdx.x * 2] = sh[0]; psd[blockIdx.x * 2 + 1] = sh2[0]; }
}

__global__ void k_std2(const double* __restrict__ psd, int n0, int n1, int n2, int n3,
                       float* __restrict__ sigma) {
  int l = threadIdx.x;  // 64 lanes
  double s = psd[l * 2], ss = psd[l * 2 + 1];
  for (int off = 1; off < 16; off <<= 1) { s += __shfl_xor(s, off); ss += __shfl_xor(ss, off); }
  if ((l & 15) == 0) {
    int t = l >> 4;
    int n = (t == 0) ? n0 : (t == 1) ? n1 : (t == 2) ? n2 : n3;
    double mean = s / n;
    double var = (ss - s * mean) / (double)(n - 1);
    if (var < 0.0) var = 0.0;
    sigma[t] = fmaxf((float)sqrt(var), 1e-6f);
  }
}

// partitionable threefry random_bits: counter (0, j) -> bits = o0 ^ o1
__global__ void k_perturb(const float* __restrict__ p, float* __restrict__ ph, int n,
                          u32 k0, u32 k1, const float* __restrict__ sigma, int sidx) {
  int j = blockIdx.x * blockDim.x + threadIdx.x;
  if (j < n) {
    u32 r0, r1;
    tf2x32(k0, k1, 0u, (u32)j, &r0, &r1);
    ph[j] = p[j] + sigma[sidx] * bits2normal(r0 ^ r1);
  }
}

// transpose f32 [K][N] -> bf16 [N][K]
__global__ void k_transpose(const float* __restrict__ in, u16* __restrict__ out, int K, int N) {
  int j = blockIdx.x * blockDim.x + threadIdx.x;
  if (j < K * N) {
    int k = j / N, n = j - k * N;
    out[(size_t)n * K + k] = f2b(in[j]);
  }
}

// f32 -> bf16 elementwise (vectorized: 4 elems/thread)
__global__ void k_bf16cast(const float* __restrict__ in, u16* __restrict__ out, int n4) {
  int j = blockIdx.x * blockDim.x + threadIdx.x;
  if (j < n4) {
    float4 v = ((const float4*)in)[j];
    u32 w0 = ((u32)f2b(v.x)) | (((u32)f2b(v.y)) << 16);
    u32 w1 = ((u32)f2b(v.z)) | (((u32)f2b(v.w)) << 16);
    ((u32*)out)[j * 2] = w0;
    ((u32*)out)[j * 2 + 1] = w1;
  }
}

__global__ void k_bcat(const float* __restrict__ b2, const float* __restrict__ b2h,
                       float* __restrict__ bcat) {
  int i = threadIdx.x;  // 512 threads
  bcat[i] = (i < 256) ? b2[i] : b2h[i - 256];
}

// ---------------- CSR aggregations (vectorized + MLP-unrolled) ----------------
// px = P @ xb : xb bf16 [N][128] -> px bf16 [N][128]; u32 (2 bf16) per lane, 8-deep unroll
__global__ __launch_bounds__(256) void k_agg_px(const u16* __restrict__ xb, u16* __restrict__ px,
                                                const int* __restrict__ rp, const int* __restrict__ src,
                                                const float* __restrict__ wst, const float* __restrict__ dinv,
                                                int n) {
  int wv = threadIdx.x >> 6, lane = threadIdx.x & 63;
  int node = blockIdx.x * 4 + wv;
  if (node >= n) return;
  float a0 = 0.f, a1 = 0.f;
  int s0 = rp[node], s1 = rp[node + 1];
  int s = s0;
  for (; s + 8 <= s1; s += 8) {
    u32 v[8]; float wg[8];
#pragma unroll
    for (int u = 0; u < 8; ++u) {
      int r = src[s + u];
      wg[u] = wst[s + u];
      v[u] = *((const u32*)(xb + (size_t)r * 128) + lane);
    }
#pragma unroll
    for (int u = 0; u < 8; ++u) { a0 += wg[u] * blo(v[u]); a1 += wg[u] * bhi(v[u]); }
  }
  for (; s < s1; ++s) {
    float wgt = wst[s];
    int r = src[s];
    u32 w = *((const u32*)(xb + (size_t)r * 128) + lane);
    a0 += wgt * blo(w); a1 += wgt * bhi(w);
  }
  float sw = dinv[node]; sw *= sw;
  u32 w = *((const u32*)(xb + (size_t)node * 128) + lane);
  a0 += sw * blo(w); a1 += sw * bhi(w);
  u32 o = ((u32)f2b(a0)) | (((u32)f2b(a1)) << 16);
  *((u32*)(px + (size_t)node * 128) + lane) = o;
}

// merged layer-2 agg: ycat bf16 [N][512]; uint4 per lane, 4-deep unroll
__global__ __launch_bounds__(256) void k_agg512(const u16* __restrict__ ycat,
                                                float* __restrict__ zc, u16* __restrict__ zcb,
                                                float* __restrict__ zh,
                                                const int* __restrict__ rp, const int* __restrict__ src,
                                                const float* __restrict__ wst, const float* __restrict__ dinv,
                                                const float* __restrict__ bcat, int n) {
  int wv = threadIdx.x >> 6, lane = threadIdx.x & 63;
  int node = blockIdx.x * 4 + wv;
  if (node >= n) return;
  float acc[8] = {};
  int s0 = rp[node], s1 = rp[node + 1];
  int s = s0;
  for (; s + 4 <= s1; s += 4) {
    uint4 v[4]; float wg[4];
#pragma unroll
    for (int u = 0; u < 4; ++u) {
      int r = src[s + u];
      wg[u] = wst[s + u];
      v[u] = *((const uint4*)(ycat + (size_t)r * 512) + lane);
    }
#pragma unroll
    for (int u = 0; u < 4; ++u)
#pragma unroll
      for (int q = 0; q < 4; ++q) {
        u32 word = ((const u32*)&v[u])[q];
        acc[2 * q]     += wg[u] * blo(word);
        acc[2 * q + 1] += wg[u] * bhi(word);
      }
  }
  for (; s < s1; ++s) {
    float wgt = wst[s];
    int r = src[s];
    uint4 v = *((const uint4*)(ycat + (size_t)r * 512) + lane);
#pragma unroll
    for (int q = 0; q < 4; ++q) {
      u32 word = ((const u32*)&v)[q];
      acc[2 * q]     += wgt * blo(word);
      acc[2 * q + 1] += wgt * bhi(word);
    }
  }
  float sw = dinv[node]; sw *= sw;
  uint4 v = *((const uint4*)(ycat + (size_t)node * 512) + lane);
#pragma unroll
  for (int q = 0; q < 4; ++q) {
    u32 word = ((const u32*)&v)[q];
    acc[2 * q]     += sw * blo(word);
    acc[2 * q + 1] += sw * bhi(word);
  }
  int f0 = lane * 8;
#pragma unroll
  for (int j = 0; j < 8; ++j) acc[j] += bcat[f0 + j];
  if (lane < 32) {
    float* o = zc + (size_t)node * 256 + f0;
    u16* ob = zcb + (size_t)node * 256 + f0;
#pragma unroll
    for (int j = 0; j < 8; ++j) { o[j] = acc[j]; ob[j] = f2b(acc[j]); }
  } else {
    float* o = zh + (size_t)node * 256 + (f0 - 256);
#pragma unroll
    for (int j = 0; j < 8; ++j) o[j] = acc[j];
  }
}

// decoder agg: yd bf16 [N][128] -> x_hat f32 [N][128] (+bd); u32 per lane, 8-deep unroll
__global__ __launch_bounds__(256) void k_agg_dec(const u16* __restrict__ yd, float* __restrict__ xhat,
                                                 const int* __restrict__ rp, const int* __restrict__ src,
                                                 const float* __restrict__ wst, const float* __restrict__ dinv,
                                                 const float* __restrict__ bd, int n) {
  int wv = threadIdx.x >> 6, lane = threadIdx.x & 63;
  int node = blockIdx.x * 4 + wv;
  if (node >= n) return;
  float a0 = 0.f, a1 = 0.f;
  int s0 = rp[node], s1 = rp[node + 1];
  int s = s0;
  for (; s + 8 <= s1; s += 8) {
    u32 v[8]; float wg[8];
#pragma unroll
    for (int u = 0; u < 8; ++u) {
      int r = src[s + u];
      wg[u] = wst[s + u];
      v[u] = *((const u32*)(yd + (size_t)r * 128) + lane);
    }
#pragma unroll
    for (int u = 0; u < 8; ++u) { a0 += wg[u] * blo(v[u]); a1 += wg[u] * bhi(v[u]); }
  }
  for (; s < s1; ++s) {
    float wgt = wst[s];
    int r = src[s];
    u32 w = *((const u32*)(yd + (size_t)r * 128) + lane);
    a0 += wgt * blo(w); a1 += wgt * bhi(w);
  }
  float sw = dinv[node]; sw *= sw;
  u32 w = *((const u32*)(yd + (size_t)node * 128) + lane);
  a0 += sw * blo(w); a1 += sw * bhi(w);
  float2 o;
  o.x = a0 + bd[lane * 2];
  o.y = a1 + bd[lane * 2 + 1];
  *((float2*)(xhat + (size_t)node * 128) + lane) = o;
}

// ---------------- MFMA bf16 GEMM: C = act(A @ BT^T + bias), ldc/coloff epilogue ----------------
template <bool RELU, bool BIAS, typename TC>
__global__ __launch_bounds__(256) void k_mgemm(const u16* __restrict__ A, const u16* __restrict__ BT,
                                               const float* __restrict__ bias, TC* __restrict__ C,
                                               int M, int N, int K, int ldc, int coloff) {
  __shared__ u16 As[128 * 64];
  __shared__ u16 Bs[128 * 64];
  const int t = threadIdx.x;
  const int w = t >> 6, lane = t & 63;
  const int brow = blockIdx.y * 128;
  const int bcol = blockIdx.x * 128;
  const int wr = w >> 1, wc = w & 1;

  f32x4 acc[4][4];
#pragma unroll
  for (int m = 0; m < 4; ++m)
#pragma unroll
    for (int n = 0; n < 4; ++n) acc[m][n] = (f32x4){0.f, 0.f, 0.f, 0.f};

  for (int kt = 0; kt < K; kt += 64) {
#pragma unroll
    for (int j = 0; j < 4; ++j) {
      int c = j * 4 + w;              // chunk 0..15 (wave-uniform)
      int li = c * 64 + lane;         // 16B unit index
      int row = li >> 3, col8 = li & 7;
      int ar = brow + row; if (ar > M - 1) ar = M - 1;
      __builtin_amdgcn_global_load_lds(
          (const __attribute__((address_space(1))) void*)(A + (size_t)ar * K + kt + col8 * 8),
          (__attribute__((address_space(3))) void*)(As + c * 512), 16, 0, 0);
      __builtin_amdgcn_global_load_lds(
          (const __attribute__((address_space(1))) void*)(BT + (size_t)(bcol + row) * K + kt + col8 * 8),
          (__attribute__((address_space(3))) void*)(Bs + c * 512), 16, 0, 0);
    }
    __syncthreads();
    bf16x8 af[4][2], bb[4][2];
#pragma unroll
    for (int kk = 0; kk < 2; ++kk) {
      int kof = kk * 32 + (lane >> 4) * 8;
#pragma unroll
      for (int m = 0; m < 4; ++m)
        af[m][kk] = *(const bf16x8*)(As + (wr * 64 + m * 16 + (lane & 15)) * 64 + kof);
#pragma unroll
      for (int n = 0; n < 4; ++n)
        bb[n][kk] = *(const bf16x8*)(Bs + (wc * 64 + n * 16 + (lane & 15)) * 64 + kof);
    }
#pragma unroll
    for (int kk = 0; kk < 2; ++kk)
#pragma unroll
      for (int m = 0; m < 4; ++m)
#pragma unroll
        for (int n = 0; n < 4; ++n)
          acc[m][n] = __builtin_amdgcn_mfma_f32_16x16x32_bf16(af[m][kk], bb[n][kk], acc[m][n], 0, 0, 0);
    __syncthreads();
  }
#pragma unroll
  for (int m = 0; m < 4; ++m) {
    int r0 = brow + wr * 64 + m * 16 + (lane >> 4) * 4;
#pragma unroll
    for (int n = 0; n < 4; ++n) {
      int col = bcol + wc * 64 + n * 16 + (lane & 15);
      float bv = BIAS ? bias[col] : 0.0f;
#pragma unroll
      for (int q = 0; q < 4; ++q) {
        int rr = r0 + q;
        if (rr < M) {
          float v = acc[m][n][q] + bv;
          if (RELU) v = fmaxf(v, 0.0f);
          stor(&C[(size_t)rr * ldc + coloff + col], v);
        }
      }
    }
  }
}

// ---------------- small f32 GEMM (proj heads) ----------------
template <typename TA, typename TC, bool RELU, bool BIAS>
__global__ __launch_bounds__(256) void k_gemm(const TA* __restrict__ A, const float* __restrict__ B,
                                              const float* __restrict__ bias, TC* __restrict__ C,
                                              int M, int N, int K) {
  __shared__ float As[64][17];
  __shared__ float Bs[16][65];
  const int tx = threadIdx.x & 15;
  const int ty = threadIdx.x >> 4;
  const int row0 = blockIdx.y * 64;
  const int col0 = blockIdx.x * 64;
  float acc[4][4] = {};
  for (int k0 = 0; k0 < K; k0 += 16) {
#pragma unroll
    for (int i = 0; i < 4; ++i) {
      int lin = threadIdx.x + i * 256;
      int r = lin >> 4, c = lin & 15;
      int gr = row0 + r;
      As[r][c] = (gr < M) ? cvt(A[(size_t)gr * K + k0 + c]) : 0.0f;
    }
#pragma unroll
    for (int i = 0; i < 4; ++i) {
      int lin = threadIdx.x + i * 256;
      int r = lin >> 6, c = lin & 63;
      Bs[r][c] = B[(size_t)(k0 + r) * N + col0 + c];
    }
    __syncthreads();
#pragma unroll
    for (int k = 0; k < 16; ++k) {
      float a[4], b[4];
#pragma unroll
      for (int i = 0; i < 4; ++i) a[i] = As[ty * 4 + i][k];
#pragma unroll
      for (int j = 0; j < 4; ++j) b[j] = Bs[k][tx * 4 + j];
#pragma unroll
      for (int i = 0; i < 4; ++i)
#pragma unroll
        for (int j = 0; j < 4; ++j) acc[i][j] += a[i] * b[j];
    }
    __syncthreads();
  }
#pragma unroll
  for (int i = 0; i < 4; ++i) {
    int gr = row0 + ty * 4 + i;
    if (gr < M) {
#pragma unroll
      for (int j = 0; j < 4; ++j) {
        int gc = col0 + tx * 4 + j;
        float v = acc[i][j];
        if (BIAS) v += bias[gc];
        if (RELU) v = fmaxf(v, 0.0f);
        stor(&C[(size_t)gr * N + gc], v);
      }
    }
  }
}

__global__ void k_split(const float* __restrict__ pg3, float* __restrict__ h_g,
                        float* __restrict__ hhat_g) {
  int i = blockIdx.x * 256 + threadIdx.x;  // 8192 = 128x64
  if (i < 8192) {
    int r = i >> 6;
    if (r < 64) h_g[i] = pg3[i];
    else hhat_g[i - 4096] = pg3[i];
  }
}

// ---------------- pooling: two-stage deterministic reduction ----------------
__device__ inline int lbound(const int* a, int n, int v) {
  int lo = 0, hi = n;
  while (lo < hi) { int mid = (lo + hi) >> 1; if (a[mid] < v) lo = mid + 1; else hi = mid; }
  return lo;
}

#define POOL_NCH 32

__global__ __launch_bounds__(256) void k_pool_partial(const float* __restrict__ z,
                                                      const int* __restrict__ batch,
                                                      float* __restrict__ psum, float* __restrict__ pmax,
                                                      int n) {
  int g = blockIdx.x, ch = blockIdx.y;
  __shared__ int ss, se;
  if (threadIdx.x == 0) { ss = lbound(batch, n, g); se = lbound(batch, n, g + 1); }
  __syncthreads();
  int start = ss, len = se - ss;
  int c0 = start + (int)((long long)len * ch / POOL_NCH);
  int c1 = start + (int)((long long)len * (ch + 1) / POOL_NCH);
  int f = threadIdx.x;
  float acc = 0.0f, mx = -INFINITY;
  for (int i = c0; i < c1; ++i) {
    float v = z[(size_t)i * 256 + f];
    acc += v;
    mx = fmaxf(mx, v);
  }
  size_t o = ((size_t)g * POOL_NCH + ch) * 256 + f;
  psum[o] = acc;
  pmax[o] = mx;
}

// stage 2: writes zg (d_out layout) AND gcat row (stacked proj input)
__global__ __launch_bounds__(256) void k_pool_final(const float* __restrict__ psum,
                                                    const float* __restrict__ pmax,
                                                    const int* __restrict__ batch,
                                                    float* __restrict__ zg, float* __restrict__ gcat,
                                                    int rowoff, int n) {
  int g = blockIdx.x, f = threadIdx.x;
  float s = 0.0f, m = -INFINITY;
#pragma unroll 4
  for (int c = 0; c < POOL_NCH; ++c) {
    size_t o = ((size_t)g * POOL_NCH + c) * 256 + f;
    s += psum[o];
    m = fmaxf(m, pmax[o]);
  }
  __shared__ int ss, se;
  if (threadIdx.x == 0) { ss = lbound(batch, n, g); se = lbound(batch, n, g + 1); }
  __syncthreads();
  int cnt = se - ss;
  float mean = s / fmaxf((float)cnt, 1.0f);
  float mxo = (cnt > 0) ? m : 0.0f;
  zg[(size_t)g * 512 + f] = mean;
  zg[(size_t)g * 512 + 256 + f] = mxo;
  gcat[(size_t)(rowoff + g) * 512 + f] = mean;
  gcat[(size_t)(rowoff + g) * 512 + 256 + f] = mxo;
}

// ---------------- launch ----------------
extern "C" void kernel_launch(void* const* d_in, const int* in_sizes, int n_in,
                              void* d_out, int out_size, void* d_ws, size_t ws_size,
                              hipStream_t stream) {
  const float* x   = (const float*)d_in[0];
  const int*   ei  = (const int*)d_in[1];
  const int*   bat = (const int*)d_in[2];
  const float* W1  = (const float*)d_in[4];
  const float* b1  = (const float*)d_in[5];
  const float* W2  = (const float*)d_in[6];
  const float* b2  = (const float*)d_in[7];
  const float* Wd  = (const float*)d_in[8];
  const float* bd  = (const float*)d_in[9];
  const float* P1w = (const float*)d_in[10];
  const float* P1b = (const float*)d_in[11];
  const float* P2w = (const float*)d_in[12];
  const float* P2b = (const float*)d_in[13];
  const float* P3w = (const float*)d_in[14];
  const float* P3b = (const float*)d_in[15];

  const int N = in_sizes[0] / 128;  // 50000
  const int E = in_sizes[1] / 2;    // 400000
  const int B = 64;
  const int NB = (N + 1023) / 1024;

  char* w = (char*)d_ws;
  auto carve = [&](size_t bytes) -> void* {
    void* p = (void*)w;
    w += (bytes + 255) & ~(size_t)255;
    return p;
  };
  int*    cnt        = (int*)carve((size_t)N * 4);
  int*    row_ptr    = (int*)carve((size_t)(N + 1) * 4);
  int*    cursor     = (int*)carve((size_t)N * 4);
  float*  dinv       = (float*)carve((size_t)N * 4);
  int*    incl       = (int*)carve((size_t)N * 4);
  int*    bsum       = (int*)carve((size_t)1024 * 4);
  int*    src_sorted = (int*)carve((size_t)E * 4);
  float*  w_sorted   = (float*)carve((size_t)E * 4);
  float*  sigma      = (float*)carve(256);
  double* psd        = (double*)carve((size_t)64 * 2 * 8);
  float*  W1h        = (float*)carve((size_t)128 * 512 * 4);
  float*  b1h        = (float*)carve((size_t)512 * 4);
  float*  W2h        = (float*)carve((size_t)512 * 256 * 4);
  float*  b2h        = (float*)carve((size_t)256 * 4);
  float*  bcat       = (float*)carve((size_t)512 * 4);
  u16*    W1T        = (u16*)carve((size_t)128 * 512 * 2);
  u16*    W2T        = (u16*)carve((size_t)512 * 256 * 2);
  u16*    WdT        = (u16*)carve((size_t)256 * 128 * 2);
  u16*    W1hT       = (u16*)carve((size_t)128 * 512 * 2);
  u16*    W2hT       = (u16*)carve((size_t)512 * 256 * 2);
  u16*    xb         = (u16*)carve((size_t)N * 128 * 2);
  u16*    px         = (u16*)carve((size_t)N * 128 * 2);
  u16*    z1         = (u16*)carve((size_t)N * 512 * 2);   // L1 scratch (reused both branches)
  u16*    ycat       = (u16*)carve((size_t)N * 512 * 2);   // [y_clean | y_pert]; later aliased as yd
  u16*    znb        = (u16*)carve((size_t)N * 256 * 2);   // bf16 z_node (decoder A)
  float*  gcat       = (float*)carve((size_t)128 * 512 * 4);
  float*  pg1        = (float*)carve((size_t)128 * 256 * 4);
  float*  pg2        = (float*)carve((size_t)128 * 128 * 4);
  float*  pg3        = (float*)carve((size_t)128 * 64 * 4);
  float*  psum       = (float*)carve((size_t)B * POOL_NCH * 256 * 4);
  float*  pmax       = (float*)carve((size_t)B * POOL_NCH * 256 * 4);
  u16*    yd         = ycat;  // alias: ycat dead after k_agg512

  float* out       = (float*)d_out;
  float* z_node    = out;
  float* z_g       = z_node + (size_t)N * 256;
  float* zhat_node = z_g + (size_t)B * 512;
  float* zhat_g    = zhat_node + (size_t)N * 256;
  float* h_g       = zhat_g + (size_t)B * 512;
  float* hhat_g    = h_g + (size_t)B * 64;
  float* x_hat     = hhat_g + (size_t)B * 64;

  // nk = split(key(42), 4): nk[i] = threefry(key, (0, i))
  u32 nk[4][2];
  for (u32 i = 0; i < 4; ++i) tf2x32(0u, 42u, 0u, i, &nk[i][0], &nk[i][1]);

  // --- graph preprocessing ---
  hipMemsetAsync(cnt, 0, (size_t)N * 4, stream);
  k_count<<<(E + 255) / 256, 256, 0, stream>>>(ei, cnt, E);
  k_scan_local<<<NB, 1024, 0, stream>>>(cnt, incl, bsum, N);
  k_scan_bsum<<<1, 1024, 0, stream>>>(bsum, NB);
  k_scan_final<<<NB, 1024, 0, stream>>>(cnt, incl, bsum, row_ptr, cursor, dinv, N, E);
  k_place<<<(E + 255) / 256, 256, 0, stream>>>(ei, cursor, dinv, src_sorted, w_sorted, E);

  // --- perturbed weights ---
  k_std1<<<64, 256, 0, stream>>>(W1, 128 * 512, b1, 512, W2, 512 * 256, b2, 256, psd);
  k_std2<<<1, 64, 0, stream>>>(psd, 128 * 512, 512, 512 * 256, 256, sigma);
  k_perturb<<<(65536 + 255) / 256, 256, 0, stream>>>(W1, W1h, 128 * 512, nk[0][0], nk[0][1], sigma, 0);
  k_perturb<<<2, 256, 0, stream>>>(b1, b1h, 512, nk[1][0], nk[1][1], sigma, 1);
  k_perturb<<<(131072 + 255) / 256, 256, 0, stream>>>(W2, W2h, 512 * 256, nk[2][0], nk[2][1], sigma, 2);
  k_perturb<<<1, 256, 0, stream>>>(b2, b2h, 256, nk[3][0], nk[3][1], sigma, 3);
  k_bcat<<<1, 512, 0, stream>>>(b2, b2h, bcat);

  // --- bf16 transposed weight panels + bf16 x ---
  k_transpose<<<(65536 + 255) / 256, 256, 0, stream>>>(W1, W1T, 128, 512);
  k_transpose<<<(131072 + 255) / 256, 256, 0, stream>>>(W2, W2T, 512, 256);
  k_transpose<<<(32768 + 255) / 256, 256, 0, stream>>>(Wd, WdT, 256, 128);
  k_transpose<<<(65536 + 255) / 256, 256, 0, stream>>>(W1h, W1hT, 128, 512);
  k_transpose<<<(131072 + 255) / 256, 256, 0, stream>>>(W2h, W2hT, 512, 256);
  k_bf16cast<<<((N * 128 / 4) + 255) / 256, 256, 0, stream>>>(x, xb, N * 128 / 4);

  const int aggBlocks = (N + 3) / 4;

  // px = P @ x (shared by both branches), gathering bf16 x
  k_agg_px<<<aggBlocks, 256, 0, stream>>>(xb, px, row_ptr, src_sorted, w_sorted, dinv, N);

  const int MB = (N + 127) / 128;
  dim3 m512(4, MB), m256(2, MB), m128(1, MB);

  // perturbed branch L1+L2 -> ycat cols 256-511
  k_mgemm<true, true, u16><<<m512, 256, 0, stream>>>(px, W1hT, b1h, z1, N, 512, 128, 512, 0);
  k_mgemm<false, false, u16><<<m256, 256, 0, stream>>>(z1, W2hT, nullptr, ycat, N, 256, 512, 512, 256);
  // clean branch L1+L2 -> ycat cols 0-255 (z1 reused)
  k_mgemm<true, true, u16><<<m512, 256, 0, stream>>>(px, W1T, b1, z1, N, 512, 128, 512, 0);
  k_mgemm<false, false, u16><<<m256, 256, 0, stream>>>(z1, W2T, nullptr, ycat, N, 256, 512, 512, 0);

  // single merged aggregation pass: z_node (+znb bf16) and zhat_node
  k_agg512<<<aggBlocks, 256, 0, stream>>>(ycat, z_node, znb, zhat_node,
                                          row_ptr, src_sorted, w_sorted, dinv, bcat, N);

  // pooling (two-stage), dual-writing gcat for stacked proj heads
  dim3 pgrid(B, POOL_NCH);
  k_pool_partial<<<pgrid, 256, 0, stream>>>(z_node, bat, psum, pmax, N);
  k_pool_final<<<B, 256, 0, stream>>>(psum, pmax, bat, z_g, gcat, 0, N);
  k_pool_partial<<<pgrid, 256, 0, stream>>>(zhat_node, bat, psum, pmax, N);
  k_pool_final<<<B, 256, 0, stream>>>(psum, pmax, bat, zhat_g, gcat, 64, N);

  // decoder: x_hat = P @ (z_node @ Wd) + bd   (yd aliases ycat, dead after agg512)
  k_mgemm<false, false, u16><<<m128, 256, 0, stream>>>(znb, WdT, nullptr, yd, N, 128, 256, 128, 0);
  k_agg_dec<<<aggBlocks, 256, 0, stream>>>(yd, x_hat, row_ptr, src_sorted, w_sorted, dinv, bd, N);

  // stacked projection heads: [z_g; zhat_g] (128 rows)
  dim3 q1(4, 2), q2(2, 2), q3(1, 2);
  k_gemm<float, float, true, true><<<q1, 256, 0, stream>>>(gcat, P1w, P1b, pg1, 128, 256, 512);
  k_gemm<float, float, true, true><<<q2, 256, 0, stream>>>(pg1, P2w, P2b, pg2, 128, 128, 256);
  k_gemm<float, float, false, true><<<q3, 256, 0, stream>>>(pg2, P3w, P3b, pg3, 128, 64, 128);
  k_split<<<32, 256, 0, stream>>>(pg3, h_g, hhat_g);
}

// Round 8
// 565.237 us; speedup vs baseline: 3.5319x; 1.0250x over previous
//
#include <hip/hip_runtime.h>

typedef unsigned short u16;
typedef unsigned int u32;
typedef short bf16x8 __attribute__((ext_vector_type(8)));
typedef float f32x4 __attribute__((ext_vector_type(4)));

// ---------------- threefry2x32 (JAX-compatible, 20 rounds) ----------------
__host__ __device__ inline u32 rotl32(u32 x, int r) { return (x << r) | (x >> (32 - r)); }

__host__ __device__ inline void tf_r4(u32& x0, u32& x1, int r0, int r1, int r2, int r3) {
  x0 += x1; x1 = rotl32(x1, r0); x1 ^= x0;
  x0 += x1; x1 = rotl32(x1, r1); x1 ^= x0;
  x0 += x1; x1 = rotl32(x1, r2); x1 ^= x0;
  x0 += x1; x1 = rotl32(x1, r3); x1 ^= x0;
}

__host__ __device__ inline void tf2x32(u32 k0, u32 k1, u32 c0, u32 c1, u32* o0, u32* o1) {
  u32 ks2 = 0x1BD11BDAu ^ k0 ^ k1;
  u32 x0 = c0 + k0, x1 = c1 + k1;
  tf_r4(x0, x1, 13, 15, 26, 6);  x0 += k1;  x1 += ks2 + 1u;
  tf_r4(x0, x1, 17, 29, 16, 24); x0 += ks2; x1 += k0 + 2u;
  tf_r4(x0, x1, 13, 15, 26, 6);  x0 += k0;  x1 += k1 + 3u;
  tf_r4(x0, x1, 17, 29, 16, 24); x0 += k1;  x1 += ks2 + 4u;
  tf_r4(x0, x1, 13, 15, 26, 6);  x0 += ks2; x1 += k0 + 5u;
  *o0 = x0; *o1 = x1;
}

// XLA/Giles f32 erfinv
__device__ inline float erfinv_f(float x) {
  float w = -log1pf(-x * x);
  float p;
  if (w < 5.0f) {
    w -= 2.5f;
    p = 2.81022636e-08f;
    p = 3.43273939e-07f + p * w;
    p = -3.5233877e-06f + p * w;
    p = -4.39150654e-06f + p * w;
    p = 0.00021858087f + p * w;
    p = -0.00125372503f + p * w;
    p = -0.00417768164f + p * w;
    p = 0.246640727f + p * w;
    p = 1.50140941f + p * w;
  } else {
    w = sqrtf(w) - 3.0f;
    p = -0.000200214257f;
    p = 0.000100950558f + p * w;
    p = 0.00134934322f + p * w;
    p = -0.00367342844f + p * w;
    p = 0.00573950773f + p * w;
    p = -0.0076224613f + p * w;
    p = 0.00943887047f + p * w;
    p = 1.00167406f + p * w;
    p = 2.83297682f + p * w;
  }
  return p * x;
}

__device__ inline float bits2normal(u32 b) {
  float f = __uint_as_float((b >> 9) | 0x3F800000u) - 1.0f;  // [0,1)
  float u = f * 2.0f - 0.99999994f;
  u = fmaxf(u, -0.99999994f);
  return 1.41421356f * erfinv_f(u);
}

// ---------------- dtype helpers ----------------
__device__ inline float cvt(float v) { return v; }
__device__ inline float cvt(u16 v) { return __uint_as_float(((u32)v) << 16); }
__device__ inline void stor(float* p, float v) { *p = v; }
__device__ inline void stor(u16* p, float v) {
  u32 x = __float_as_uint(v);
  *p = (u16)((x + 0x7FFFu + ((x >> 16) & 1u)) >> 16);  // RTNE bf16
}
__device__ inline u16 f2b(float v) {
  u32 x = __float_as_uint(v);
  return (u16)((x + 0x7FFFu + ((x >> 16) & 1u)) >> 16);
}
__device__ inline float blo(u32 w) { return __uint_as_float(w << 16); }
__device__ inline float bhi(u32 w) { return __uint_as_float(w & 0xFFFF0000u); }

// ---------------- fused prep A: count + std1 + clean transposes + x cast ----------------
// block ranges: [0,c1) count | [c1,+64) std1 | then W1T(256) W2T(512) WdT(128) xb(n4/256)
__global__ __launch_bounds__(256) void k_prepA(const int* __restrict__ ei, int* __restrict__ cnt, int E,
                                               const float* __restrict__ W1, const float* __restrict__ b1,
                                               const float* __restrict__ W2, const float* __restrict__ b2,
                                               double* __restrict__ psd,
                                               const float* __restrict__ Wd,
                                               u16* __restrict__ W1T, u16* __restrict__ W2T, u16* __restrict__ WdT,
                                               const float* __restrict__ x, u16* __restrict__ xb,
                                               int N, int c1) {
  __shared__ double sh[256];
  __shared__ double sh2[256];
  int b = blockIdx.x;
  if (b < c1) {  // degree count
    int e = b * 256 + threadIdx.x;
    if (e < E) atomicAdd(&cnt[ei[E + e]], 1);
    return;
  }
  b -= c1;
  if (b < 64) {  // std1: 4 tensors x 16 chunks
    int t = b >> 4, ch = b & 15;
    const float* p; int n;
    if (t == 0) { p = W1; n = 128 * 512; }
    else if (t == 1) { p = b1; n = 512; }
    else if (t == 2) { p = W2; n = 512 * 256; }
    else { p = b2; n = 256; }
    int s0 = (int)((long long)n * ch / 16), s1 = (int)((long long)n * (ch + 1) / 16);
    double s = 0.0, ss = 0.0;
    for (int i = s0 + threadIdx.x; i < s1; i += 256) { double v = p[i]; s += v; ss += v * v; }
    sh[threadIdx.x] = s; sh2[threadIdx.x] = ss;
    __syncthreads();
    for (int o = 128; o > 0; o >>= 1) {
      if (threadIdx.x < o) { sh[threadIdx.x] += sh[threadIdx.x + o]; sh2[threadIdx.x] += sh2[threadIdx.x + o]; }
      __syncthreads();
    }
    if (threadIdx.x == 0) { psd[b * 2] = sh[0]; psd[b * 2 + 1] = sh2[0]; }
    return;
  }
  b -= 64;
  if (b < 256) {  // W1T: f32 [128][512] -> bf16 [512][128]
    int j = b * 256 + threadIdx.x;
    int k = j >> 9, n = j & 511;
    W1T[(size_t)n * 128 + k] = f2b(W1[j]);
    return;
  }
  b -= 256;
  if (b < 512) {  // W2T: [512][256] -> [256][512]
    int j = b * 256 + threadIdx.x;
    int k = j >> 8, n = j & 255;
    W2T[(size_t)n * 512 + k] = f2b(W2[j]);
    return;
  }
  b -= 512;
  if (b < 128) {  // WdT: [256][128] -> [128][256]
    int j = b * 256 + threadIdx.x;
    int k = j >> 7, n = j & 127;
    WdT[(size_t)n * 256 + k] = f2b(Wd[j]);
    return;
  }
  b -= 128;
  {  // xb cast: 4 f32 per thread
    int j = b * 256 + threadIdx.x;
    int n4 = N * 128 / 4;
    if (j < n4) {
      float4 v = ((const float4*)x)[j];
      ((u32*)xb)[j * 2] = ((u32)f2b(v.x)) | (((u32)f2b(v.y)) << 16);
      ((u32*)xb)[j * 2 + 1] = ((u32)f2b(v.z)) | (((u32)f2b(v.w)) << 16);
    }
  }
}

__global__ void k_std2(const double* __restrict__ psd, float* __restrict__ sigma) {
  int l = threadIdx.x;  // 64 lanes
  double s = psd[l * 2], ss = psd[l * 2 + 1];
  for (int off = 1; off < 16; off <<= 1) { s += __shfl_xor(s, off); ss += __shfl_xor(ss, off); }
  if ((l & 15) == 0) {
    int t = l >> 4;
    int n = (t == 0) ? 128 * 512 : (t == 1) ? 512 : (t == 2) ? 512 * 256 : 256;
    double mean = s / n;
    double var = (ss - s * mean) / (double)(n - 1);
    if (var < 0.0) var = 0.0;
    sigma[t] = fmaxf((float)sqrt(var), 1e-6f);
  }
}

// ---------------- fused perturb: writes W1hT/W2hT bf16 (transposed) + b1h/b2h/bcat ----------------
// blocks: [0,256) W1 | [256,258) b1 | [258,770) W2 | [770] b2
__global__ __launch_bounds__(256) void k_perturbAll(const float* __restrict__ W1, const float* __restrict__ b1,
                                                    const float* __restrict__ W2, const float* __restrict__ b2,
                                                    u16* __restrict__ W1hT, float* __restrict__ b1h,
                                                    u16* __restrict__ W2hT, float* __restrict__ b2h,
                                                    float* __restrict__ bcat,
                                                    const float* __restrict__ sigma,
                                                    u32 k00, u32 k01, u32 k10, u32 k11,
                                                    u32 k20, u32 k21, u32 k30, u32 k31) {
  int b = blockIdx.x;
  u32 r0, r1;
  if (b < 256) {  // W1 [128][512]
    int j = b * 256 + threadIdx.x;
    tf2x32(k00, k01, 0u, (u32)j, &r0, &r1);
    float v = W1[j] + sigma[0] * bits2normal(r0 ^ r1);
    int k = j >> 9, n = j & 511;
    W1hT[(size_t)n * 128 + k] = f2b(v);
    return;
  }
  b -= 256;
  if (b < 2) {  // b1 [512]
    int j = b * 256 + threadIdx.x;
    tf2x32(k10, k11, 0u, (u32)j, &r0, &r1);
    b1h[j] = b1[j] + sigma[1] * bits2normal(r0 ^ r1);
    return;
  }
  b -= 2;
  if (b < 512) {  // W2 [512][256]
    int j = b * 256 + threadIdx.x;
    tf2x32(k20, k21, 0u, (u32)j, &r0, &r1);
    float v = W2[j] + sigma[2] * bits2normal(r0 ^ r1);
    int k = j >> 8, n = j & 255;
    W2hT[(size_t)n * 512 + k] = f2b(v);
    return;
  }
  {  // b2 [256] + bcat
    int j = threadIdx.x;
    tf2x32(k30, k31, 0u, (u32)j, &r0, &r1);
    float v = b2[j] + sigma[3] * bits2normal(r0 ^ r1);
    b2h[j] = v;
    bcat[256 + j] = v;
    bcat[j] = b2[j];
  }
}

// ---------------- graph preprocessing ----------------
__global__ __launch_bounds__(1024) void k_scan_local(const int* __restrict__ cnt,
                                                     int* __restrict__ incl, int* __restrict__ bsum,
                                                     int n) {
  __shared__ int buf[1024];
  int i = blockIdx.x * 1024 + threadIdx.x;
  int v = (i < n) ? cnt[i] : 0;
  buf[threadIdx.x] = v;
  __syncthreads();
  for (int off = 1; off < 1024; off <<= 1) {
    int t = (threadIdx.x >= off) ? buf[threadIdx.x - off] : 0;
    __syncthreads();
    buf[threadIdx.x] += t;
    __syncthreads();
  }
  if (i < n) incl[i] = buf[threadIdx.x];
  if (threadIdx.x == 1023) bsum[blockIdx.x] = buf[1023];
}

__global__ __launch_bounds__(1024) void k_scan_bsum(int* __restrict__ bsum, int nb) {
  __shared__ int buf[1024];
  int v = (threadIdx.x < nb) ? bsum[threadIdx.x] : 0;
  buf[threadIdx.x] = v;
  __syncthreads();
  for (int off = 1; off < 1024; off <<= 1) {
    int t = (threadIdx.x >= off) ? buf[threadIdx.x - off] : 0;
    __syncthreads();
    buf[threadIdx.x] += t;
    __syncthreads();
  }
  if (threadIdx.x < nb) bsum[threadIdx.x] = buf[threadIdx.x] - v;  // exclusive
}

__global__ __launch_bounds__(1024) void k_scan_final(const int* __restrict__ cnt,
                                                     const int* __restrict__ incl,
                                                     const int* __restrict__ bsum,
                                                     int* __restrict__ row_ptr, int* __restrict__ cursor,
                                                     float* __restrict__ dinv, int n, int E) {
  int i = blockIdx.x * 1024 + threadIdx.x;
  if (i < n) {
    int c = cnt[i];
    int ex = incl[i] + bsum[blockIdx.x] - c;
    row_ptr[i] = ex;
    cursor[i] = ex;
    dinv[i] = 1.0f / sqrtf((float)(c + 1));  // deg includes self-loop
  }
  if (i == 0) row_ptr[n] = E;
}

__global__ void k_place(const int* __restrict__ ei, int* __restrict__ cursor,
                        const float* __restrict__ dinv, int* __restrict__ src_sorted,
                        float* __restrict__ w_sorted, int E) {
  int e = blockIdx.x * blockDim.x + threadIdx.x;
  if (e < E) {
    int s = ei[e], d = ei[E + e];
    int slot = atomicAdd(&cursor[d], 1);
    src_sorted[slot] = s;
    w_sorted[slot] = dinv[s] * dinv[d];
  }
}

// ---------------- CSR aggregations (vectorized + MLP-unrolled) ----------------
__global__ __launch_bounds__(256) void k_agg_px(const u16* __restrict__ xb, u16* __restrict__ px,
                                                const int* __restrict__ rp, const int* __restrict__ src,
                                                const float* __restrict__ wst, const float* __restrict__ dinv,
                                                int n) {
  int wv = threadIdx.x >> 6, lane = threadIdx.x & 63;
  int node = blockIdx.x * 4 + wv;
  if (node >= n) return;
  float a0 = 0.f, a1 = 0.f;
  int s0 = rp[node], s1 = rp[node + 1];
  int s = s0;
  for (; s + 8 <= s1; s += 8) {
    u32 v[8]; float wg[8];
#pragma unroll
    for (int u = 0; u < 8; ++u) {
      int r = src[s + u];
      wg[u] = wst[s + u];
      v[u] = *((const u32*)(xb + (size_t)r * 128) + lane);
    }
#pragma unroll
    for (int u = 0; u < 8; ++u) { a0 += wg[u] * blo(v[u]); a1 += wg[u] * bhi(v[u]); }
  }
  for (; s < s1; ++s) {
    float wgt = wst[s];
    int r = src[s];
    u32 w = *((const u32*)(xb + (size_t)r * 128) + lane);
    a0 += wgt * blo(w); a1 += wgt * bhi(w);
  }
  float sw = dinv[node]; sw *= sw;
  u32 w = *((const u32*)(xb + (size_t)node * 128) + lane);
  a0 += sw * blo(w); a1 += sw * bhi(w);
  u32 o = ((u32)f2b(a0)) | (((u32)f2b(a1)) << 16);
  *((u32*)(px + (size_t)node * 128) + lane) = o;
}

// merged layer-2 agg: ycat bf16 [N][512]; uint4 per lane, 8-deep unroll
__global__ __launch_bounds__(256) void k_agg512(const u16* __restrict__ ycat,
                                                float* __restrict__ zc, u16* __restrict__ zcb,
                                                float* __restrict__ zh,
                                                const int* __restrict__ rp, const int* __restrict__ src,
                                                const float* __restrict__ wst, const float* __restrict__ dinv,
                                                const float* __restrict__ bcat, int n) {
  int wv = threadIdx.x >> 6, lane = threadIdx.x & 63;
  int node = blockIdx.x * 4 + wv;
  if (node >= n) return;
  float acc[8] = {};
  int s0 = rp[node], s1 = rp[node + 1];
  int s = s0;
  for (; s + 8 <= s1; s += 8) {
    uint4 v[8]; float wg[8];
#pragma unroll
    for (int u = 0; u < 8; ++u) {
      int r = src[s + u];
      wg[u] = wst[s + u];
      v[u] = *((const uint4*)(ycat + (size_t)r * 512) + lane);
    }
#pragma unroll
    for (int u = 0; u < 8; ++u)
#pragma unroll
      for (int q = 0; q < 4; ++q) {
        u32 word = ((const u32*)&v[u])[q];
        acc[2 * q]     += wg[u] * blo(word);
        acc[2 * q + 1] += wg[u] * bhi(word);
      }
  }
  for (; s < s1; ++s) {
    float wgt = wst[s];
    int r = src[s];
    uint4 v = *((const uint4*)(ycat + (size_t)r * 512) + lane);
#pragma unroll
    for (int q = 0; q < 4; ++q) {
      u32 word = ((const u32*)&v)[q];
      acc[2 * q]     += wgt * blo(word);
      acc[2 * q + 1] += wgt * bhi(word);
    }
  }
  float sw = dinv[node]; sw *= sw;
  uint4 v = *((const uint4*)(ycat + (size_t)node * 512) + lane);
#pragma unroll
  for (int q = 0; q < 4; ++q) {
    u32 word = ((const u32*)&v)[q];
    acc[2 * q]     += sw * blo(word);
    acc[2 * q + 1] += sw * bhi(word);
  }
  int f0 = lane * 8;
#pragma unroll
  for (int j = 0; j < 8; ++j) acc[j] += bcat[f0 + j];
  if (lane < 32) {
    float* o = zc + (size_t)node * 256 + f0;
    u16* ob = zcb + (size_t)node * 256 + f0;
#pragma unroll
    for (int j = 0; j < 8; ++j) { o[j] = acc[j]; ob[j] = f2b(acc[j]); }
  } else {
    float* o = zh + (size_t)node * 256 + (f0 - 256);
#pragma unroll
    for (int j = 0; j < 8; ++j) o[j] = acc[j];
  }
}

__global__ __launch_bounds__(256) void k_agg_dec(const u16* __restrict__ yd, float* __restrict__ xhat,
                                                 const int* __restrict__ rp, const int* __restrict__ src,
                                                 const float* __restrict__ wst, const float* __restrict__ dinv,
                                                 const float* __restrict__ bd, int n) {
  int wv = threadIdx.x >> 6, lane = threadIdx.x & 63;
  int node = blockIdx.x * 4 + wv;
  if (node >= n) return;
  float a0 = 0.f, a1 = 0.f;
  int s0 = rp[node], s1 = rp[node + 1];
  int s = s0;
  for (; s + 8 <= s1; s += 8) {
    u32 v[8]; float wg[8];
#pragma unroll
    for (int u = 0; u < 8; ++u) {
      int r = src[s + u];
      wg[u] = wst[s + u];
      v[u] = *((const u32*)(yd + (size_t)r * 128) + lane);
    }
#pragma unroll
    for (int u = 0; u < 8; ++u) { a0 += wg[u] * blo(v[u]); a1 += wg[u] * bhi(v[u]); }
  }
  for (; s < s1; ++s) {
    float wgt = wst[s];
    int r = src[s];
    u32 w = *((const u32*)(yd + (size_t)r * 128) + lane);
    a0 += wgt * blo(w); a1 += wgt * bhi(w);
  }
  float sw = dinv[node]; sw *= sw;
  u32 w = *((const u32*)(yd + (size_t)node * 128) + lane);
  a0 += sw * blo(w); a1 += sw * bhi(w);
  float2 o;
  o.x = a0 + bd[lane * 2];
  o.y = a1 + bd[lane * 2 + 1];
  *((float2*)(xhat + (size_t)node * 128) + lane) = o;
}

// ---------------- MFMA bf16 GEMM: C = act(A @ BT^T + bias), ldc/coloff epilogue ----------------
template <bool RELU, bool BIAS, typename TC>
__global__ __launch_bounds__(256) void k_mgemm(const u16* __restrict__ A, const u16* __restrict__ BT,
                                               const float* __restrict__ bias, TC* __restrict__ C,
                                               int M, int N, int K, int ldc, int coloff) {
  __shared__ u16 As[128 * 64];
  __shared__ u16 Bs[128 * 64];
  const int t = threadIdx.x;
  const int w = t >> 6, lane = t & 63;
  const int brow = blockIdx.y * 128;
  const int bcol = blockIdx.x * 128;
  const int wr = w >> 1, wc = w & 1;

  f32x4 acc[4][4];
#pragma unroll
  for (int m = 0; m < 4; ++m)
#pragma unroll
    for (int n = 0; n < 4; ++n) acc[m][n] = (f32x4){0.f, 0.f, 0.f, 0.f};

  for (int kt = 0; kt < K; kt += 64) {
#pragma unroll
    for (int j = 0; j < 4; ++j) {
      int c = j * 4 + w;              // chunk 0..15 (wave-uniform)
      int li = c * 64 + lane;         // 16B unit index
      int row = li >> 3, col8 = li & 7;
      int ar = brow + row; if (ar > M - 1) ar = M - 1;
      __builtin_amdgcn_global_load_lds(
          (const __attribute__((address_space(1))) void*)(A + (size_t)ar * K + kt + col8 * 8),
          (__attribute__((address_space(3))) void*)(As + c * 512), 16, 0, 0);
      __builtin_amdgcn_global_load_lds(
          (const __attribute__((address_space(1))) void*)(BT + (size_t)(bcol + row) * K + kt + col8 * 8),
          (__attribute__((address_space(3))) void*)(Bs + c * 512), 16, 0, 0);
    }
    __syncthreads();
    bf16x8 af[4][2], bb[4][2];
#pragma unroll
    for (int kk = 0; kk < 2; ++kk) {
      int kof = kk * 32 + (lane >> 4) * 8;
#pragma unroll
      for (int m = 0; m < 4; ++m)
        af[m][kk] = *(const bf16x8*)(As + (wr * 64 + m * 16 + (lane & 15)) * 64 + kof);
#pragma unroll
      for (int n = 0; n < 4; ++n)
        bb[n][kk] = *(const bf16x8*)(Bs + (wc * 64 + n * 16 + (lane & 15)) * 64 + kof);
    }
#pragma unroll
    for (int kk = 0; kk < 2; ++kk)
#pragma unroll
      for (int m = 0; m < 4; ++m)
#pragma unroll
        for (int n = 0; n < 4; ++n)
          acc[m][n] = __builtin_amdgcn_mfma_f32_16x16x32_bf16(af[m][kk], bb[n][kk], acc[m][n], 0, 0, 0);
    __syncthreads();
  }
#pragma unroll
  for (int m = 0; m < 4; ++m) {
    int r0 = brow + wr * 64 + m * 16 + (lane >> 4) * 4;
#pragma unroll
    for (int n = 0; n < 4; ++n) {
      int col = bcol + wc * 64 + n * 16 + (lane & 15);
      float bv = BIAS ? bias[col] : 0.0f;
#pragma unroll
      for (int q = 0; q < 4; ++q) {
        int rr = r0 + q;
        if (rr < M) {
          float v = acc[m][n][q] + bv;
          if (RELU) v = fmaxf(v, 0.0f);
          stor(&C[(size_t)rr * ldc + coloff + col], v);
        }
      }
    }
  }
}

// ---------------- small f32 GEMM (proj heads) ----------------
template <typename TA, typename TC, bool RELU, bool BIAS>
__global__ __launch_bounds__(256) void k_gemm(const TA* __restrict__ A, const float* __restrict__ B,
                                              const float* __restrict__ bias, TC* __restrict__ C,
                                              int M, int N, int K) {
  __shared__ float As[64][17];
  __shared__ float Bs[16][65];
  const int tx = threadIdx.x & 15;
  const int ty = threadIdx.x >> 4;
  const int row0 = blockIdx.y * 64;
  const int col0 = blockIdx.x * 64;
  float acc[4][4] = {};
  for (int k0 = 0; k0 < K; k0 += 16) {
#pragma unroll
    for (int i = 0; i < 4; ++i) {
      int lin = threadIdx.x + i * 256;
      int r = lin >> 4, c = lin & 15;
      int gr = row0 + r;
      As[r][c] = (gr < M) ? cvt(A[(size_t)gr * K + k0 + c]) : 0.0f;
    }
#pragma unroll
    for (int i = 0; i < 4; ++i) {
      int lin = threadIdx.x + i * 256;
      int r = lin >> 6, c = lin & 63;
      Bs[r][c] = (col0 + c < N) ? B[(size_t)(k0 + r) * N + col0 + c] : 0.0f;
    }
    __syncthreads();
#pragma unroll
    for (int k = 0; k < 16; ++k) {
      float a[4], b[4];
#pragma unroll
      for (int i = 0; i < 4; ++i) a[i] = As[ty * 4 + i][k];
#pragma unroll
      for (int j = 0; j < 4; ++j) b[j] = Bs[k][tx * 4 + j];
#pragma unroll
      for (int i = 0; i < 4; ++i)
#pragma unroll
        for (int j = 0; j < 4; ++j) acc[i][j] += a[i] * b[j];
    }
    __syncthreads();
  }
#pragma unroll
  for (int i = 0; i < 4; ++i) {
    int gr = row0 + ty * 4 + i;
    if (gr < M) {
#pragma unroll
      for (int j = 0; j < 4; ++j) {
        int gc = col0 + tx * 4 + j;
        if (gc < N) {
          float v = acc[i][j];
          if (BIAS) v += bias[gc];
          if (RELU) v = fmaxf(v, 0.0f);
          stor(&C[(size_t)gr * N + gc], v);
        }
      }
    }
  }
}

// ---------------- pooling: two-stage deterministic reduction (both branches fused) ----------------
__device__ inline int lbound(const int* a, int n, int v) {
  int lo = 0, hi = n;
  while (lo < hi) { int mid = (lo + hi) >> 1; if (a[mid] < v) lo = mid + 1; else hi = mid; }
  return lo;
}

#define POOL_NCH 32

// grid (B, 2*NCH): y < NCH -> clean branch, else perturbed
__global__ __launch_bounds__(256) void k_pool_partial2(const float* __restrict__ zc,
                                                       const float* __restrict__ zh,
                                                       const int* __restrict__ batch,
                                                       float* __restrict__ psum, float* __restrict__ pmax,
                                                       int n) {
  int g = blockIdx.x, yy = blockIdx.y;
  int half = (yy >= POOL_NCH) ? 1 : 0;
  int ch = yy - half * POOL_NCH;
  const float* z = half ? zh : zc;
  __shared__ int ss, se;
  if (threadIdx.x == 0) { ss = lbound(batch, n, g); se = lbound(batch, n, g + 1); }
  __syncthreads();
  int start = ss, len = se - ss;
  int c0 = start + (int)((long long)len * ch / POOL_NCH);
  int c1 = start + (int)((long long)len * (ch + 1) / POOL_NCH);
  int f = threadIdx.x;
  float acc = 0.0f, mx = -INFINITY;
  for (int i = c0; i < c1; ++i) {
    float v = z[(size_t)i * 256 + f];
    acc += v;
    mx = fmaxf(mx, v);
  }
  size_t o = ((size_t)(half * 64 + g) * POOL_NCH + ch) * 256 + f;
  psum[o] = acc;
  pmax[o] = mx;
}

// grid 128: g<64 clean -> z_g + gcat row; g>=64 pert -> zhat_g + gcat row
__global__ __launch_bounds__(256) void k_pool_final2(const float* __restrict__ psum,
                                                     const float* __restrict__ pmax,
                                                     const int* __restrict__ batch,
                                                     float* __restrict__ z_g, float* __restrict__ zhat_g,
                                                     float* __restrict__ gcat, int n) {
  int gg = blockIdx.x, f = threadIdx.x;
  int g = gg & 63, half = gg >> 6;
  float s = 0.0f, m = -INFINITY;
#pragma unroll 4
  for (int c = 0; c < POOL_NCH; ++c) {
    size_t o = ((size_t)gg * POOL_NCH + c) * 256 + f;
    s += psum[o];
    m = fmaxf(m, pmax[o]);
  }
  __shared__ int ss, se;
  if (threadIdx.x == 0) { ss = lbound(batch, n, g); se = lbound(batch, n, g + 1); }
  __syncthreads();
  int cnt = se - ss;
  float mean = s / fmaxf((float)cnt, 1.0f);
  float mxo = (cnt > 0) ? m : 0.0f;
  float* zg = half ? zhat_g : z_g;
  zg[(size_t)g * 512 + f] = mean;
  zg[(size_t)g * 512 + 256 + f] = mxo;
  gcat[(size_t)gg * 512 + f] = mean;
  gcat[(size_t)gg * 512 + 256 + f] = mxo;
}

// ---------------- launch ----------------
extern "C" void kernel_launch(void* const* d_in, const int* in_sizes, int n_in,
                              void* d_out, int out_size, void* d_ws, size_t ws_size,
                              hipStream_t stream) {
  const float* x   = (const float*)d_in[0];
  const int*   ei  = (const int*)d_in[1];
  const int*   bat = (const int*)d_in[2];
  const float* W1  = (const float*)d_in[4];
  const float* b1  = (const float*)d_in[5];
  const float* W2  = (const float*)d_in[6];
  const float* b2  = (const float*)d_in[7];
  const float* Wd  = (const float*)d_in[8];
  const float* bd  = (const float*)d_in[9];
  const float* P1w = (const float*)d_in[10];
  const float* P1b = (const float*)d_in[11];
  const float* P2w = (const float*)d_in[12];
  const float* P2b = (const float*)d_in[13];
  const float* P3w = (const float*)d_in[14];
  const float* P3b = (const float*)d_in[15];

  const int N = in_sizes[0] / 128;  // 50000
  const int E = in_sizes[1] / 2;    // 400000
  const int B = 64;
  const int NB = (N + 1023) / 1024;

  char* w = (char*)d_ws;
  auto carve = [&](size_t bytes) -> void* {
    void* p = (void*)w;
    w += (bytes + 255) & ~(size_t)255;
    return p;
  };
  int*    cnt        = (int*)carve((size_t)N * 4);
  int*    row_ptr    = (int*)carve((size_t)(N + 1) * 4);
  int*    cursor     = (int*)carve((size_t)N * 4);
  float*  dinv       = (float*)carve((size_t)N * 4);
  int*    incl       = (int*)carve((size_t)N * 4);
  int*    bsum       = (int*)carve((size_t)1024 * 4);
  int*    src_sorted = (int*)carve((size_t)E * 4);
  float*  w_sorted   = (float*)carve((size_t)E * 4);
  float*  sigma      = (float*)carve(256);
  double* psd        = (double*)carve((size_t)64 * 2 * 8);
  float*  b1h        = (float*)carve((size_t)512 * 4);
  float*  b2h        = (float*)carve((size_t)256 * 4);
  float*  bcat       = (float*)carve((size_t)512 * 4);
  u16*    W1T        = (u16*)carve((size_t)128 * 512 * 2);
  u16*    W2T        = (u16*)carve((size_t)512 * 256 * 2);
  u16*    WdT        = (u16*)carve((size_t)256 * 128 * 2);
  u16*    W1hT       = (u16*)carve((size_t)128 * 512 * 2);
  u16*    W2hT       = (u16*)carve((size_t)512 * 256 * 2);
  u16*    xb         = (u16*)carve((size_t)N * 128 * 2);
  u16*    px         = (u16*)carve((size_t)N * 128 * 2);
  u16*    z1         = (u16*)carve((size_t)N * 512 * 2);   // L1 scratch (reused both branches)
  u16*    ycat       = (u16*)carve((size_t)N * 512 * 2);   // [y_clean | y_pert]; later aliased as yd
  u16*    znb        = (u16*)carve((size_t)N * 256 * 2);   // bf16 z_node (decoder A)
  float*  gcat       = (float*)carve((size_t)128 * 512 * 4);
  float*  pg1        = (float*)carve((size_t)128 * 256 * 4);
  float*  pg2        = (float*)carve((size_t)128 * 128 * 4);
  float*  psum       = (float*)carve((size_t)2 * B * POOL_NCH * 256 * 4);
  float*  pmax       = (float*)carve((size_t)2 * B * POOL_NCH * 256 * 4);
  u16*    yd         = ycat;  // alias: ycat dead after k_agg512

  float* out       = (float*)d_out;
  float* z_node    = out;
  float* z_g       = z_node + (size_t)N * 256;
  float* zhat_node = z_g + (size_t)B * 512;
  float* zhat_g    = zhat_node + (size_t)N * 256;
  float* h_g       = zhat_g + (size_t)B * 512;
  // hhat_g = h_g + 4096 (contiguous) -> last proj GEMM writes both via M=128, ldc=64
  float* x_hat     = h_g + (size_t)2 * B * 64;

  // nk = split(key(42), 4): nk[i] = threefry(key, (0, i))
  u32 nk[4][2];
  for (u32 i = 0; i < 4; ++i) tf2x32(0u, 42u, 0u, i, &nk[i][0], &nk[i][1]);

  // --- fused prep: count + std1 + clean transposes + xb cast ---
  const int c1 = (E + 255) / 256;
  const int n4b = (N * 128 / 4 + 255) / 256;
  const int prepABlocks = c1 + 64 + 256 + 512 + 128 + n4b;
  hipMemsetAsync(cnt, 0, (size_t)N * 4, stream);
  k_prepA<<<prepABlocks, 256, 0, stream>>>(ei, cnt, E, W1, b1, W2, b2, psd,
                                           Wd, W1T, W2T, WdT, x, xb, N, c1);

  // --- scan + CSR build ---
  k_scan_local<<<NB, 1024, 0, stream>>>(cnt, incl, bsum, N);
  k_scan_bsum<<<1, 1024, 0, stream>>>(bsum, NB);
  k_scan_final<<<NB, 1024, 0, stream>>>(cnt, incl, bsum, row_ptr, cursor, dinv, N, E);
  k_place<<<(E + 255) / 256, 256, 0, stream>>>(ei, cursor, dinv, src_sorted, w_sorted, E);

  // --- sigma + fused perturb (writes transposed bf16 panels directly) ---
  k_std2<<<1, 64, 0, stream>>>(psd, sigma);
  k_perturbAll<<<771, 256, 0, stream>>>(W1, b1, W2, b2, W1hT, b1h, W2hT, b2h, bcat, sigma,
                                        nk[0][0], nk[0][1], nk[1][0], nk[1][1],
                                        nk[2][0], nk[2][1], nk[3][0], nk[3][1]);

  const int aggBlocks = (N + 3) / 4;

  // px = P @ x (shared by both branches)
  k_agg_px<<<aggBlocks, 256, 0, stream>>>(xb, px, row_ptr, src_sorted, w_sorted, dinv, N);

  const int MB = (N + 127) / 128;
  dim3 m512(4, MB), m256(2, MB), m128(1, MB);

  // perturbed branch L1+L2 -> ycat cols 256-511
  k_mgemm<true, true, u16><<<m512, 256, 0, stream>>>(px, W1hT, b1h, z1, N, 512, 128, 512, 0);
  k_mgemm<false, false, u16><<<m256, 256, 0, stream>>>(z1, W2hT, nullptr, ycat, N, 256, 512, 512, 256);
  // clean branch L1+L2 -> ycat cols 0-255 (z1 reused)
  k_mgemm<true, true, u16><<<m512, 256, 0, stream>>>(px, W1T, b1, z1, N, 512, 128, 512, 0);
  k_mgemm<false, false, u16><<<m256, 256, 0, stream>>>(z1, W2T, nullptr, ycat, N, 256, 512, 512, 0);

  // single merged aggregation pass: z_node (+znb bf16) and zhat_node
  k_agg512<<<aggBlocks, 256, 0, stream>>>(ycat, z_node, znb, zhat_node,
                                          row_ptr, src_sorted, w_sorted, dinv, bcat, N);

  // pooling (two-stage, both branches per launch)
  dim3 pgrid(B, 2 * POOL_NCH);
  k_pool_partial2<<<pgrid, 256, 0, stream>>>(z_node, zhat_node, bat, psum, pmax, N);
  k_pool_final2<<<128, 256, 0, stream>>>(psum, pmax, bat, z_g, zhat_g, gcat, N);

  // decoder: x_hat = P @ (z_node @ Wd) + bd   (yd aliases ycat, dead after agg512)
  k_mgemm<false, false, u16><<<m128, 256, 0, stream>>>(znb, WdT, nullptr, yd, N, 128, 256, 128, 0);
  k_agg_dec<<<aggBlocks, 256, 0, stream>>>(yd, x_hat, row_ptr, src_sorted, w_sorted, dinv, bd, N);

  // stacked projection heads: [z_g; zhat_g] (128 rows); last GEMM writes h_g||hhat_g directly
  dim3 q1(4, 2), q2(2, 2), q3(1, 2);
  k_gemm<float, float, true, true><<<q1, 256, 0, stream>>>(gcat, P1w, P1b, pg1, 128, 256, 512);
  k_gemm<float, float, true, true><<<q2, 256, 0, stream>>>(pg1, P2w, P2b, pg2, 128, 128, 256);
  k_gemm<float, float, false, true><<<q3, 256, 0, stream>>>(pg2, P3w, P3b, h_g, 128, 64, 128);
}

// Round 9
// 558.366 us; speedup vs baseline: 3.5754x; 1.0123x over previous
//
#include <hip/hip_runtime.h>

typedef unsigned short u16;
typedef unsigned int u32;
typedef short bf16x8 __attribute__((ext_vector_type(8)));
typedef float f32x4 __attribute__((ext_vector_type(4)));

// ---------------- threefry2x32 (JAX-compatible, 20 rounds) ----------------
__host__ __device__ inline u32 rotl32(u32 x, int r) { return (x << r) | (x >> (32 - r)); }

__host__ __device__ inline void tf_r4(u32& x0, u32& x1, int r0, int r1, int r2, int r3) {
  x0 += x1; x1 = rotl32(x1, r0); x1 ^= x0;
  x0 += x1; x1 = rotl32(x1, r1); x1 ^= x0;
  x0 += x1; x1 = rotl32(x1, r2); x1 ^= x0;
  x0 += x1; x1 = rotl32(x1, r3); x1 ^= x0;
}

__host__ __device__ inline void tf2x32(u32 k0, u32 k1, u32 c0, u32 c1, u32* o0, u32* o1) {
  u32 ks2 = 0x1BD11BDAu ^ k0 ^ k1;
  u32 x0 = c0 + k0, x1 = c1 + k1;
  tf_r4(x0, x1, 13, 15, 26, 6);  x0 += k1;  x1 += ks2 + 1u;
  tf_r4(x0, x1, 17, 29, 16, 24); x0 += ks2; x1 += k0 + 2u;
  tf_r4(x0, x1, 13, 15, 26, 6);  x0 += k0;  x1 += k1 + 3u;
  tf_r4(x0, x1, 17, 29, 16, 24); x0 += k1;  x1 += ks2 + 4u;
  tf_r4(x0, x1, 13, 15, 26, 6);  x0 += ks2; x1 += k0 + 5u;
  *o0 = x0; *o1 = x1;
}

// XLA/Giles f32 erfinv
__device__ inline float erfinv_f(float x) {
  float w = -log1pf(-x * x);
  float p;
  if (w < 5.0f) {
    w -= 2.5f;
    p = 2.81022636e-08f;
    p = 3.43273939e-07f + p * w;
    p = -3.5233877e-06f + p * w;
    p = -4.39150654e-06f + p * w;
    p = 0.00021858087f + p * w;
    p = -0.00125372503f + p * w;
    p = -0.00417768164f + p * w;
    p = 0.246640727f + p * w;
    p = 1.50140941f + p * w;
  } else {
    w = sqrtf(w) - 3.0f;
    p = -0.000200214257f;
    p = 0.000100950558f + p * w;
    p = 0.00134934322f + p * w;
    p = -0.00367342844f + p * w;
    p = 0.00573950773f + p * w;
    p = -0.0076224613f + p * w;
    p = 0.00943887047f + p * w;
    p = 1.00167406f + p * w;
    p = 2.83297682f + p * w;
  }
  return p * x;
}

__device__ inline float bits2normal(u32 b) {
  float f = __uint_as_float((b >> 9) | 0x3F800000u) - 1.0f;  // [0,1)
  float u = f * 2.0f - 0.99999994f;
  u = fmaxf(u, -0.99999994f);
  return 1.41421356f * erfinv_f(u);
}

// ---------------- dtype helpers ----------------
__device__ inline float cvt(float v) { return v; }
__device__ inline float cvt(u16 v) { return __uint_as_float(((u32)v) << 16); }
__device__ inline void stor(float* p, float v) { *p = v; }
__device__ inline void stor(u16* p, float v) {
  u32 x = __float_as_uint(v);
  *p = (u16)((x + 0x7FFFu + ((x >> 16) & 1u)) >> 16);  // RTNE bf16
}
__device__ inline u16 f2b(float v) {
  u32 x = __float_as_uint(v);
  return (u16)((x + 0x7FFFu + ((x >> 16) & 1u)) >> 16);
}
__device__ inline float blo(u32 w) { return __uint_as_float(w << 16); }
__device__ inline float bhi(u32 w) { return __uint_as_float(w & 0xFFFF0000u); }

// ---------------- fused prep A: count + std1 + clean transposes + x cast ----------------
__global__ __launch_bounds__(256) void k_prepA(const int* __restrict__ ei, int* __restrict__ cnt, int E,
                                               const float* __restrict__ W1, const float* __restrict__ b1,
                                               const float* __restrict__ W2, const float* __restrict__ b2,
                                               double* __restrict__ psd,
                                               const float* __restrict__ Wd,
                                               u16* __restrict__ W1T, u16* __restrict__ W2T, u16* __restrict__ WdT,
                                               const float* __restrict__ x, u16* __restrict__ xb,
                                               int N, int c1) {
  __shared__ double sh[256];
  __shared__ double sh2[256];
  int b = blockIdx.x;
  if (b < c1) {  // degree count
    int e = b * 256 + threadIdx.x;
    if (e < E) atomicAdd(&cnt[ei[E + e]], 1);
    return;
  }
  b -= c1;
  if (b < 64) {  // std1: 4 tensors x 16 chunks
    int t = b >> 4, ch = b & 15;
    const float* p; int n;
    if (t == 0) { p = W1; n = 128 * 512; }
    else if (t == 1) { p = b1; n = 512; }
    else if (t == 2) { p = W2; n = 512 * 256; }
    else { p = b2; n = 256; }
    int s0 = (int)((long long)n * ch / 16), s1 = (int)((long long)n * (ch + 1) / 16);
    double s = 0.0, ss = 0.0;
    for (int i = s0 + threadIdx.x; i < s1; i += 256) { double v = p[i]; s += v; ss += v * v; }
    sh[threadIdx.x] = s; sh2[threadIdx.x] = ss;
    __syncthreads();
    for (int o = 128; o > 0; o >>= 1) {
      if (threadIdx.x < o) { sh[threadIdx.x] += sh[threadIdx.x + o]; sh2[threadIdx.x] += sh2[threadIdx.x + o]; }
      __syncthreads();
    }
    if (threadIdx.x == 0) { psd[b * 2] = sh[0]; psd[b * 2 + 1] = sh2[0]; }
    return;
  }
  b -= 64;
  if (b < 256) {  // W1T: f32 [128][512] -> bf16 [512][128]
    int j = b * 256 + threadIdx.x;
    int k = j >> 9, n = j & 511;
    W1T[(size_t)n * 128 + k] = f2b(W1[j]);
    return;
  }
  b -= 256;
  if (b < 512) {  // W2T: [512][256] -> [256][512]
    int j = b * 256 + threadIdx.x;
    int k = j >> 8, n = j & 255;
    W2T[(size_t)n * 512 + k] = f2b(W2[j]);
    return;
  }
  b -= 512;
  if (b < 128) {  // WdT: [256][128] -> [128][256]
    int j = b * 256 + threadIdx.x;
    int k = j >> 7, n = j & 127;
    WdT[(size_t)n * 256 + k] = f2b(Wd[j]);
    return;
  }
  b -= 128;
  {  // xb cast: 4 f32 per thread
    int j = b * 256 + threadIdx.x;
    int n4 = N * 128 / 4;
    if (j < n4) {
      float4 v = ((const float4*)x)[j];
      ((u32*)xb)[j * 2] = ((u32)f2b(v.x)) | (((u32)f2b(v.y)) << 16);
      ((u32*)xb)[j * 2 + 1] = ((u32)f2b(v.z)) | (((u32)f2b(v.w)) << 16);
    }
  }
}

__global__ void k_std2(const double* __restrict__ psd, float* __restrict__ sigma) {
  int l = threadIdx.x;  // 64 lanes
  double s = psd[l * 2], ss = psd[l * 2 + 1];
  for (int off = 1; off < 16; off <<= 1) { s += __shfl_xor(s, off); ss += __shfl_xor(ss, off); }
  if ((l & 15) == 0) {
    int t = l >> 4;
    int n = (t == 0) ? 128 * 512 : (t == 1) ? 512 : (t == 2) ? 512 * 256 : 256;
    double mean = s / n;
    double var = (ss - s * mean) / (double)(n - 1);
    if (var < 0.0) var = 0.0;
    sigma[t] = fmaxf((float)sqrt(var), 1e-6f);
  }
}

// ---------------- fused perturb ----------------
__global__ __launch_bounds__(256) void k_perturbAll(const float* __restrict__ W1, const float* __restrict__ b1,
                                                    const float* __restrict__ W2, const float* __restrict__ b2,
                                                    u16* __restrict__ W1hT, float* __restrict__ b1h,
                                                    u16* __restrict__ W2hT, float* __restrict__ b2h,
                                                    float* __restrict__ bcat,
                                                    const float* __restrict__ sigma,
                                                    u32 k00, u32 k01, u32 k10, u32 k11,
                                                    u32 k20, u32 k21, u32 k30, u32 k31) {
  int b = blockIdx.x;
  u32 r0, r1;
  if (b < 256) {  // W1 [128][512]
    int j = b * 256 + threadIdx.x;
    tf2x32(k00, k01, 0u, (u32)j, &r0, &r1);
    float v = W1[j] + sigma[0] * bits2normal(r0 ^ r1);
    int k = j >> 9, n = j & 511;
    W1hT[(size_t)n * 128 + k] = f2b(v);
    return;
  }
  b -= 256;
  if (b < 2) {  // b1 [512]
    int j = b * 256 + threadIdx.x;
    tf2x32(k10, k11, 0u, (u32)j, &r0, &r1);
    b1h[j] = b1[j] + sigma[1] * bits2normal(r0 ^ r1);
    return;
  }
  b -= 2;
  if (b < 512) {  // W2 [512][256]
    int j = b * 256 + threadIdx.x;
    tf2x32(k20, k21, 0u, (u32)j, &r0, &r1);
    float v = W2[j] + sigma[2] * bits2normal(r0 ^ r1);
    int k = j >> 8, n = j & 255;
    W2hT[(size_t)n * 512 + k] = f2b(v);
    return;
  }
  {  // b2 [256] + bcat
    int j = threadIdx.x;
    tf2x32(k30, k31, 0u, (u32)j, &r0, &r1);
    float v = b2[j] + sigma[3] * bits2normal(r0 ^ r1);
    b2h[j] = v;
    bcat[256 + j] = v;
    bcat[j] = b2[j];
  }
}

// ---------------- graph preprocessing ----------------
__global__ __launch_bounds__(1024) void k_scan_local(const int* __restrict__ cnt,
                                                     int* __restrict__ incl, int* __restrict__ bsum,
                                                     int n) {
  __shared__ int buf[1024];
  int i = blockIdx.x * 1024 + threadIdx.x;
  int v = (i < n) ? cnt[i] : 0;
  buf[threadIdx.x] = v;
  __syncthreads();
  for (int off = 1; off < 1024; off <<= 1) {
    int t = (threadIdx.x >= off) ? buf[threadIdx.x - off] : 0;
    __syncthreads();
    buf[threadIdx.x] += t;
    __syncthreads();
  }
  if (i < n) incl[i] = buf[threadIdx.x];
  if (threadIdx.x == 1023) bsum[blockIdx.x] = buf[1023];
}

__global__ __launch_bounds__(1024) void k_scan_bsum(int* __restrict__ bsum, int nb) {
  __shared__ int buf[1024];
  int v = (threadIdx.x < nb) ? bsum[threadIdx.x] : 0;
  buf[threadIdx.x] = v;
  __syncthreads();
  for (int off = 1; off < 1024; off <<= 1) {
    int t = (threadIdx.x >= off) ? buf[threadIdx.x - off] : 0;
    __syncthreads();
    buf[threadIdx.x] += t;
    __syncthreads();
  }
  if (threadIdx.x < nb) bsum[threadIdx.x] = buf[threadIdx.x] - v;  // exclusive
}

__global__ __launch_bounds__(1024) void k_scan_final(const int* __restrict__ cnt,
                                                     const int* __restrict__ incl,
                                                     const int* __restrict__ bsum,
                                                     int* __restrict__ row_ptr, int* __restrict__ cursor,
                                                     float* __restrict__ dinv, int n, int E) {
  int i = blockIdx.x * 1024 + threadIdx.x;
  if (i < n) {
    int c = cnt[i];
    int ex = incl[i] + bsum[blockIdx.x] - c;
    row_ptr[i] = ex;
    cursor[i] = ex;
    dinv[i] = 1.0f / sqrtf((float)(c + 1));  // deg includes self-loop
  }
  if (i == 0) row_ptr[n] = E;
}

__global__ void k_place(const int* __restrict__ ei, int* __restrict__ cursor,
                        const float* __restrict__ dinv, int* __restrict__ src_sorted,
                        float* __restrict__ w_sorted, int E) {
  int e = blockIdx.x * blockDim.x + threadIdx.x;
  if (e < E) {
    int s = ei[e], d = ei[E + e];
    int slot = atomicAdd(&cursor[d], 1);
    src_sorted[slot] = s;
    w_sorted[slot] = dinv[s] * dinv[d];
  }
}

// ---------------- CSR aggregations ----------------
__global__ __launch_bounds__(256) void k_agg_px(const u16* __restrict__ xb, u16* __restrict__ px,
                                                const int* __restrict__ rp, const int* __restrict__ src,
                                                const float* __restrict__ wst, const float* __restrict__ dinv,
                                                int n) {
  int wv = threadIdx.x >> 6, lane = threadIdx.x & 63;
  int node = blockIdx.x * 4 + wv;
  if (node >= n) return;
  float a0 = 0.f, a1 = 0.f;
  int s0 = rp[node], s1 = rp[node + 1];
  int s = s0;
  for (; s + 8 <= s1; s += 8) {
    u32 v[8]; float wg[8];
#pragma unroll
    for (int u = 0; u < 8; ++u) {
      int r = src[s + u];
      wg[u] = wst[s + u];
      v[u] = *((const u32*)(xb + (size_t)r * 128) + lane);
    }
#pragma unroll
    for (int u = 0; u < 8; ++u) { a0 += wg[u] * blo(v[u]); a1 += wg[u] * bhi(v[u]); }
  }
  for (; s < s1; ++s) {
    float wgt = wst[s];
    int r = src[s];
    u32 w = *((const u32*)(xb + (size_t)r * 128) + lane);
    a0 += wgt * blo(w); a1 += wgt * bhi(w);
  }
  float sw = dinv[node]; sw *= sw;
  u32 w = *((const u32*)(xb + (size_t)node * 128) + lane);
  a0 += sw * blo(w); a1 += sw * bhi(w);
  u32 o = ((u32)f2b(a0)) | (((u32)f2b(a1)) << 16);
  *((u32*)(px + (size_t)node * 128) + lane) = o;
}

// merged layer-2 agg: 4-deep unroll + NON-TEMPORAL output stores (keep ycat L3-resident)
__global__ __launch_bounds__(256) void k_agg512(const u16* __restrict__ ycat,
                                                float* __restrict__ zc, u16* __restrict__ zcb,
                                                float* __restrict__ zh,
                                                const int* __restrict__ rp, const int* __restrict__ src,
                                                const float* __restrict__ wst, const float* __restrict__ dinv,
                                                const float* __restrict__ bcat, int n) {
  int wv = threadIdx.x >> 6, lane = threadIdx.x & 63;
  int node = blockIdx.x * 4 + wv;
  if (node >= n) return;
  float acc[8] = {};
  int s0 = rp[node], s1 = rp[node + 1];
  int s = s0;
  for (; s + 4 <= s1; s += 4) {
    uint4 v[4]; float wg[4];
#pragma unroll
    for (int u = 0; u < 4; ++u) {
      int r = src[s + u];
      wg[u] = wst[s + u];
      v[u] = *((const uint4*)(ycat + (size_t)r * 512) + lane);
    }
#pragma unroll
    for (int u = 0; u < 4; ++u)
#pragma unroll
      for (int q = 0; q < 4; ++q) {
        u32 word = ((const u32*)&v[u])[q];
        acc[2 * q]     += wg[u] * blo(word);
        acc[2 * q + 1] += wg[u] * bhi(word);
      }
  }
  for (; s < s1; ++s) {
    float wgt = wst[s];
    int r = src[s];
    uint4 v = *((const uint4*)(ycat + (size_t)r * 512) + lane);
#pragma unroll
    for (int q = 0; q < 4; ++q) {
      u32 word = ((const u32*)&v)[q];
      acc[2 * q]     += wgt * blo(word);
      acc[2 * q + 1] += wgt * bhi(word);
    }
  }
  float sw = dinv[node]; sw *= sw;
  uint4 v = *((const uint4*)(ycat + (size_t)node * 512) + lane);
#pragma unroll
  for (int q = 0; q < 4; ++q) {
    u32 word = ((const u32*)&v)[q];
    acc[2 * q]     += sw * blo(word);
    acc[2 * q + 1] += sw * bhi(word);
  }
  int f0 = lane * 8;
#pragma unroll
  for (int j = 0; j < 8; ++j) acc[j] += bcat[f0 + j];
  if (lane < 32) {
    float* o = zc + (size_t)node * 256 + f0;
    u16* ob = zcb + (size_t)node * 256 + f0;
#pragma unroll
    for (int j = 0; j < 8; ++j) {
      __builtin_nontemporal_store(acc[j], o + j);
      __builtin_nontemporal_store(f2b(acc[j]), ob + j);
    }
  } else {
    float* o = zh + (size_t)node * 256 + (f0 - 256);
#pragma unroll
    for (int j = 0; j < 8; ++j) __builtin_nontemporal_store(acc[j], o + j);
  }
}

__global__ __launch_bounds__(256) void k_agg_dec(const u16* __restrict__ yd, float* __restrict__ xhat,
                                                 const int* __restrict__ rp, const int* __restrict__ src,
                                                 const float* __restrict__ wst, const float* __restrict__ dinv,
                                                 const float* __restrict__ bd, int n) {
  int wv = threadIdx.x >> 6, lane = threadIdx.x & 63;
  int node = blockIdx.x * 4 + wv;
  if (node >= n) return;
  float a0 = 0.f, a1 = 0.f;
  int s0 = rp[node], s1 = rp[node + 1];
  int s = s0;
  for (; s + 8 <= s1; s += 8) {
    u32 v[8]; float wg[8];
#pragma unroll
    for (int u = 0; u < 8; ++u) {
      int r = src[s + u];
      wg[u] = wst[s + u];
      v[u] = *((const u32*)(yd + (size_t)r * 128) + lane);
    }
#pragma unroll
    for (int u = 0; u < 8; ++u) { a0 += wg[u] * blo(v[u]); a1 += wg[u] * bhi(v[u]); }
  }
  for (; s < s1; ++s) {
    float wgt = wst[s];
    int r = src[s];
    u32 w = *((const u32*)(yd + (size_t)r * 128) + lane);
    a0 += wgt * blo(w); a1 += wgt * bhi(w);
  }
  float sw = dinv[node]; sw *= sw;
  u32 w = *((const u32*)(yd + (size_t)node * 128) + lane);
  a0 += sw * blo(w); a1 += sw * bhi(w);
  float* o = xhat + (size_t)node * 128 + lane * 2;
  __builtin_nontemporal_store(a0 + bd[lane * 2], o);
  __builtin_nontemporal_store(a1 + bd[lane * 2 + 1], o + 1);
}

// ---------------- MFMA bf16 GEMM ----------------
template <bool RELU, bool BIAS, typename TC>
__global__ __launch_bounds__(256) void k_mgemm(const u16* __restrict__ A, const u16* __restrict__ BT,
                                               const float* __restrict__ bias, TC* __restrict__ C,
                                               int M, int N, int K, int ldc, int coloff) {
  __shared__ u16 As[128 * 64];
  __shared__ u16 Bs[128 * 64];
  const int t = threadIdx.x;
  const int w = t >> 6, lane = t & 63;
  const int brow = blockIdx.y * 128;
  const int bcol = blockIdx.x * 128;
  const int wr = w >> 1, wc = w & 1;

  f32x4 acc[4][4];
#pragma unroll
  for (int m = 0; m < 4; ++m)
#pragma unroll
    for (int n = 0; n < 4; ++n) acc[m][n] = (f32x4){0.f, 0.f, 0.f, 0.f};

  for (int kt = 0; kt < K; kt += 64) {
#pragma unroll
    for (int j = 0; j < 4; ++j) {
      int c = j * 4 + w;              // chunk 0..15 (wave-uniform)
      int li = c * 64 + lane;         // 16B unit index
      int row = li >> 3, col8 = li & 7;
      int ar = brow + row; if (ar > M - 1) ar = M - 1;
      __builtin_amdgcn_global_load_lds(
          (const __attribute__((address_space(1))) void*)(A + (size_t)ar * K + kt + col8 * 8),
          (__attribute__((address_space(3))) void*)(As + c * 512), 16, 0, 0);
      __builtin_amdgcn_global_load_lds(
          (const __attribute__((address_space(1))) void*)(BT + (size_t)(bcol + row) * K + kt + col8 * 8),
          (__attribute__((address_space(3))) void*)(Bs + c * 512), 16, 0, 0);
    }
    __syncthreads();
    bf16x8 af[4][2], bb[4][2];
#pragma unroll
    for (int kk = 0; kk < 2; ++kk) {
      int kof = kk * 32 + (lane >> 4) * 8;
#pragma unroll
      for (int m = 0; m < 4; ++m)
        af[m][kk] = *(const bf16x8*)(As + (wr * 64 + m * 16 + (lane & 15)) * 64 + kof);
#pragma unroll
      for (int n = 0; n < 4; ++n)
        bb[n][kk] = *(const bf16x8*)(Bs + (wc * 64 + n * 16 + (lane & 15)) * 64 + kof);
    }
#pragma unroll
    for (int kk = 0; kk < 2; ++kk)
#pragma unroll
      for (int m = 0; m < 4; ++m)
#pragma unroll
        for (int n = 0; n < 4; ++n)
          acc[m][n] = __builtin_amdgcn_mfma_f32_16x16x32_bf16(af[m][kk], bb[n][kk], acc[m][n], 0, 0, 0);
    __syncthreads();
  }
#pragma unroll
  for (int m = 0; m < 4; ++m) {
    int r0 = brow + wr * 64 + m * 16 + (lane >> 4) * 4;
#pragma unroll
    for (int n = 0; n < 4; ++n) {
      int col = bcol + wc * 64 + n * 16 + (lane & 15);
      float bv = BIAS ? bias[col] : 0.0f;
#pragma unroll
      for (int q = 0; q < 4; ++q) {
        int rr = r0 + q;
        if (rr < M) {
          float v = acc[m][n][q] + bv;
          if (RELU) v = fmaxf(v, 0.0f);
          stor(&C[(size_t)rr * ldc + coloff + col], v);
        }
      }
    }
  }
}

// ---------------- small f32 GEMM (proj heads) ----------------
template <typename TA, typename TC, bool RELU, bool BIAS>
__global__ __launch_bounds__(256) void k_gemm(const TA* __restrict__ A, const float* __restrict__ B,
                                              const float* __restrict__ bias, TC* __restrict__ C,
                                              int M, int N, int K) {
  __shared__ float As[64][17];
  __shared__ float Bs[16][65];
  const int tx = threadIdx.x & 15;
  const int ty = threadIdx.x >> 4;
  const int row0 = blockIdx.y * 64;
  const int col0 = blockIdx.x * 64;
  float acc[4][4] = {};
  for (int k0 = 0; k0 < K; k0 += 16) {
#pragma unroll
    for (int i = 0; i < 4; ++i) {
      int lin = threadIdx.x + i * 256;
      int r = lin >> 4, c = lin & 15;
      int gr = row0 + r;
      As[r][c] = (gr < M) ? cvt(A[(size_t)gr * K + k0 + c]) : 0.0f;
    }
#pragma unroll
    for (int i = 0; i < 4; ++i) {
      int lin = threadIdx.x + i * 256;
      int r = lin >> 6, c = lin & 63;
      Bs[r][c] = (col0 + c < N) ? B[(size_t)(k0 + r) * N + col0 + c] : 0.0f;
    }
    __syncthreads();
#pragma unroll
    for (int k = 0; k < 16; ++k) {
      float a[4], b[4];
#pragma unroll
      for (int i = 0; i < 4; ++i) a[i] = As[ty * 4 + i][k];
#pragma unroll
      for (int j = 0; j < 4; ++j) b[j] = Bs[k][tx * 4 + j];
#pragma unroll
      for (int i = 0; i < 4; ++i)
#pragma unroll
        for (int j = 0; j < 4; ++j) acc[i][j] += a[i] * b[j];
    }
    __syncthreads();
  }
#pragma unroll
  for (int i = 0; i < 4; ++i) {
    int gr = row0 + ty * 4 + i;
    if (gr < M) {
#pragma unroll
      for (int j = 0; j < 4; ++j) {
        int gc = col0 + tx * 4 + j;
        if (gc < N) {
          float v = acc[i][j];
          if (BIAS) v += bias[gc];
          if (RELU) v = fmaxf(v, 0.0f);
          stor(&C[(size_t)gr * N + gc], v);
        }
      }
    }
  }
}

// ---------------- pooling ----------------
__device__ inline int lbound(const int* a, int n, int v) {
  int lo = 0, hi = n;
  while (lo < hi) { int mid = (lo + hi) >> 1; if (a[mid] < v) lo = mid + 1; else hi = mid; }
  return lo;
}

#define POOL_NCH 32

__global__ __launch_bounds__(256) void k_pool_partial2(const float* __restrict__ zc,
                                                       const float* __restrict__ zh,
                                                       const int* __restrict__ batch,
                                                       float* __restrict__ psum, float* __restrict__ pmax,
                                                       int n) {
  int g = blockIdx.x, yy = blockIdx.y;
  int half = (yy >= POOL_NCH) ? 1 : 0;
  int ch = yy - half * POOL_NCH;
  const float* z = half ? zh : zc;
  __shared__ int ss, se;
  if (threadIdx.x == 0) { ss = lbound(batch, n, g); se = lbound(batch, n, g + 1); }
  __syncthreads();
  int start = ss, len = se - ss;
  int c0 = start + (int)((long long)len * ch / POOL_NCH);
  int c1 = start + (int)((long long)len * (ch + 1) / POOL_NCH);
  int f = threadIdx.x;
  float acc = 0.0f, mx = -INFINITY;
  for (int i = c0; i < c1; ++i) {
    float v = z[(size_t)i * 256 + f];
    acc += v;
    mx = fmaxf(mx, v);
  }
  size_t o = ((size_t)(half * 64 + g) * POOL_NCH + ch) * 256 + f;
  psum[o] = acc;
  pmax[o] = mx;
}

__global__ __launch_bounds__(256) void k_pool_final2(const float* __restrict__ psum,
                                                     const float* __restrict__ pmax,
                                                     const int* __restrict__ batch,
                                                     float* __restrict__ z_g, float* __restrict__ zhat_g,
                                                     float* __restrict__ gcat, int n) {
  int gg = blockIdx.x, f = threadIdx.x;
  int g = gg & 63, half = gg >> 6;
  float s = 0.0f, m = -INFINITY;
#pragma unroll 4
  for (int c = 0; c < POOL_NCH; ++c) {
    size_t o = ((size_t)gg * POOL_NCH + c) * 256 + f;
    s += psum[o];
    m = fmaxf(m, pmax[o]);
  }
  __shared__ int ss, se;
  if (threadIdx.x == 0) { ss = lbound(batch, n, g); se = lbound(batch, n, g + 1); }
  __syncthreads();
  int cnt = se - ss;
  float mean = s / fmaxf((float)cnt, 1.0f);
  float mxo = (cnt > 0) ? m : 0.0f;
  float* zg = half ? zhat_g : z_g;
  zg[(size_t)g * 512 + f] = mean;
  zg[(size_t)g * 512 + 256 + f] = mxo;
  gcat[(size_t)gg * 512 + f] = mean;
  gcat[(size_t)gg * 512 + 256 + f] = mxo;
}

// ---------------- launch ----------------
extern "C" void kernel_launch(void* const* d_in, const int* in_sizes, int n_in,
                              void* d_out, int out_size, void* d_ws, size_t ws_size,
                              hipStream_t stream) {
  const float* x   = (const float*)d_in[0];
  const int*   ei  = (const int*)d_in[1];
  const int*   bat = (const int*)d_in[2];
  const float* W1  = (const float*)d_in[4];
  const float* b1  = (const float*)d_in[5];
  const float* W2  = (const float*)d_in[6];
  const float* b2  = (const float*)d_in[7];
  const float* Wd  = (const float*)d_in[8];
  const float* bd  = (const float*)d_in[9];
  const float* P1w = (const float*)d_in[10];
  const float* P1b = (const float*)d_in[11];
  const float* P2w = (const float*)d_in[12];
  const float* P2b = (const float*)d_in[13];
  const float* P3w = (const float*)d_in[14];
  const float* P3b = (const float*)d_in[15];

  const int N = in_sizes[0] / 128;  // 50000
  const int E = in_sizes[1] / 2;    // 400000
  const int B = 64;
  const int NB = (N + 1023) / 1024;

  char* w = (char*)d_ws;
  auto carve = [&](size_t bytes) -> void* {
    void* p = (void*)w;
    w += (bytes + 255) & ~(size_t)255;
    return p;
  };
  int*    cnt        = (int*)carve((size_t)N * 4);
  int*    row_ptr    = (int*)carve((size_t)(N + 1) * 4);
  int*    cursor     = (int*)carve((size_t)N * 4);
  float*  dinv       = (float*)carve((size_t)N * 4);
  int*    incl       = (int*)carve((size_t)N * 4);
  int*    bsum       = (int*)carve((size_t)1024 * 4);
  int*    src_sorted = (int*)carve((size_t)E * 4);
  float*  w_sorted   = (float*)carve((size_t)E * 4);
  float*  sigma      = (float*)carve(256);
  double* psd        = (double*)carve((size_t)64 * 2 * 8);
  float*  b1h        = (float*)carve((size_t)512 * 4);
  float*  b2h        = (float*)carve((size_t)256 * 4);
  float*  bcat       = (float*)carve((size_t)512 * 4);
  u16*    W1T        = (u16*)carve((size_t)128 * 512 * 2);
  u16*    W2T        = (u16*)carve((size_t)512 * 256 * 2);
  u16*    WdT        = (u16*)carve((size_t)256 * 128 * 2);
  u16*    W1hT       = (u16*)carve((size_t)128 * 512 * 2);
  u16*    W2hT       = (u16*)carve((size_t)512 * 256 * 2);
  u16*    xb         = (u16*)carve((size_t)N * 128 * 2);
  u16*    px         = (u16*)carve((size_t)N * 128 * 2);
  u16*    z1         = (u16*)carve((size_t)N * 512 * 2);   // L1 scratch (reused both branches)
  u16*    ycat       = (u16*)carve((size_t)N * 512 * 2);   // [y_clean | y_pert]; later aliased as yd
  u16*    znb        = (u16*)carve((size_t)N * 256 * 2);   // bf16 z_node (decoder A)
  float*  gcat       = (float*)carve((size_t)128 * 512 * 4);
  float*  pg1        = (float*)carve((size_t)128 * 256 * 4);
  float*  pg2        = (float*)carve((size_t)128 * 128 * 4);
  float*  psum       = (float*)carve((size_t)2 * B * POOL_NCH * 256 * 4);
  float*  pmax       = (float*)carve((size_t)2 * B * POOL_NCH * 256 * 4);
  u16*    yd         = ycat;  // alias: ycat dead after k_agg512

  float* out       = (float*)d_out;
  float* z_node    = out;
  float* z_g       = z_node + (size_t)N * 256;
  float* zhat_node = z_g + (size_t)B * 512;
  float* zhat_g    = zhat_node + (size_t)N * 256;
  float* h_g       = zhat_g + (size_t)B * 512;
  float* x_hat     = h_g + (size_t)2 * B * 64;

  // nk = split(key(42), 4): nk[i] = threefry(key, (0, i))
  u32 nk[4][2];
  for (u32 i = 0; i < 4; ++i) tf2x32(0u, 42u, 0u, i, &nk[i][0], &nk[i][1]);

  // --- fused prep: count + std1 + clean transposes + xb cast ---
  const int c1 = (E + 255) / 256;
  const int n4b = (N * 128 / 4 + 255) / 256;
  const int prepABlocks = c1 + 64 + 256 + 512 + 128 + n4b;
  hipMemsetAsync(cnt, 0, (size_t)N * 4, stream);
  k_prepA<<<prepABlocks, 256, 0, stream>>>(ei, cnt, E, W1, b1, W2, b2, psd,
                                           Wd, W1T, W2T, WdT, x, xb, N, c1);

  // --- scan + CSR build ---
  k_scan_local<<<NB, 1024, 0, stream>>>(cnt, incl, bsum, N);
  k_scan_bsum<<<1, 1024, 0, stream>>>(bsum, NB);
  k_scan_final<<<NB, 1024, 0, stream>>>(cnt, incl, bsum, row_ptr, cursor, dinv, N, E);
  k_place<<<(E + 255) / 256, 256, 0, stream>>>(ei, cursor, dinv, src_sorted, w_sorted, E);

  // --- sigma + fused perturb ---
  k_std2<<<1, 64, 0, stream>>>(psd, sigma);
  k_perturbAll<<<771, 256, 0, stream>>>(W1, b1, W2, b2, W1hT, b1h, W2hT, b2h, bcat, sigma,
                                        nk[0][0], nk[0][1], nk[1][0], nk[1][1],
                                        nk[2][0], nk[2][1], nk[3][0], nk[3][1]);

  const int aggBlocks = (N + 3) / 4;

  // px = P @ x (shared by both branches)
  k_agg_px<<<aggBlocks, 256, 0, stream>>>(xb, px, row_ptr, src_sorted, w_sorted, dinv, N);

  const int MB = (N + 127) / 128;
  dim3 m512(4, MB), m256(2, MB), m128(1, MB);

  // perturbed branch L1+L2 -> ycat cols 256-511
  k_mgemm<true, true, u16><<<m512, 256, 0, stream>>>(px, W1hT, b1h, z1, N, 512, 128, 512, 0);
  k_mgemm<false, false, u16><<<m256, 256, 0, stream>>>(z1, W2hT, nullptr, ycat, N, 256, 512, 512, 256);
  // clean branch L1+L2 -> ycat cols 0-255 (z1 reused)
  k_mgemm<true, true, u16><<<m512, 256, 0, stream>>>(px, W1T, b1, z1, N, 512, 128, 512, 0);
  k_mgemm<false, false, u16><<<m256, 256, 0, stream>>>(z1, W2T, nullptr, ycat, N, 256, 512, 512, 0);

  // single merged aggregation pass: z_node (+znb bf16) and zhat_node (nt stores)
  k_agg512<<<aggBlocks, 256, 0, stream>>>(ycat, z_node, znb, zhat_node,
                                          row_ptr, src_sorted, w_sorted, dinv, bcat, N);

  // pooling (two-stage, both branches per launch)
  dim3 pgrid(B, 2 * POOL_NCH);
  k_pool_partial2<<<pgrid, 256, 0, stream>>>(z_node, zhat_node, bat, psum, pmax, N);
  k_pool_final2<<<128, 256, 0, stream>>>(psum, pmax, bat, z_g, zhat_g, gcat, N);

  // decoder: x_hat = P @ (z_node @ Wd) + bd
  k_mgemm<false, false, u16><<<m128, 256, 0, stream>>>(znb, WdT, nullptr, yd, N, 128, 256, 128, 0);
  k_agg_dec<<<aggBlocks, 256, 0, stream>>>(yd, x_hat, row_ptr, src_sorted, w_sorted, dinv, bd, N);

  // stacked projection heads: [z_g; zhat_g] (128 rows); last GEMM writes h_g||hhat_g directly
  dim3 q1(4, 2), q2(2, 2), q3(1, 2);
  k_gemm<float, float, true, true><<<q1, 256, 0, stream>>>(gcat, P1w, P1b, pg1, 128, 256, 512);
  k_gemm<float, float, true, true><<<q2, 256, 0, stream>>>(pg1, P2w, P2b, pg2, 128, 128, 256);
  k_gemm<float, float, false, true><<<q3, 256, 0, stream>>>(pg2, P3w, P3b, h_g, 128, 64, 128);
}